// Round 8
// baseline (267.049 us; speedup 1.0000x reference)
//
#include <hip/hip_runtime.h>
#include <hip/hip_bf16.h>

// Problem constants
#define HH 40
#define WW 40
#define KK 5
#define PP 1296            // 36*36
#define LL 25
#define MM 384
#define NN 64
#define NPTS (NN * PP)     // 82944
#define JITTER 1e-6f

typedef unsigned short u16;
typedef unsigned int   u32;
using short8  = __attribute__((ext_vector_type(8))) short;
using floatx4 = __attribute__((ext_vector_type(4))) float;

#define FRAG_N (MM * MM)        // u16 per frag half-array (147456)
#define ZFRAG_N (24 * 64 * 8)   // 12288

// ---------------------------------------------------------------------------
// bf16 split helpers (RNE)
__device__ inline u16 f2bf(float v) {
    u32 b = __float_as_uint(v);
    return (u16)((b + 0x7FFFu + ((b >> 16) & 1u)) >> 16);
}
__device__ inline float bf2f(u16 h) { return __uint_as_float(((u32)h) << 16); }
__device__ inline void split_bf16(float v, u16& hi, u16& lo) {
    hi = f2bf(v);
    lo = f2bf(v - bf2f(hi));
}

// A-fragment linear index (u16 units) for element (m,k), HW-verified rounds 2-7.
__device__ inline int frag_idx(int m, int k) {
    return (((m >> 4) * 12 + (k >> 5)) * 64 + ((m & 15) + (((k >> 3) & 3) << 4))) * 8 + (k & 7);
}

// ---------------------------------------------------------------------------
// Split-bf16 MFMA 64x64-tile GEMM on A-frag operands: C = A . B^T_storage.
__device__ inline void frag_gemm64(const u16* __restrict__ Ah, const u16* __restrict__ Al,
                                   const u16* __restrict__ Bh, const u16* __restrict__ Bl,
                                   int bi, int bj, int w, int l, floatx4 acc[2][2]) {
    int mt0 = bi * 4 + 2 * (w & 1);
    int nt0 = bj * 4 + 2 * (w >> 1);
#pragma unroll
    for (int i = 0; i < 2; ++i)
#pragma unroll
        for (int jn = 0; jn < 2; ++jn) { floatx4 z = {0.f, 0.f, 0.f, 0.f}; acc[i][jn] = z; }
    for (int kt = 0; kt < 12; ++kt) {
        int ab0 = (((mt0 + 0) * 12 + kt) * 64 + l) * 8;
        int ab1 = (((mt0 + 1) * 12 + kt) * 64 + l) * 8;
        int bb0 = (((nt0 + 0) * 12 + kt) * 64 + l) * 8;
        int bb1 = (((nt0 + 1) * 12 + kt) * 64 + l) * 8;
        short8 a0h = *(const short8*)&Ah[ab0];
        short8 a0l = *(const short8*)&Al[ab0];
        short8 a1h = *(const short8*)&Ah[ab1];
        short8 a1l = *(const short8*)&Al[ab1];
        short8 b0h = *(const short8*)&Bh[bb0];
        short8 b0l = *(const short8*)&Bl[bb0];
        short8 b1h = *(const short8*)&Bh[bb1];
        short8 b1l = *(const short8*)&Bl[bb1];
        acc[0][0] = __builtin_amdgcn_mfma_f32_16x16x32_bf16(a0h, b0h, acc[0][0], 0, 0, 0);
        acc[0][0] = __builtin_amdgcn_mfma_f32_16x16x32_bf16(a0h, b0l, acc[0][0], 0, 0, 0);
        acc[0][0] = __builtin_amdgcn_mfma_f32_16x16x32_bf16(a0l, b0h, acc[0][0], 0, 0, 0);
        acc[0][1] = __builtin_amdgcn_mfma_f32_16x16x32_bf16(a0h, b1h, acc[0][1], 0, 0, 0);
        acc[0][1] = __builtin_amdgcn_mfma_f32_16x16x32_bf16(a0h, b1l, acc[0][1], 0, 0, 0);
        acc[0][1] = __builtin_amdgcn_mfma_f32_16x16x32_bf16(a0l, b1h, acc[0][1], 0, 0, 0);
        acc[1][0] = __builtin_amdgcn_mfma_f32_16x16x32_bf16(a1h, b0h, acc[1][0], 0, 0, 0);
        acc[1][0] = __builtin_amdgcn_mfma_f32_16x16x32_bf16(a1h, b0l, acc[1][0], 0, 0, 0);
        acc[1][0] = __builtin_amdgcn_mfma_f32_16x16x32_bf16(a1l, b0h, acc[1][0], 0, 0, 0);
        acc[1][1] = __builtin_amdgcn_mfma_f32_16x16x32_bf16(a1h, b1h, acc[1][1], 0, 0, 0);
        acc[1][1] = __builtin_amdgcn_mfma_f32_16x16x32_bf16(a1h, b1l, acc[1][1], 0, 0, 0);
        acc[1][1] = __builtin_amdgcn_mfma_f32_16x16x32_bf16(a1l, b1h, acc[1][1], 0, 0, 0);
    }
}

__device__ inline void dwrite_frag(u16* __restrict__ Oh, u16* __restrict__ Ol,
                                   int m, int p, float v) {
    int idx = frag_idx(m, p);
    u16 hi, lo;
    split_bf16(v, hi, lo);
    Oh[idx] = hi; Ol[idx] = lo;
}

// ---------------------------------------------------------------------------
// Launch 1: Kuu dense + Kuu frags + rowsums + z2 + Z frags + Q frags.
__global__ void __launch_bounds__(384) prep_kernel(
    const float* __restrict__ Z, const float* __restrict__ q_sqrt,
    const float* __restrict__ var_p, const float* __restrict__ ls_p,
    float* __restrict__ Kuu, float* __restrict__ rsum, float* __restrict__ z2g,
    u16* __restrict__ Kfh, u16* __restrict__ Kfl,
    u16* __restrict__ Qh, u16* __restrict__ Ql,
    u16* __restrict__ Zfh, u16* __restrict__ Zfl) {
    __shared__ float Zs[LL];
    __shared__ float red[384];
    int r = blockIdx.x, tid = threadIdx.x;
    if (tid < LL) Zs[tid] = Z[r * LL + tid];
    __syncthreads();
    float var = var_p[0];
    float ls = ls_p[0];
    float c0 = -0.5f / (ls * ls);
    float s = 0.f;
#pragma unroll
    for (int d = 0; d < LL; ++d) {
        float dd = Zs[d] - Z[tid * LL + d];
        s += dd * dd;
    }
    float v = var * expf(c0 * s);
    if (tid == r) v += JITTER;
    Kuu[r * MM + tid] = v;
    red[tid] = v;
    __syncthreads();
    if (tid < 128) red[tid] += red[tid + 256];
    __syncthreads();
    for (int o = 128; o > 0; o >>= 1) {
        if (tid < o) red[tid] += red[tid + o];
        __syncthreads();
    }
    if (tid == 0) {
        rsum[r] = red[0];
        float t = 0.f;
#pragma unroll
        for (int d = 0; d < LL; ++d) t += Zs[d] * Zs[d];
        z2g[r] = t;
    }
    // frag-order writes: one element per thread (384*384 == FRAG_N)
    {
        int o = r * MM + tid;
        int j = o & 7, ln = (o >> 3) & 63, kt = (o >> 9) % 12, mt = o / 6144;
        int m = mt * 16 + (ln & 15);
        int k = kt * 32 + ((ln >> 4) << 3) + j;
        u16 h, lo;
        // Q frag
        float qv = (k <= m) ? q_sqrt[m * MM + k] : 0.f;
        split_bf16(qv, h, lo);
        Qh[o] = h; Ql[o] = lo;
        // Kuu frag (recompute distance for (m,k))
        float s2 = 0.f;
#pragma unroll
        for (int d = 0; d < LL; ++d) {
            float dd = Z[m * LL + d] - Z[k * LL + d];
            s2 += dd * dd;
        }
        float kv = var * expf(c0 * s2);
        if (m == k) kv += JITTER;
        split_bf16(kv, h, lo);
        Kfh[o] = h; Kfl[o] = lo;
        // Z frag
        if (o < ZFRAG_N) {
            int zt = o >> 9;
            int mz = zt * 16 + (ln & 15);
            int kd = ((ln >> 4) << 3) + j;
            float zv = (kd < LL) ? Z[mz * LL + kd] : 0.f;
            split_bf16(zv, h, lo);
            Zfh[o] = h; Zfl[o] = lo;
        }
    }
}

// ---------------------------------------------------------------------------
// Launch 2: blocks 0-35: X1 = alpha*(2I - alpha*Kuu);
//           36-71: R1 = I - 2a*K + a^2*(K@K)  (K frags from prep);
//           72-107: SK = Q@Q^T - Kuu.
__global__ void __launch_bounds__(256) ns1_kernel(
    const float* __restrict__ Kuu, const float* __restrict__ rsum,
    const u16* __restrict__ Kfh, const u16* __restrict__ Kfl,
    const u16* __restrict__ Qh, const u16* __restrict__ Ql,
    u16* __restrict__ Xh, u16* __restrict__ Xl,
    u16* __restrict__ Rh, u16* __restrict__ Rl,
    u16* __restrict__ SKh, u16* __restrict__ SKl) {
    __shared__ float red[256];
    int tid = threadIdx.x, blk = blockIdx.x;
    int w = tid >> 6, l = tid & 63;
    float alpha = 0.f;
    if (blk < 72) {
        float v0 = rsum[tid];
        if (tid < 128) v0 = fmaxf(v0, rsum[tid + 256]);
        red[tid] = v0;
        __syncthreads();
        for (int o = 128; o > 0; o >>= 1) {
            if (tid < o) red[tid] = fmaxf(red[tid], red[tid + o]);
            __syncthreads();
        }
        alpha = 1.0f / red[0];
    }
    if (blk < 36) {
        float a2 = alpha * alpha;
        for (int o = blk * 256 + tid; o < FRAG_N; o += 36 * 256) {
            int j = o & 7, ln = (o >> 3) & 63, kt = (o >> 9) % 12, mt = o / 6144;
            int m = mt * 16 + (ln & 15);
            int k = kt * 32 + ((ln >> 4) << 3) + j;
            float v = ((m == k) ? 2.f * alpha : 0.f) - a2 * Kuu[m * MM + k];
            u16 h, lo;
            split_bf16(v, h, lo);
            Xh[o] = h; Xl[o] = lo;
        }
    } else if (blk < 72) {
        int tile = blk - 36;
        int bi = tile / 6, bj = tile % 6;
        floatx4 acc[2][2];
        frag_gemm64(Kfh, Kfl, Kfh, Kfl, bi, bj, w, l, acc);   // K @ K
        int mt0 = bi * 4 + 2 * (w & 1), nt0 = bj * 4 + 2 * (w >> 1);
        float a2 = alpha * alpha;
#pragma unroll
        for (int i = 0; i < 2; ++i)
#pragma unroll
            for (int jn = 0; jn < 2; ++jn)
#pragma unroll
                for (int j = 0; j < 4; ++j) {
                    int m = (mt0 + i) * 16 + ((l >> 4) << 2) + j;
                    int p = (nt0 + jn) * 16 + (l & 15);
                    float v = a2 * acc[i][jn][j] - 2.f * alpha * Kuu[m * MM + p]
                            + ((m == p) ? 1.f : 0.f);
                    dwrite_frag(Rh, Rl, m, p, v);
                }
    } else {
        int tile = blk - 72;
        int bi = tile / 6, bj = tile % 6;
        floatx4 acc[2][2];
        frag_gemm64(Qh, Ql, Qh, Ql, bi, bj, w, l, acc);
        int mt0 = bi * 4 + 2 * (w & 1), nt0 = bj * 4 + 2 * (w >> 1);
#pragma unroll
        for (int i = 0; i < 2; ++i)
#pragma unroll
            for (int jn = 0; jn < 2; ++jn)
#pragma unroll
                for (int j = 0; j < 4; ++j) {
                    int m = (mt0 + i) * 16 + ((l >> 4) << 2) + j;
                    int p = (nt0 + jn) * 16 + (l & 15);
                    dwrite_frag(SKh, SKl, m, p, acc[i][jn][j] - Kuu[m * MM + p]);
                }
    }
}

// ---------------------------------------------------------------------------
// NS rounds: blocks 0-35: X' = X + X@R ; 36-71: R' = R@R
__global__ void __launch_bounds__(256) ns_kernel(
    const u16* __restrict__ cxh, const u16* __restrict__ cxl,
    const u16* __restrict__ crh, const u16* __restrict__ crl,
    u16* __restrict__ nxh, u16* __restrict__ nxl,
    u16* __restrict__ nrh, u16* __restrict__ nrl) {
    int blk = blockIdx.x, tid = threadIdx.x;
    bool isX = (blk < 36);
    int tile = isX ? blk : blk - 36;
    int bi = tile / 6, bj = tile % 6;
    int w = tid >> 6, l = tid & 63;
    floatx4 acc[2][2];
    frag_gemm64(isX ? cxh : crh, isX ? cxl : crl, crh, crl, bi, bj, w, l, acc);
    int mt0 = bi * 4 + 2 * (w & 1), nt0 = bj * 4 + 2 * (w >> 1);
    u16* Oh = isX ? nxh : nrh;
    u16* Ol = isX ? nxl : nrl;
#pragma unroll
    for (int i = 0; i < 2; ++i)
#pragma unroll
        for (int jn = 0; jn < 2; ++jn)
#pragma unroll
            for (int j = 0; j < 4; ++j) {
                int m = (mt0 + i) * 16 + ((l >> 4) << 2) + j;
                int p = (nt0 + jn) * 16 + (l & 15);
                float v = acc[i][jn][j];
                if (isX) {
                    int id = frag_idx(m, p);
                    v += bf2f(cxh[id]) + bf2f(cxl[id]);
                }
                dwrite_frag(Oh, Ol, m, p, v);
            }
}

// ---------------------------------------------------------------------------
// Launch 8: blocks 0-35: Y = X @ SK ; blocks 36-41: cvec = X @ q_mu
__global__ void __launch_bounds__(256) y_kernel(
    const u16* __restrict__ Xh, const u16* __restrict__ Xl,
    const u16* __restrict__ SKh, const u16* __restrict__ SKl,
    const float* __restrict__ qmu,
    u16* __restrict__ Yh, u16* __restrict__ Yl, float* __restrict__ cvec) {
    __shared__ float q[MM];
    int tid = threadIdx.x, blk = blockIdx.x;
    int w = tid >> 6, l = tid & 63;
    if (blk < 36) {
        int bi = blk / 6, bj = blk % 6;
        floatx4 acc[2][2];
        frag_gemm64(Xh, Xl, SKh, SKl, bi, bj, w, l, acc);
        int mt0 = bi * 4 + 2 * (w & 1), nt0 = bj * 4 + 2 * (w >> 1);
#pragma unroll
        for (int i = 0; i < 2; ++i)
#pragma unroll
            for (int jn = 0; jn < 2; ++jn)
#pragma unroll
                for (int j = 0; j < 4; ++j) {
                    int m = (mt0 + i) * 16 + ((l >> 4) << 2) + j;
                    int p = (nt0 + jn) * 16 + (l & 15);
                    dwrite_frag(Yh, Yl, m, p, acc[i][jn][j]);
                }
    } else {
        if (tid < MM) q[tid] = qmu[tid];
        if (tid + 256 < MM) q[tid + 256] = qmu[tid + 256];
        __syncthreads();
        int mt = (blk - 36) * 4 + w;
        float s = 0.f;
        for (int kt = 0; kt < 12; ++kt) {
            int b = ((mt * 12 + kt) * 64 + l) * 8;
            short8 h8 = *(const short8*)&Xh[b];
            short8 l8 = *(const short8*)&Xl[b];
            int kb = kt * 32 + ((l >> 4) << 3);
#pragma unroll
            for (int j = 0; j < 8; ++j)
                s += (bf2f((u16)h8[j]) + bf2f((u16)l8[j])) * q[kb + j];
        }
        s += __shfl_xor(s, 16);
        s += __shfl_xor(s, 32);
        if (l < 16) cvec[mt * 16 + l] = s;
    }
}

// Launch 9: Bq = Y @ X
__global__ void __launch_bounds__(256) bq_kernel(
    const u16* __restrict__ Yh, const u16* __restrict__ Yl,
    const u16* __restrict__ Xh, const u16* __restrict__ Xl,
    u16* __restrict__ Bh, u16* __restrict__ Bl) {
    int blk = blockIdx.x, tid = threadIdx.x;
    int bi = blk / 6, bj = blk % 6;
    int w = tid >> 6, l = tid & 63;
    floatx4 acc[2][2];
    frag_gemm64(Yh, Yl, Xh, Xl, bi, bj, w, l, acc);
    int mt0 = bi * 4 + 2 * (w & 1), nt0 = bj * 4 + 2 * (w >> 1);
#pragma unroll
    for (int i = 0; i < 2; ++i)
#pragma unroll
        for (int jn = 0; jn < 2; ++jn)
#pragma unroll
            for (int j = 0; j < 4; ++j) {
                int m = (mt0 + i) * 16 + ((l >> 4) << 2) + j;
                int p = (nt0 + jn) * 16 + (l & 15);
                dwrite_frag(Bh, Bl, m, p, acc[i][jn][j]);
            }
}

// ---------------------------------------------------------------------------
// Main fused kernel, 128 points/block, 512 threads, pipelined halves:
// phase2(h0) runs barrier-free alongside phase1(h1) (disjoint kh regions).
__global__ void __launch_bounds__(512) main_kernel(
    const float* __restrict__ Xin,
    const u16* __restrict__ Zfh, const u16* __restrict__ Zfl,
    const float* __restrict__ z2g,
    const u16* __restrict__ Bfh, const u16* __restrict__ Bfl,
    const float* __restrict__ cvec,
    const float* __restrict__ var_p, const float* __restrict__ ls_p,
    float* __restrict__ out) {
    __shared__ u16 kh[12 * 8 * 64 * 8];   // 96 KB: B-frag K tile (hi)
    __shared__ float patch[128 * 36];     // 18 KB
    __shared__ float zsq[MM];
    __shared__ float xsq[128];
    __shared__ float red[1024];

    int tid = threadIdx.x;
    int np0 = blockIdx.x * 128;
    float var = var_p[0];
    float ls = ls_p[0];
    float c2 = -0.72134752044f / (ls * ls);   // -0.5*log2(e)/ls^2

    if (tid < MM) zsq[tid] = z2g[tid];
    for (int e = tid; e < 128 * 36; e += 512) {
        int pt = e / 36, c = e % 36;
        float v = 0.f;
        if (c < 25) {
            int np = np0 + pt;
            int n = np / PP, p = np % PP;
            int oi = p / 36, oj = p % 36;
            v = Xin[n * (HH * WW) + (oi + c / 5) * WW + (oj + c % 5)];
        }
        patch[e] = v;
    }
    __syncthreads();
    if (tid < 128) {
        float s = 0.f;
#pragma unroll
        for (int d = 0; d < LL; ++d) { float x = patch[tid * 36 + d]; s += x * x; }
        xsq[tid] = s;
    }
    __syncthreads();

    int w = tid >> 6, l = tid & 63;
    int u = l >> 4;

    u32 kpk[3][8][2];                     // packed bf16 K values (diag left factor)
    float mp[8] = {0.f, 0.f, 0.f, 0.f, 0.f, 0.f, 0.f, 0.f};

    // ---- half 0: pb read, cross GEMM, finalize ----
    short8 pb0h[4], pb0l[4];
#pragma unroll
    for (int nt = 0; nt < 4; ++nt) {
        int p = nt * 16 + (l & 15);
        int pb = p * 36 + (u << 3);
        float4 f0 = *(const float4*)&patch[pb];
        float4 f1 = *(const float4*)&patch[pb + 4];
        float xv[8] = {f0.x, f0.y, f0.z, f0.w, f1.x, f1.y, f1.z, f1.w};
#pragma unroll
        for (int j = 0; j < 8; ++j) {
            u16 hh, lo;
            split_bf16(xv[j], hh, lo);
            pb0h[nt][j] = (short)hh;
            pb0l[nt][j] = (short)lo;
        }
    }
    {
        floatx4 acc2[3][4];
#pragma unroll
        for (int i = 0; i < 3; ++i) {
            int zt = w * 3 + i;
            short8 zah = *(const short8*)&Zfh[(zt * 64 + l) * 8];
            short8 zal = *(const short8*)&Zfl[(zt * 64 + l) * 8];
#pragma unroll
            for (int nt = 0; nt < 4; ++nt) {
                floatx4 z = {0.f, 0.f, 0.f, 0.f};
                z = __builtin_amdgcn_mfma_f32_16x16x32_bf16(zah, pb0h[nt], z, 0, 0, 0);
                z = __builtin_amdgcn_mfma_f32_16x16x32_bf16(zah, pb0l[nt], z, 0, 0, 0);
                z = __builtin_amdgcn_mfma_f32_16x16x32_bf16(zal, pb0h[nt], z, 0, 0, 0);
                acc2[i][nt] = z;
            }
        }
#pragma unroll
        for (int i = 0; i < 3; ++i) {
            int a2 = w * 3 + i;
            int kt = a2 >> 1;
            int rr = 2 * (a2 & 1) + (u >> 1);
            int k0 = a2 * 16 + 4 * u;
            float4 c4 = *(const float4*)&cvec[k0];
            float cvl[4] = {c4.x, c4.y, c4.z, c4.w};
#pragma unroll
            for (int nt = 0; nt < 4; ++nt) {
                int p = nt * 16 + (l & 15);
                u16 hi[4];
#pragma unroll
                for (int j = 0; j < 4; ++j) {
                    float s = zsq[k0 + j] + xsq[p] - 2.f * acc2[i][nt][j];
                    float v = var * exp2f(s * c2);
                    mp[nt] += cvl[j] * v;
                    hi[j] = f2bf(v);
                }
                u32 p0 = (u32)hi[0] | ((u32)hi[1] << 16);
                u32 p1 = (u32)hi[2] | ((u32)hi[3] << 16);
                int base = ((kt * 8 + nt) * 64 + rr * 16 + (l & 15)) * 8 + 4 * (u & 1);
                *(u32*)&kh[base]     = p0;
                *(u32*)&kh[base + 2] = p1;
                kpk[i][nt][0] = p0;
                kpk[i][nt][1] = p1;
            }
        }
    }
    // prefetch half-1 patch frags (last patch use)
    short8 pb1h[4], pb1l[4];
#pragma unroll
    for (int nt = 0; nt < 4; ++nt) {
        int p = 64 + nt * 16 + (l & 15);
        int pb = p * 36 + (u << 3);
        float4 f0 = *(const float4*)&patch[pb];
        float4 f1 = *(const float4*)&patch[pb + 4];
        float xv[8] = {f0.x, f0.y, f0.z, f0.w, f1.x, f1.y, f1.z, f1.w};
#pragma unroll
        for (int j = 0; j < 8; ++j) {
            u16 hh, lo;
            split_bf16(xv[j], hh, lo);
            pb1h[nt][j] = (short)hh;
            pb1l[nt][j] = (short)lo;
        }
    }
    __syncthreads();   // kh[h0] published

    floatx4 acc[3][8];
#pragma unroll
    for (int i = 0; i < 3; ++i)
#pragma unroll
        for (int nt = 0; nt < 8; ++nt) { floatx4 z = {0.f, 0.f, 0.f, 0.f}; acc[i][nt] = z; }

    // ---- phase 2 on h0 (reads kh ntg 0-3) ----
    for (int kt = 0; kt < 12; ++kt) {
        short8 bh[4];
#pragma unroll
        for (int nt = 0; nt < 4; ++nt)
            bh[nt] = *(const short8*)&kh[((kt * 8 + nt) * 64 + l) * 8];
#pragma unroll
        for (int i = 0; i < 3; ++i) {
            int mt = w * 3 + i;
            int ab = ((mt * 12 + kt) * 64 + l) * 8;
            short8 ah = *(const short8*)&Bfh[ab];
            short8 al = *(const short8*)&Bfl[ab];
#pragma unroll
            for (int nt = 0; nt < 4; ++nt) {
                acc[i][nt] = __builtin_amdgcn_mfma_f32_16x16x32_bf16(ah, bh[nt], acc[i][nt], 0, 0, 0);
                acc[i][nt] = __builtin_amdgcn_mfma_f32_16x16x32_bf16(al, bh[nt], acc[i][nt], 0, 0, 0);
            }
        }
    }

    // ---- phase 1 on h1 (no barrier: writes kh ntg 4-7, disjoint from h0 reads;
    //      waves drift so this VALU overlaps other waves' phase-2 MFMA) ----
    {
        floatx4 acc2[3][4];
#pragma unroll
        for (int i = 0; i < 3; ++i) {
            int zt = w * 3 + i;
            short8 zah = *(const short8*)&Zfh[(zt * 64 + l) * 8];
            short8 zal = *(const short8*)&Zfl[(zt * 64 + l) * 8];
#pragma unroll
            for (int nt = 0; nt < 4; ++nt) {
                floatx4 z = {0.f, 0.f, 0.f, 0.f};
                z = __builtin_amdgcn_mfma_f32_16x16x32_bf16(zah, pb1h[nt], z, 0, 0, 0);
                z = __builtin_amdgcn_mfma_f32_16x16x32_bf16(zah, pb1l[nt], z, 0, 0, 0);
                z = __builtin_amdgcn_mfma_f32_16x16x32_bf16(zal, pb1h[nt], z, 0, 0, 0);
                acc2[i][nt] = z;
            }
        }
#pragma unroll
        for (int i = 0; i < 3; ++i) {
            int a2 = w * 3 + i;
            int kt = a2 >> 1;
            int rr = 2 * (a2 & 1) + (u >> 1);
            int k0 = a2 * 16 + 4 * u;
            float4 c4 = *(const float4*)&cvec[k0];
            float cvl[4] = {c4.x, c4.y, c4.z, c4.w};
#pragma unroll
            for (int nt = 0; nt < 4; ++nt) {
                int ntg = 4 + nt;
                int p = 64 + nt * 16 + (l & 15);
                u16 hi[4];
#pragma unroll
                for (int j = 0; j < 4; ++j) {
                    float s = zsq[k0 + j] + xsq[p] - 2.f * acc2[i][nt][j];
                    float v = var * exp2f(s * c2);
                    mp[ntg] += cvl[j] * v;
                    hi[j] = f2bf(v);
                }
                u32 p0 = (u32)hi[0] | ((u32)hi[1] << 16);
                u32 p1 = (u32)hi[2] | ((u32)hi[3] << 16);
                int base = ((kt * 8 + ntg) * 64 + rr * 16 + (l & 15)) * 8 + 4 * (u & 1);
                *(u32*)&kh[base]     = p0;
                *(u32*)&kh[base + 2] = p1;
                kpk[i][ntg][0] = p0;
                kpk[i][ntg][1] = p1;
            }
        }
    }
    __syncthreads();   // kh[h1] published

    // ---- phase 2 on h1 (reads kh ntg 4-7) ----
    for (int kt = 0; kt < 12; ++kt) {
        short8 bh[4];
#pragma unroll
        for (int nt = 0; nt < 4; ++nt)
            bh[nt] = *(const short8*)&kh[((kt * 8 + 4 + nt) * 64 + l) * 8];
#pragma unroll
        for (int i = 0; i < 3; ++i) {
            int mt = w * 3 + i;
            int ab = ((mt * 12 + kt) * 64 + l) * 8;
            short8 ah = *(const short8*)&Bfh[ab];
            short8 al = *(const short8*)&Bfl[ab];
#pragma unroll
            for (int nt = 0; nt < 4; ++nt) {
                acc[i][4 + nt] = __builtin_amdgcn_mfma_f32_16x16x32_bf16(ah, bh[nt], acc[i][4 + nt], 0, 0, 0);
                acc[i][4 + nt] = __builtin_amdgcn_mfma_f32_16x16x32_bf16(al, bh[nt], acc[i][4 + nt], 0, 0, 0);
            }
        }
    }

    // ---- epilogues ----
    // mean
#pragma unroll
    for (int nt = 0; nt < 8; ++nt) {
        mp[nt] += __shfl_xor(mp[nt], 16);
        mp[nt] += __shfl_xor(mp[nt], 32);
    }
    if (l < 16) {
#pragma unroll
        for (int nt = 0; nt < 8; ++nt) red[w * 128 + nt * 16 + l] = mp[nt];
    }
    __syncthreads();
    if (tid < 128) {
        float s = 0.f;
#pragma unroll
        for (int ww = 0; ww < 8; ++ww) s += red[ww * 128 + tid];
        out[np0 + tid] = s;
    }
    __syncthreads();
    // diag: register dot (identical D-frag maps for kpk and acc)
    float dp[8] = {0.f, 0.f, 0.f, 0.f, 0.f, 0.f, 0.f, 0.f};
#pragma unroll
    for (int i = 0; i < 3; ++i)
#pragma unroll
        for (int nt = 0; nt < 8; ++nt) {
            float kv0 = bf2f((u16)(kpk[i][nt][0] & 0xFFFFu));
            float kv1 = bf2f((u16)(kpk[i][nt][0] >> 16));
            float kv2 = bf2f((u16)(kpk[i][nt][1] & 0xFFFFu));
            float kv3 = bf2f((u16)(kpk[i][nt][1] >> 16));
            dp[nt] += kv0 * acc[i][nt][0] + kv1 * acc[i][nt][1]
                    + kv2 * acc[i][nt][2] + kv3 * acc[i][nt][3];
        }
#pragma unroll
    for (int nt = 0; nt < 8; ++nt) {
        dp[nt] += __shfl_xor(dp[nt], 16);
        dp[nt] += __shfl_xor(dp[nt], 32);
    }
    if (l < 16) {
#pragma unroll
        for (int nt = 0; nt < 8; ++nt) red[w * 128 + nt * 16 + l] = dp[nt];
    }
    __syncthreads();
    if (tid < 128) {
        float s = 0.f;
#pragma unroll
        for (int ww = 0; ww < 8; ++ww) s += red[ww * 128 + tid];
        out[NPTS + np0 + tid] = var + s;
    }
}

// ---------------------------------------------------------------------------
extern "C" void kernel_launch(void* const* d_in, const int* in_sizes, int n_in,
                              void* d_out, int out_size, void* d_ws, size_t ws_size,
                              hipStream_t stream) {
    const float* Xin    = (const float*)d_in[0];
    const float* Z      = (const float*)d_in[1];
    const float* q_mu   = (const float*)d_in[2];
    const float* q_sqrt = (const float*)d_in[3];
    const float* var_p  = (const float*)d_in[4];
    const float* ls_p   = (const float*)d_in[5];
    float* out = (float*)d_out;

    const size_t HB = (size_t)FRAG_N * 2;  // 294912 B per frag half-array
    char* base = (char*)d_ws;
    float* Kuu = (float*)base;                 // 2 HB; Bq frags overlay later
    u16* Bqh = (u16*)base;
    u16* Bql = (u16*)(base + HB);
    u16* Xh_a = (u16*)(base + 2 * HB);         // Kuu frags overlay (used only in ns1)
    u16* Xl_a = (u16*)(base + 3 * HB);
    u16* Kfh = Xh_a;
    u16* Kfl = Xl_a;
    u16* Xh_b = (u16*)(base + 4 * HB);
    u16* Xl_b = (u16*)(base + 5 * HB);
    u16* Rh_a = (u16*)(base + 6 * HB);
    u16* Rl_a = (u16*)(base + 7 * HB);
    u16* Rh_b = (u16*)(base + 8 * HB);
    u16* Rl_b = (u16*)(base + 9 * HB);
    u16* Qh   = (u16*)(base + 10 * HB);        // Q frags; Y overlays later
    u16* Ql   = (u16*)(base + 11 * HB);
    u16* Yh = Qh;
    u16* Yl = Ql;
    u16* SKh  = (u16*)(base + 12 * HB);
    u16* SKl  = (u16*)(base + 13 * HB);
    char* pF = base + 14 * HB;
    u16* Zfh = (u16*)pF;
    u16* Zfl = (u16*)(pF + ZFRAG_N * 2);
    float* z2g  = (float*)(pF + ZFRAG_N * 4);
    float* cvec = z2g + MM;
    float* rsum = cvec + MM;

    // 1) prep: Kuu dense+frags, rowsums, z2, Z frags, Q frags
    prep_kernel<<<MM, 384, 0, stream>>>(Z, q_sqrt, var_p, ls_p, Kuu, rsum, z2g,
                                        Kfh, Kfl, Qh, Ql, Zfh, Zfl);
    // 2) ns1: X1 elementwise | R1 = I-2aK+a^2 K@K | SK = QQ^T - Kuu
    ns1_kernel<<<108, 256, 0, stream>>>(Kuu, rsum, Kfh, Kfl, Qh, Ql,
                                        Xh_b, Xl_b, Rh_b, Rl_b, SKh, SKl);
    // 3-7) NS rounds 2..6 (5 launches; final X lands in b-slots after odd count? 
    //      start b, 5 swaps -> ends in a... track pointers)
    u16 *cxh = Xh_b, *cxl = Xl_b, *nxh = Xh_a, *nxl = Xl_a;
    u16 *crh = Rh_b, *crl = Rl_b, *nrh = Rh_a, *nrl = Rl_a;
    for (int it = 0; it < 5; ++it) {
        ns_kernel<<<72, 256, 0, stream>>>(cxh, cxl, crh, crl, nxh, nxl, nrh, nrl);
        u16* t;
        t = cxh; cxh = nxh; nxh = t;
        t = cxl; cxl = nxl; nxl = t;
        t = crh; crh = nrh; nrh = t;
        t = crl; crl = nrl; nrl = t;
    }
    // 8) Y = X@SK | cvec = X@q_mu
    y_kernel<<<42, 256, 0, stream>>>(cxh, cxl, SKh, SKl, q_mu, Yh, Yl, cvec);
    // 9) Bq = Y@X (into Kuu region)
    bq_kernel<<<36, 256, 0, stream>>>(Yh, Yl, cxh, cxl, Bqh, Bql);
    // 10) main (128 points/block, pipelined)
    main_kernel<<<NPTS / 128, 512, 0, stream>>>(Xin, Zfh, Zfl, z2g, Bqh, Bql, cvec,
                                                var_p, ls_p, out);
}

// Round 10
// 266.449 us; speedup vs baseline: 1.0022x; 1.0022x over previous
//
#include <hip/hip_runtime.h>
#include <hip/hip_bf16.h>

// Problem constants
#define HH 40
#define WW 40
#define KK 5
#define PP 1296            // 36*36
#define LL 25
#define MM 384
#define NN 64
#define NPTS (NN * PP)     // 82944
#define JITTER 1e-6f

typedef unsigned short u16;
typedef unsigned int   u32;
using short8  = __attribute__((ext_vector_type(8))) short;
using floatx4 = __attribute__((ext_vector_type(4))) float;

#define FRAG_N (MM * MM)        // u16 per frag half-array (147456)
#define ZFRAG_N (24 * 64 * 8)   // 12288

// ---------------------------------------------------------------------------
// bf16 split helpers (RNE)
__device__ inline u16 f2bf(float v) {
    u32 b = __float_as_uint(v);
    return (u16)((b + 0x7FFFu + ((b >> 16) & 1u)) >> 16);
}
__device__ inline float bf2f(u16 h) { return __uint_as_float(((u32)h) << 16); }
__device__ inline void split_bf16(float v, u16& hi, u16& lo) {
    hi = f2bf(v);
    lo = f2bf(v - bf2f(hi));
}

// A-fragment linear index (u16 units) for element (m,k), HW-verified rounds 2-8.
__device__ inline int frag_idx(int m, int k) {
    return (((m >> 4) * 12 + (k >> 5)) * 64 + ((m & 15) + (((k >> 3) & 3) << 4))) * 8 + (k & 7);
}

// ---------------------------------------------------------------------------
// Split-bf16 MFMA 64x64-tile GEMM on A-frag operands: C = A . B^T_storage.
__device__ inline void frag_gemm64(const u16* __restrict__ Ah, const u16* __restrict__ Al,
                                   const u16* __restrict__ Bh, const u16* __restrict__ Bl,
                                   int bi, int bj, int w, int l, floatx4 acc[2][2]) {
    int mt0 = bi * 4 + 2 * (w & 1);
    int nt0 = bj * 4 + 2 * (w >> 1);
#pragma unroll
    for (int i = 0; i < 2; ++i)
#pragma unroll
        for (int jn = 0; jn < 2; ++jn) { floatx4 z = {0.f, 0.f, 0.f, 0.f}; acc[i][jn] = z; }
    for (int kt = 0; kt < 12; ++kt) {
        int ab0 = (((mt0 + 0) * 12 + kt) * 64 + l) * 8;
        int ab1 = (((mt0 + 1) * 12 + kt) * 64 + l) * 8;
        int bb0 = (((nt0 + 0) * 12 + kt) * 64 + l) * 8;
        int bb1 = (((nt0 + 1) * 12 + kt) * 64 + l) * 8;
        short8 a0h = *(const short8*)&Ah[ab0];
        short8 a0l = *(const short8*)&Al[ab0];
        short8 a1h = *(const short8*)&Ah[ab1];
        short8 a1l = *(const short8*)&Al[ab1];
        short8 b0h = *(const short8*)&Bh[bb0];
        short8 b0l = *(const short8*)&Bl[bb0];
        short8 b1h = *(const short8*)&Bh[bb1];
        short8 b1l = *(const short8*)&Bl[bb1];
        acc[0][0] = __builtin_amdgcn_mfma_f32_16x16x32_bf16(a0h, b0h, acc[0][0], 0, 0, 0);
        acc[0][0] = __builtin_amdgcn_mfma_f32_16x16x32_bf16(a0h, b0l, acc[0][0], 0, 0, 0);
        acc[0][0] = __builtin_amdgcn_mfma_f32_16x16x32_bf16(a0l, b0h, acc[0][0], 0, 0, 0);
        acc[0][1] = __builtin_amdgcn_mfma_f32_16x16x32_bf16(a0h, b1h, acc[0][1], 0, 0, 0);
        acc[0][1] = __builtin_amdgcn_mfma_f32_16x16x32_bf16(a0h, b1l, acc[0][1], 0, 0, 0);
        acc[0][1] = __builtin_amdgcn_mfma_f32_16x16x32_bf16(a0l, b1h, acc[0][1], 0, 0, 0);
        acc[1][0] = __builtin_amdgcn_mfma_f32_16x16x32_bf16(a1h, b0h, acc[1][0], 0, 0, 0);
        acc[1][0] = __builtin_amdgcn_mfma_f32_16x16x32_bf16(a1h, b0l, acc[1][0], 0, 0, 0);
        acc[1][0] = __builtin_amdgcn_mfma_f32_16x16x32_bf16(a1l, b0h, acc[1][0], 0, 0, 0);
        acc[1][1] = __builtin_amdgcn_mfma_f32_16x16x32_bf16(a1h, b1h, acc[1][1], 0, 0, 0);
        acc[1][1] = __builtin_amdgcn_mfma_f32_16x16x32_bf16(a1h, b1l, acc[1][1], 0, 0, 0);
        acc[1][1] = __builtin_amdgcn_mfma_f32_16x16x32_bf16(a1l, b1h, acc[1][1], 0, 0, 0);
    }
}

__device__ inline void dwrite_frag(u16* __restrict__ Oh, u16* __restrict__ Ol,
                                   int m, int p, float v) {
    int idx = frag_idx(m, p);
    u16 hi, lo;
    split_bf16(v, hi, lo);
    Oh[idx] = hi; Ol[idx] = lo;
}

// ---------------------------------------------------------------------------
// Launch 1: Kuu dense + Kuu frags + rowsums + z2 + Z frags + Q frags.
__global__ void __launch_bounds__(384) prep_kernel(
    const float* __restrict__ Z, const float* __restrict__ q_sqrt,
    const float* __restrict__ var_p, const float* __restrict__ ls_p,
    float* __restrict__ Kuu, float* __restrict__ rsum, float* __restrict__ z2g,
    u16* __restrict__ Kfh, u16* __restrict__ Kfl,
    u16* __restrict__ Qh, u16* __restrict__ Ql,
    u16* __restrict__ Zfh, u16* __restrict__ Zfl) {
    __shared__ float Zs[LL];
    __shared__ float red[384];
    int r = blockIdx.x, tid = threadIdx.x;
    if (tid < LL) Zs[tid] = Z[r * LL + tid];
    __syncthreads();
    float var = var_p[0];
    float ls = ls_p[0];
    float c0 = -0.5f / (ls * ls);
    float s = 0.f;
#pragma unroll
    for (int d = 0; d < LL; ++d) {
        float dd = Zs[d] - Z[tid * LL + d];
        s += dd * dd;
    }
    float v = var * expf(c0 * s);
    if (tid == r) v += JITTER;
    Kuu[r * MM + tid] = v;
    red[tid] = v;
    __syncthreads();
    if (tid < 128) red[tid] += red[tid + 256];
    __syncthreads();
    for (int o = 128; o > 0; o >>= 1) {
        if (tid < o) red[tid] += red[tid + o];
        __syncthreads();
    }
    if (tid == 0) {
        rsum[r] = red[0];
        float t = 0.f;
#pragma unroll
        for (int d = 0; d < LL; ++d) t += Zs[d] * Zs[d];
        z2g[r] = t;
    }
    // frag-order writes: one element per thread (384*384 == FRAG_N)
    {
        int o = r * MM + tid;
        int j = o & 7, ln = (o >> 3) & 63, kt = (o >> 9) % 12, mt = o / 6144;
        int m = mt * 16 + (ln & 15);
        int k = kt * 32 + ((ln >> 4) << 3) + j;
        u16 h, lo;
        // Q frag
        float qv = (k <= m) ? q_sqrt[m * MM + k] : 0.f;
        split_bf16(qv, h, lo);
        Qh[o] = h; Ql[o] = lo;
        // Kuu frag (recompute distance for (m,k))
        float s2 = 0.f;
#pragma unroll
        for (int d = 0; d < LL; ++d) {
            float dd = Z[m * LL + d] - Z[k * LL + d];
            s2 += dd * dd;
        }
        float kv = var * expf(c0 * s2);
        if (m == k) kv += JITTER;
        split_bf16(kv, h, lo);
        Kfh[o] = h; Kfl[o] = lo;
        // Z frag
        if (o < ZFRAG_N) {
            int zt = o >> 9;
            int mz = zt * 16 + (ln & 15);
            int kd = ((ln >> 4) << 3) + j;
            float zv = (kd < LL) ? Z[mz * LL + kd] : 0.f;
            split_bf16(zv, h, lo);
            Zfh[o] = h; Zfl[o] = lo;
        }
    }
}

// ---------------------------------------------------------------------------
// Launch 2: blocks 0-35: X1 = alpha*(2I - alpha*Kuu);
//           36-71: R1 = I - 2a*K + a^2*(K@K)  (K frags from prep);
//           72-107: SK = Q@Q^T - Kuu.
__global__ void __launch_bounds__(256) ns1_kernel(
    const float* __restrict__ Kuu, const float* __restrict__ rsum,
    const u16* __restrict__ Kfh, const u16* __restrict__ Kfl,
    const u16* __restrict__ Qh, const u16* __restrict__ Ql,
    u16* __restrict__ Xh, u16* __restrict__ Xl,
    u16* __restrict__ Rh, u16* __restrict__ Rl,
    u16* __restrict__ SKh, u16* __restrict__ SKl) {
    __shared__ float red[256];
    int tid = threadIdx.x, blk = blockIdx.x;
    int w = tid >> 6, l = tid & 63;
    float alpha = 0.f;
    if (blk < 72) {
        float v0 = rsum[tid];
        if (tid < 128) v0 = fmaxf(v0, rsum[tid + 256]);
        red[tid] = v0;
        __syncthreads();
        for (int o = 128; o > 0; o >>= 1) {
            if (tid < o) red[tid] = fmaxf(red[tid], red[tid + o]);
            __syncthreads();
        }
        alpha = 1.0f / red[0];
    }
    if (blk < 36) {
        float a2 = alpha * alpha;
        for (int o = blk * 256 + tid; o < FRAG_N; o += 36 * 256) {
            int j = o & 7, ln = (o >> 3) & 63, kt = (o >> 9) % 12, mt = o / 6144;
            int m = mt * 16 + (ln & 15);
            int k = kt * 32 + ((ln >> 4) << 3) + j;
            float v = ((m == k) ? 2.f * alpha : 0.f) - a2 * Kuu[m * MM + k];
            u16 h, lo;
            split_bf16(v, h, lo);
            Xh[o] = h; Xl[o] = lo;
        }
    } else if (blk < 72) {
        int tile = blk - 36;
        int bi = tile / 6, bj = tile % 6;
        floatx4 acc[2][2];
        frag_gemm64(Kfh, Kfl, Kfh, Kfl, bi, bj, w, l, acc);   // K @ K
        int mt0 = bi * 4 + 2 * (w & 1), nt0 = bj * 4 + 2 * (w >> 1);
        float a2 = alpha * alpha;
#pragma unroll
        for (int i = 0; i < 2; ++i)
#pragma unroll
            for (int jn = 0; jn < 2; ++jn)
#pragma unroll
                for (int j = 0; j < 4; ++j) {
                    int m = (mt0 + i) * 16 + ((l >> 4) << 2) + j;
                    int p = (nt0 + jn) * 16 + (l & 15);
                    float v = a2 * acc[i][jn][j] - 2.f * alpha * Kuu[m * MM + p]
                            + ((m == p) ? 1.f : 0.f);
                    dwrite_frag(Rh, Rl, m, p, v);
                }
    } else {
        int tile = blk - 72;
        int bi = tile / 6, bj = tile % 6;
        floatx4 acc[2][2];
        frag_gemm64(Qh, Ql, Qh, Ql, bi, bj, w, l, acc);
        int mt0 = bi * 4 + 2 * (w & 1), nt0 = bj * 4 + 2 * (w >> 1);
#pragma unroll
        for (int i = 0; i < 2; ++i)
#pragma unroll
            for (int jn = 0; jn < 2; ++jn)
#pragma unroll
                for (int j = 0; j < 4; ++j) {
                    int m = (mt0 + i) * 16 + ((l >> 4) << 2) + j;
                    int p = (nt0 + jn) * 16 + (l & 15);
                    dwrite_frag(SKh, SKl, m, p, acc[i][jn][j] - Kuu[m * MM + p]);
                }
    }
}

// ---------------------------------------------------------------------------
// NS rounds: blocks 0-35: X' = X + X@R ; 36-71: R' = R@R
__global__ void __launch_bounds__(256) ns_kernel(
    const u16* __restrict__ cxh, const u16* __restrict__ cxl,
    const u16* __restrict__ crh, const u16* __restrict__ crl,
    u16* __restrict__ nxh, u16* __restrict__ nxl,
    u16* __restrict__ nrh, u16* __restrict__ nrl) {
    int blk = blockIdx.x, tid = threadIdx.x;
    bool isX = (blk < 36);
    int tile = isX ? blk : blk - 36;
    int bi = tile / 6, bj = tile % 6;
    int w = tid >> 6, l = tid & 63;
    floatx4 acc[2][2];
    frag_gemm64(isX ? cxh : crh, isX ? cxl : crl, crh, crl, bi, bj, w, l, acc);
    int mt0 = bi * 4 + 2 * (w & 1), nt0 = bj * 4 + 2 * (w >> 1);
    u16* Oh = isX ? nxh : nrh;
    u16* Ol = isX ? nxl : nrl;
#pragma unroll
    for (int i = 0; i < 2; ++i)
#pragma unroll
        for (int jn = 0; jn < 2; ++jn)
#pragma unroll
            for (int j = 0; j < 4; ++j) {
                int m = (mt0 + i) * 16 + ((l >> 4) << 2) + j;
                int p = (nt0 + jn) * 16 + (l & 15);
                float v = acc[i][jn][j];
                if (isX) {
                    int id = frag_idx(m, p);
                    v += bf2f(cxh[id]) + bf2f(cxl[id]);
                }
                dwrite_frag(Oh, Ol, m, p, v);
            }
}

// ---------------------------------------------------------------------------
// Launch 8: blocks 0-35: Y = X @ SK ; blocks 36-41: cvec = X @ q_mu
__global__ void __launch_bounds__(256) y_kernel(
    const u16* __restrict__ Xh, const u16* __restrict__ Xl,
    const u16* __restrict__ SKh, const u16* __restrict__ SKl,
    const float* __restrict__ qmu,
    u16* __restrict__ Yh, u16* __restrict__ Yl, float* __restrict__ cvec) {
    __shared__ float q[MM];
    int tid = threadIdx.x, blk = blockIdx.x;
    int w = tid >> 6, l = tid & 63;
    if (blk < 36) {
        int bi = blk / 6, bj = blk % 6;
        floatx4 acc[2][2];
        frag_gemm64(Xh, Xl, SKh, SKl, bi, bj, w, l, acc);
        int mt0 = bi * 4 + 2 * (w & 1), nt0 = bj * 4 + 2 * (w >> 1);
#pragma unroll
        for (int i = 0; i < 2; ++i)
#pragma unroll
            for (int jn = 0; jn < 2; ++jn)
#pragma unroll
                for (int j = 0; j < 4; ++j) {
                    int m = (mt0 + i) * 16 + ((l >> 4) << 2) + j;
                    int p = (nt0 + jn) * 16 + (l & 15);
                    dwrite_frag(Yh, Yl, m, p, acc[i][jn][j]);
                }
    } else {
        if (tid < MM) q[tid] = qmu[tid];
        if (tid + 256 < MM) q[tid + 256] = qmu[tid + 256];
        __syncthreads();
        int mt = (blk - 36) * 4 + w;
        float s = 0.f;
        for (int kt = 0; kt < 12; ++kt) {
            int b = ((mt * 12 + kt) * 64 + l) * 8;
            short8 h8 = *(const short8*)&Xh[b];
            short8 l8 = *(const short8*)&Xl[b];
            int kb = kt * 32 + ((l >> 4) << 3);
#pragma unroll
            for (int j = 0; j < 8; ++j)
                s += (bf2f((u16)h8[j]) + bf2f((u16)l8[j])) * q[kb + j];
        }
        s += __shfl_xor(s, 16);
        s += __shfl_xor(s, 32);
        if (l < 16) cvec[mt * 16 + l] = s;
    }
}

// Launch 9: Bq = Y @ X
__global__ void __launch_bounds__(256) bq_kernel(
    const u16* __restrict__ Yh, const u16* __restrict__ Yl,
    const u16* __restrict__ Xh, const u16* __restrict__ Xl,
    u16* __restrict__ Bh, u16* __restrict__ Bl) {
    int blk = blockIdx.x, tid = threadIdx.x;
    int bi = blk / 6, bj = blk % 6;
    int w = tid >> 6, l = tid & 63;
    floatx4 acc[2][2];
    frag_gemm64(Yh, Yl, Xh, Xl, bi, bj, w, l, acc);
    int mt0 = bi * 4 + 2 * (w & 1), nt0 = bj * 4 + 2 * (w >> 1);
#pragma unroll
    for (int i = 0; i < 2; ++i)
#pragma unroll
        for (int jn = 0; jn < 2; ++jn)
#pragma unroll
            for (int j = 0; j < 4; ++j) {
                int m = (mt0 + i) * 16 + ((l >> 4) << 2) + j;
                int p = (nt0 + jn) * 16 + (l & 15);
                dwrite_frag(Bh, Bl, m, p, acc[i][jn][j]);
            }
}

// ---------------------------------------------------------------------------
// Main fused kernel, 128 points/block, 512 threads, pipelined halves.
// __launch_bounds__(512, 2): 2 waves/EU min -> 256-VGPR budget, NO spill
// (round 8 spilled at the default 128-VGPR target: 135 MB scratch writes).
__global__ void __launch_bounds__(512, 2) main_kernel(
    const float* __restrict__ Xin,
    const u16* __restrict__ Zfh, const u16* __restrict__ Zfl,
    const float* __restrict__ z2g,
    const u16* __restrict__ Bfh, const u16* __restrict__ Bfl,
    const float* __restrict__ cvec,
    const float* __restrict__ var_p, const float* __restrict__ ls_p,
    float* __restrict__ out) {
    __shared__ u16 kh[12 * 8 * 64 * 8];   // 96 KB: B-frag K tile (hi)
    __shared__ float patch[128 * 36];     // 18 KB
    __shared__ float zsq[MM];
    __shared__ float xsq[128];
    __shared__ float red[1024];

    int tid = threadIdx.x;
    int np0 = blockIdx.x * 128;
    float var = var_p[0];
    float ls = ls_p[0];
    float c2 = -0.72134752044f / (ls * ls);   // -0.5*log2(e)/ls^2

    if (tid < MM) zsq[tid] = z2g[tid];
    for (int e = tid; e < 128 * 36; e += 512) {
        int pt = e / 36, c = e % 36;
        float v = 0.f;
        if (c < 25) {
            int np = np0 + pt;
            int n = np / PP, p = np % PP;
            int oi = p / 36, oj = p % 36;
            v = Xin[n * (HH * WW) + (oi + c / 5) * WW + (oj + c % 5)];
        }
        patch[e] = v;
    }
    __syncthreads();
    if (tid < 128) {
        float s = 0.f;
#pragma unroll
        for (int d = 0; d < LL; ++d) { float x = patch[tid * 36 + d]; s += x * x; }
        xsq[tid] = s;
    }
    __syncthreads();

    int w = tid >> 6, l = tid & 63;
    int u = l >> 4;

    u32 kpk[3][8][2];                     // packed bf16 K values (diag left factor)
    float mp[8] = {0.f, 0.f, 0.f, 0.f, 0.f, 0.f, 0.f, 0.f};

    // ---- half 0: pb read, cross GEMM, finalize ----
    short8 pb0h[4], pb0l[4];
#pragma unroll
    for (int nt = 0; nt < 4; ++nt) {
        int p = nt * 16 + (l & 15);
        int pb = p * 36 + (u << 3);
        float4 f0 = *(const float4*)&patch[pb];
        float4 f1 = *(const float4*)&patch[pb + 4];
        float xv[8] = {f0.x, f0.y, f0.z, f0.w, f1.x, f1.y, f1.z, f1.w};
#pragma unroll
        for (int j = 0; j < 8; ++j) {
            u16 hh, lo;
            split_bf16(xv[j], hh, lo);
            pb0h[nt][j] = (short)hh;
            pb0l[nt][j] = (short)lo;
        }
    }
    {
        floatx4 acc2[3][4];
#pragma unroll
        for (int i = 0; i < 3; ++i) {
            int zt = w * 3 + i;
            short8 zah = *(const short8*)&Zfh[(zt * 64 + l) * 8];
            short8 zal = *(const short8*)&Zfl[(zt * 64 + l) * 8];
#pragma unroll
            for (int nt = 0; nt < 4; ++nt) {
                floatx4 z = {0.f, 0.f, 0.f, 0.f};
                z = __builtin_amdgcn_mfma_f32_16x16x32_bf16(zah, pb0h[nt], z, 0, 0, 0);
                z = __builtin_amdgcn_mfma_f32_16x16x32_bf16(zah, pb0l[nt], z, 0, 0, 0);
                z = __builtin_amdgcn_mfma_f32_16x16x32_bf16(zal, pb0h[nt], z, 0, 0, 0);
                acc2[i][nt] = z;
            }
        }
#pragma unroll
        for (int i = 0; i < 3; ++i) {
            int a2 = w * 3 + i;
            int kt = a2 >> 1;
            int rr = 2 * (a2 & 1) + (u >> 1);
            int k0 = a2 * 16 + 4 * u;
            float4 c4 = *(const float4*)&cvec[k0];
            float cvl[4] = {c4.x, c4.y, c4.z, c4.w};
#pragma unroll
            for (int nt = 0; nt < 4; ++nt) {
                int p = nt * 16 + (l & 15);
                u16 hi[4];
#pragma unroll
                for (int j = 0; j < 4; ++j) {
                    float s = zsq[k0 + j] + xsq[p] - 2.f * acc2[i][nt][j];
                    float v = var * exp2f(s * c2);
                    mp[nt] += cvl[j] * v;
                    hi[j] = f2bf(v);
                }
                u32 p0 = (u32)hi[0] | ((u32)hi[1] << 16);
                u32 p1 = (u32)hi[2] | ((u32)hi[3] << 16);
                int base = ((kt * 8 + nt) * 64 + rr * 16 + (l & 15)) * 8 + 4 * (u & 1);
                *(u32*)&kh[base]     = p0;
                *(u32*)&kh[base + 2] = p1;
                kpk[i][nt][0] = p0;
                kpk[i][nt][1] = p1;
            }
        }
    }
    // prefetch half-1 patch frags (last patch use)
    short8 pb1h[4], pb1l[4];
#pragma unroll
    for (int nt = 0; nt < 4; ++nt) {
        int p = 64 + nt * 16 + (l & 15);
        int pb = p * 36 + (u << 3);
        float4 f0 = *(const float4*)&patch[pb];
        float4 f1 = *(const float4*)&patch[pb + 4];
        float xv[8] = {f0.x, f0.y, f0.z, f0.w, f1.x, f1.y, f1.z, f1.w};
#pragma unroll
        for (int j = 0; j < 8; ++j) {
            u16 hh, lo;
            split_bf16(xv[j], hh, lo);
            pb1h[nt][j] = (short)hh;
            pb1l[nt][j] = (short)lo;
        }
    }
    __syncthreads();   // kh[h0] published

    floatx4 acc[3][8];
#pragma unroll
    for (int i = 0; i < 3; ++i)
#pragma unroll
        for (int nt = 0; nt < 8; ++nt) { floatx4 z = {0.f, 0.f, 0.f, 0.f}; acc[i][nt] = z; }

    // ---- phase 2 on h0 (reads kh ntg 0-3) ----
    for (int kt = 0; kt < 12; ++kt) {
        short8 bh[4];
#pragma unroll
        for (int nt = 0; nt < 4; ++nt)
            bh[nt] = *(const short8*)&kh[((kt * 8 + nt) * 64 + l) * 8];
#pragma unroll
        for (int i = 0; i < 3; ++i) {
            int mt = w * 3 + i;
            int ab = ((mt * 12 + kt) * 64 + l) * 8;
            short8 ah = *(const short8*)&Bfh[ab];
            short8 al = *(const short8*)&Bfl[ab];
#pragma unroll
            for (int nt = 0; nt < 4; ++nt) {
                acc[i][nt] = __builtin_amdgcn_mfma_f32_16x16x32_bf16(ah, bh[nt], acc[i][nt], 0, 0, 0);
                acc[i][nt] = __builtin_amdgcn_mfma_f32_16x16x32_bf16(al, bh[nt], acc[i][nt], 0, 0, 0);
            }
        }
    }

    // ---- phase 1 on h1 (no barrier: writes kh ntg 4-7, disjoint from h0 reads;
    //      waves drift so this VALU overlaps other waves' phase-2 MFMA) ----
    {
        floatx4 acc2[3][4];
#pragma unroll
        for (int i = 0; i < 3; ++i) {
            int zt = w * 3 + i;
            short8 zah = *(const short8*)&Zfh[(zt * 64 + l) * 8];
            short8 zal = *(const short8*)&Zfl[(zt * 64 + l) * 8];
#pragma unroll
            for (int nt = 0; nt < 4; ++nt) {
                floatx4 z = {0.f, 0.f, 0.f, 0.f};
                z = __builtin_amdgcn_mfma_f32_16x16x32_bf16(zah, pb1h[nt], z, 0, 0, 0);
                z = __builtin_amdgcn_mfma_f32_16x16x32_bf16(zah, pb1l[nt], z, 0, 0, 0);
                z = __builtin_amdgcn_mfma_f32_16x16x32_bf16(zal, pb1h[nt], z, 0, 0, 0);
                acc2[i][nt] = z;
            }
        }
#pragma unroll
        for (int i = 0; i < 3; ++i) {
            int a2 = w * 3 + i;
            int kt = a2 >> 1;
            int rr = 2 * (a2 & 1) + (u >> 1);
            int k0 = a2 * 16 + 4 * u;
            float4 c4 = *(const float4*)&cvec[k0];
            float cvl[4] = {c4.x, c4.y, c4.z, c4.w};
#pragma unroll
            for (int nt = 0; nt < 4; ++nt) {
                int ntg = 4 + nt;
                int p = 64 + nt * 16 + (l & 15);
                u16 hi[4];
#pragma unroll
                for (int j = 0; j < 4; ++j) {
                    float s = zsq[k0 + j] + xsq[p] - 2.f * acc2[i][nt][j];
                    float v = var * exp2f(s * c2);
                    mp[ntg] += cvl[j] * v;
                    hi[j] = f2bf(v);
                }
                u32 p0 = (u32)hi[0] | ((u32)hi[1] << 16);
                u32 p1 = (u32)hi[2] | ((u32)hi[3] << 16);
                int base = ((kt * 8 + ntg) * 64 + rr * 16 + (l & 15)) * 8 + 4 * (u & 1);
                *(u32*)&kh[base]     = p0;
                *(u32*)&kh[base + 2] = p1;
                kpk[i][ntg][0] = p0;
                kpk[i][ntg][1] = p1;
            }
        }
    }
    __syncthreads();   // kh[h1] published

    // ---- phase 2 on h1 (reads kh ntg 4-7) ----
    for (int kt = 0; kt < 12; ++kt) {
        short8 bh[4];
#pragma unroll
        for (int nt = 0; nt < 4; ++nt)
            bh[nt] = *(const short8*)&kh[((kt * 8 + 4 + nt) * 64 + l) * 8];
#pragma unroll
        for (int i = 0; i < 3; ++i) {
            int mt = w * 3 + i;
            int ab = ((mt * 12 + kt) * 64 + l) * 8;
            short8 ah = *(const short8*)&Bfh[ab];
            short8 al = *(const short8*)&Bfl[ab];
#pragma unroll
            for (int nt = 0; nt < 4; ++nt) {
                acc[i][4 + nt] = __builtin_amdgcn_mfma_f32_16x16x32_bf16(ah, bh[nt], acc[i][4 + nt], 0, 0, 0);
                acc[i][4 + nt] = __builtin_amdgcn_mfma_f32_16x16x32_bf16(al, bh[nt], acc[i][4 + nt], 0, 0, 0);
            }
        }
    }

    // ---- epilogues ----
    // mean
#pragma unroll
    for (int nt = 0; nt < 8; ++nt) {
        mp[nt] += __shfl_xor(mp[nt], 16);
        mp[nt] += __shfl_xor(mp[nt], 32);
    }
    if (l < 16) {
#pragma unroll
        for (int nt = 0; nt < 8; ++nt) red[w * 128 + nt * 16 + l] = mp[nt];
    }
    __syncthreads();
    if (tid < 128) {
        float s = 0.f;
#pragma unroll
        for (int ww = 0; ww < 8; ++ww) s += red[ww * 128 + tid];
        out[np0 + tid] = s;
    }
    __syncthreads();
    // diag: register dot (identical D-frag maps for kpk and acc)
    float dp[8] = {0.f, 0.f, 0.f, 0.f, 0.f, 0.f, 0.f, 0.f};
#pragma unroll
    for (int i = 0; i < 3; ++i)
#pragma unroll
        for (int nt = 0; nt < 8; ++nt) {
            float kv0 = bf2f((u16)(kpk[i][nt][0] & 0xFFFFu));
            float kv1 = bf2f((u16)(kpk[i][nt][0] >> 16));
            float kv2 = bf2f((u16)(kpk[i][nt][1] & 0xFFFFu));
            float kv3 = bf2f((u16)(kpk[i][nt][1] >> 16));
            dp[nt] += kv0 * acc[i][nt][0] + kv1 * acc[i][nt][1]
                    + kv2 * acc[i][nt][2] + kv3 * acc[i][nt][3];
        }
#pragma unroll
    for (int nt = 0; nt < 8; ++nt) {
        dp[nt] += __shfl_xor(dp[nt], 16);
        dp[nt] += __shfl_xor(dp[nt], 32);
    }
    if (l < 16) {
#pragma unroll
        for (int nt = 0; nt < 8; ++nt) red[w * 128 + nt * 16 + l] = dp[nt];
    }
    __syncthreads();
    if (tid < 128) {
        float s = 0.f;
#pragma unroll
        for (int ww = 0; ww < 8; ++ww) s += red[ww * 128 + tid];
        out[NPTS + np0 + tid] = var + s;
    }
}

// ---------------------------------------------------------------------------
extern "C" void kernel_launch(void* const* d_in, const int* in_sizes, int n_in,
                              void* d_out, int out_size, void* d_ws, size_t ws_size,
                              hipStream_t stream) {
    const float* Xin    = (const float*)d_in[0];
    const float* Z      = (const float*)d_in[1];
    const float* q_mu   = (const float*)d_in[2];
    const float* q_sqrt = (const float*)d_in[3];
    const float* var_p  = (const float*)d_in[4];
    const float* ls_p   = (const float*)d_in[5];
    float* out = (float*)d_out;

    const size_t HB = (size_t)FRAG_N * 2;  // 294912 B per frag half-array
    char* base = (char*)d_ws;
    float* Kuu = (float*)base;                 // 2 HB; Bq frags overlay later
    u16* Bqh = (u16*)base;
    u16* Bql = (u16*)(base + HB);
    u16* Xh_a = (u16*)(base + 2 * HB);         // Kuu frags overlay (used only in ns1)
    u16* Xl_a = (u16*)(base + 3 * HB);
    u16* Kfh = Xh_a;
    u16* Kfl = Xl_a;
    u16* Xh_b = (u16*)(base + 4 * HB);
    u16* Xl_b = (u16*)(base + 5 * HB);
    u16* Rh_a = (u16*)(base + 6 * HB);
    u16* Rl_a = (u16*)(base + 7 * HB);
    u16* Rh_b = (u16*)(base + 8 * HB);
    u16* Rl_b = (u16*)(base + 9 * HB);
    u16* Qh   = (u16*)(base + 10 * HB);        // Q frags; Y overlays later
    u16* Ql   = (u16*)(base + 11 * HB);
    u16* Yh = Qh;
    u16* Yl = Ql;
    u16* SKh  = (u16*)(base + 12 * HB);
    u16* SKl  = (u16*)(base + 13 * HB);
    char* pF = base + 14 * HB;
    u16* Zfh = (u16*)pF;
    u16* Zfl = (u16*)(pF + ZFRAG_N * 2);
    float* z2g  = (float*)(pF + ZFRAG_N * 4);
    float* cvec = z2g + MM;
    float* rsum = cvec + MM;

    // 1) prep: Kuu dense+frags, rowsums, z2, Z frags, Q frags
    prep_kernel<<<MM, 384, 0, stream>>>(Z, q_sqrt, var_p, ls_p, Kuu, rsum, z2g,
                                        Kfh, Kfl, Qh, Ql, Zfh, Zfl);
    // 2) ns1: X1 elementwise | R1 = I-2aK+a^2 K@K | SK = QQ^T - Kuu
    ns1_kernel<<<108, 256, 0, stream>>>(Kuu, rsum, Kfh, Kfl, Qh, Ql,
                                        Xh_b, Xl_b, Rh_b, Rl_b, SKh, SKl);
    // 3-7) NS rounds 2..6 (5 launches -> 6 total NS iterations; 5 total FAILED
    //      at absmax 0.049 in round 9 — 6 is the verified convergence point)
    u16 *cxh = Xh_b, *cxl = Xl_b, *nxh = Xh_a, *nxl = Xl_a;
    u16 *crh = Rh_b, *crl = Rl_b, *nrh = Rh_a, *nrl = Rl_a;
    for (int it = 0; it < 5; ++it) {
        ns_kernel<<<72, 256, 0, stream>>>(cxh, cxl, crh, crl, nxh, nxl, nrh, nrl);
        u16* t;
        t = cxh; cxh = nxh; nxh = t;
        t = cxl; cxl = nxl; nxl = t;
        t = crh; crh = nrh; nrh = t;
        t = crl; crl = nrl; nrl = t;
    }
    // 8) Y = X@SK | cvec = X@q_mu
    y_kernel<<<42, 256, 0, stream>>>(cxh, cxl, SKh, SKl, q_mu, Yh, Yl, cvec);
    // 9) Bq = Y@X (into Kuu region)
    bq_kernel<<<36, 256, 0, stream>>>(Yh, Yl, cxh, cxl, Bqh, Bql);
    // 10) main (128 points/block, pipelined, 256-VGPR budget)
    main_kernel<<<NPTS / 128, 512, 0, stream>>>(Xin, Zfh, Zfl, z2g, Bqh, Bql, cvec,
                                                var_p, ls_p, out);
}

// Round 11
// 206.858 us; speedup vs baseline: 1.2910x; 1.2881x over previous
//
#include <hip/hip_runtime.h>
#include <hip/hip_bf16.h>

// Problem constants
#define HH 40
#define WW 40
#define KK 5
#define PP 1296            // 36*36
#define LL 25
#define MM 384
#define NN 64
#define NPTS (NN * PP)     // 82944
#define JITTER 1e-6f

typedef unsigned short u16;
typedef unsigned int   u32;
using short8  = __attribute__((ext_vector_type(8))) short;
using floatx4 = __attribute__((ext_vector_type(4))) float;

#define FRAG_N (MM * MM)        // u16 per frag half-array (147456)
#define ZFRAG_N (24 * 64 * 8)   // 12288

// ---------------------------------------------------------------------------
// bf16 split helpers (RNE)
__device__ inline u16 f2bf(float v) {
    u32 b = __float_as_uint(v);
    return (u16)((b + 0x7FFFu + ((b >> 16) & 1u)) >> 16);
}
__device__ inline float bf2f(u16 h) { return __uint_as_float(((u32)h) << 16); }
__device__ inline void split_bf16(float v, u16& hi, u16& lo) {
    hi = f2bf(v);
    lo = f2bf(v - bf2f(hi));
}

// A-fragment linear index (u16 units) for element (m,k), HW-verified rounds 2-10.
__device__ inline int frag_idx(int m, int k) {
    return (((m >> 4) * 12 + (k >> 5)) * 64 + ((m & 15) + (((k >> 3) & 3) << 4))) * 8 + (k & 7);
}

// ---------------------------------------------------------------------------
// Split-bf16 MFMA 64x64-tile GEMM on A-frag operands: C = A . B^T_storage.
__device__ inline void frag_gemm64(const u16* __restrict__ Ah, const u16* __restrict__ Al,
                                   const u16* __restrict__ Bh, const u16* __restrict__ Bl,
                                   int bi, int bj, int w, int l, floatx4 acc[2][2]) {
    int mt0 = bi * 4 + 2 * (w & 1);
    int nt0 = bj * 4 + 2 * (w >> 1);
#pragma unroll
    for (int i = 0; i < 2; ++i)
#pragma unroll
        for (int jn = 0; jn < 2; ++jn) { floatx4 z = {0.f, 0.f, 0.f, 0.f}; acc[i][jn] = z; }
    for (int kt = 0; kt < 12; ++kt) {
        int ab0 = (((mt0 + 0) * 12 + kt) * 64 + l) * 8;
        int ab1 = (((mt0 + 1) * 12 + kt) * 64 + l) * 8;
        int bb0 = (((nt0 + 0) * 12 + kt) * 64 + l) * 8;
        int bb1 = (((nt0 + 1) * 12 + kt) * 64 + l) * 8;
        short8 a0h = *(const short8*)&Ah[ab0];
        short8 a0l = *(const short8*)&Al[ab0];
        short8 a1h = *(const short8*)&Ah[ab1];
        short8 a1l = *(const short8*)&Al[ab1];
        short8 b0h = *(const short8*)&Bh[bb0];
        short8 b0l = *(const short8*)&Bl[bb0];
        short8 b1h = *(const short8*)&Bh[bb1];
        short8 b1l = *(const short8*)&Bl[bb1];
        acc[0][0] = __builtin_amdgcn_mfma_f32_16x16x32_bf16(a0h, b0h, acc[0][0], 0, 0, 0);
        acc[0][0] = __builtin_amdgcn_mfma_f32_16x16x32_bf16(a0h, b0l, acc[0][0], 0, 0, 0);
        acc[0][0] = __builtin_amdgcn_mfma_f32_16x16x32_bf16(a0l, b0h, acc[0][0], 0, 0, 0);
        acc[0][1] = __builtin_amdgcn_mfma_f32_16x16x32_bf16(a0h, b1h, acc[0][1], 0, 0, 0);
        acc[0][1] = __builtin_amdgcn_mfma_f32_16x16x32_bf16(a0h, b1l, acc[0][1], 0, 0, 0);
        acc[0][1] = __builtin_amdgcn_mfma_f32_16x16x32_bf16(a0l, b1h, acc[0][1], 0, 0, 0);
        acc[1][0] = __builtin_amdgcn_mfma_f32_16x16x32_bf16(a1h, b0h, acc[1][0], 0, 0, 0);
        acc[1][0] = __builtin_amdgcn_mfma_f32_16x16x32_bf16(a1h, b0l, acc[1][0], 0, 0, 0);
        acc[1][0] = __builtin_amdgcn_mfma_f32_16x16x32_bf16(a1l, b0h, acc[1][0], 0, 0, 0);
        acc[1][1] = __builtin_amdgcn_mfma_f32_16x16x32_bf16(a1h, b1h, acc[1][1], 0, 0, 0);
        acc[1][1] = __builtin_amdgcn_mfma_f32_16x16x32_bf16(a1h, b1l, acc[1][1], 0, 0, 0);
        acc[1][1] = __builtin_amdgcn_mfma_f32_16x16x32_bf16(a1l, b1h, acc[1][1], 0, 0, 0);
    }
}

__device__ inline void dwrite_frag(u16* __restrict__ Oh, u16* __restrict__ Ol,
                                   int m, int p, float v) {
    int idx = frag_idx(m, p);
    u16 hi, lo;
    split_bf16(v, hi, lo);
    Oh[idx] = hi; Ol[idx] = lo;
}

// ---------------------------------------------------------------------------
// Launch 1: Kuu dense + Kuu frags + rowsums + z2 + Z frags + Q frags.
__global__ void __launch_bounds__(384) prep_kernel(
    const float* __restrict__ Z, const float* __restrict__ q_sqrt,
    const float* __restrict__ var_p, const float* __restrict__ ls_p,
    float* __restrict__ Kuu, float* __restrict__ rsum, float* __restrict__ z2g,
    u16* __restrict__ Kfh, u16* __restrict__ Kfl,
    u16* __restrict__ Qh, u16* __restrict__ Ql,
    u16* __restrict__ Zfh, u16* __restrict__ Zfl) {
    __shared__ float Zs[LL];
    __shared__ float red[384];
    int r = blockIdx.x, tid = threadIdx.x;
    if (tid < LL) Zs[tid] = Z[r * LL + tid];
    __syncthreads();
    float var = var_p[0];
    float ls = ls_p[0];
    float c0 = -0.5f / (ls * ls);
    float s = 0.f;
#pragma unroll
    for (int d = 0; d < LL; ++d) {
        float dd = Zs[d] - Z[tid * LL + d];
        s += dd * dd;
    }
    float v = var * expf(c0 * s);
    if (tid == r) v += JITTER;
    Kuu[r * MM + tid] = v;
    red[tid] = v;
    __syncthreads();
    if (tid < 128) red[tid] += red[tid + 256];
    __syncthreads();
    for (int o = 128; o > 0; o >>= 1) {
        if (tid < o) red[tid] += red[tid + o];
        __syncthreads();
    }
    if (tid == 0) {
        rsum[r] = red[0];
        float t = 0.f;
#pragma unroll
        for (int d = 0; d < LL; ++d) t += Zs[d] * Zs[d];
        z2g[r] = t;
    }
    // frag-order writes: one element per thread (384*384 == FRAG_N)
    {
        int o = r * MM + tid;
        int j = o & 7, ln = (o >> 3) & 63, kt = (o >> 9) % 12, mt = o / 6144;
        int m = mt * 16 + (ln & 15);
        int k = kt * 32 + ((ln >> 4) << 3) + j;
        u16 h, lo;
        // Q frag
        float qv = (k <= m) ? q_sqrt[m * MM + k] : 0.f;
        split_bf16(qv, h, lo);
        Qh[o] = h; Ql[o] = lo;
        // Kuu frag (recompute distance for (m,k))
        float s2 = 0.f;
#pragma unroll
        for (int d = 0; d < LL; ++d) {
            float dd = Z[m * LL + d] - Z[k * LL + d];
            s2 += dd * dd;
        }
        float kv = var * expf(c0 * s2);
        if (m == k) kv += JITTER;
        split_bf16(kv, h, lo);
        Kfh[o] = h; Kfl[o] = lo;
        // Z frag
        if (o < ZFRAG_N) {
            int zt = o >> 9;
            int mz = zt * 16 + (ln & 15);
            int kd = ((ln >> 4) << 3) + j;
            float zv = (kd < LL) ? Z[mz * LL + kd] : 0.f;
            split_bf16(zv, h, lo);
            Zfh[o] = h; Zfl[o] = lo;
        }
    }
}

// ---------------------------------------------------------------------------
// Launch 2: blocks 0-35: X1 = alpha*(2I - alpha*Kuu);
//           36-71: R1 = I - 2a*K + a^2*(K@K)  (K frags from prep);
//           72-107: SK = Q@Q^T - Kuu.
__global__ void __launch_bounds__(256) ns1_kernel(
    const float* __restrict__ Kuu, const float* __restrict__ rsum,
    const u16* __restrict__ Kfh, const u16* __restrict__ Kfl,
    const u16* __restrict__ Qh, const u16* __restrict__ Ql,
    u16* __restrict__ Xh, u16* __restrict__ Xl,
    u16* __restrict__ Rh, u16* __restrict__ Rl,
    u16* __restrict__ SKh, u16* __restrict__ SKl) {
    __shared__ float red[256];
    int tid = threadIdx.x, blk = blockIdx.x;
    int w = tid >> 6, l = tid & 63;
    float alpha = 0.f;
    if (blk < 72) {
        float v0 = rsum[tid];
        if (tid < 128) v0 = fmaxf(v0, rsum[tid + 256]);
        red[tid] = v0;
        __syncthreads();
        for (int o = 128; o > 0; o >>= 1) {
            if (tid < o) red[tid] = fmaxf(red[tid], red[tid + o]);
            __syncthreads();
        }
        alpha = 1.0f / red[0];
    }
    if (blk < 36) {
        float a2 = alpha * alpha;
        for (int o = blk * 256 + tid; o < FRAG_N; o += 36 * 256) {
            int j = o & 7, ln = (o >> 3) & 63, kt = (o >> 9) % 12, mt = o / 6144;
            int m = mt * 16 + (ln & 15);
            int k = kt * 32 + ((ln >> 4) << 3) + j;
            float v = ((m == k) ? 2.f * alpha : 0.f) - a2 * Kuu[m * MM + k];
            u16 h, lo;
            split_bf16(v, h, lo);
            Xh[o] = h; Xl[o] = lo;
        }
    } else if (blk < 72) {
        int tile = blk - 36;
        int bi = tile / 6, bj = tile % 6;
        floatx4 acc[2][2];
        frag_gemm64(Kfh, Kfl, Kfh, Kfl, bi, bj, w, l, acc);   // K @ K
        int mt0 = bi * 4 + 2 * (w & 1), nt0 = bj * 4 + 2 * (w >> 1);
        float a2 = alpha * alpha;
#pragma unroll
        for (int i = 0; i < 2; ++i)
#pragma unroll
            for (int jn = 0; jn < 2; ++jn)
#pragma unroll
                for (int j = 0; j < 4; ++j) {
                    int m = (mt0 + i) * 16 + ((l >> 4) << 2) + j;
                    int p = (nt0 + jn) * 16 + (l & 15);
                    float v = a2 * acc[i][jn][j] - 2.f * alpha * Kuu[m * MM + p]
                            + ((m == p) ? 1.f : 0.f);
                    dwrite_frag(Rh, Rl, m, p, v);
                }
    } else {
        int tile = blk - 72;
        int bi = tile / 6, bj = tile % 6;
        floatx4 acc[2][2];
        frag_gemm64(Qh, Ql, Qh, Ql, bi, bj, w, l, acc);
        int mt0 = bi * 4 + 2 * (w & 1), nt0 = bj * 4 + 2 * (w >> 1);
#pragma unroll
        for (int i = 0; i < 2; ++i)
#pragma unroll
            for (int jn = 0; jn < 2; ++jn)
#pragma unroll
                for (int j = 0; j < 4; ++j) {
                    int m = (mt0 + i) * 16 + ((l >> 4) << 2) + j;
                    int p = (nt0 + jn) * 16 + (l & 15);
                    dwrite_frag(SKh, SKl, m, p, acc[i][jn][j] - Kuu[m * MM + p]);
                }
    }
}

// ---------------------------------------------------------------------------
// NS rounds: blocks 0-35: X' = X + X@R ; 36-71: R' = R@R
__global__ void __launch_bounds__(256) ns_kernel(
    const u16* __restrict__ cxh, const u16* __restrict__ cxl,
    const u16* __restrict__ crh, const u16* __restrict__ crl,
    u16* __restrict__ nxh, u16* __restrict__ nxl,
    u16* __restrict__ nrh, u16* __restrict__ nrl) {
    int blk = blockIdx.x, tid = threadIdx.x;
    bool isX = (blk < 36);
    int tile = isX ? blk : blk - 36;
    int bi = tile / 6, bj = tile % 6;
    int w = tid >> 6, l = tid & 63;
    floatx4 acc[2][2];
    frag_gemm64(isX ? cxh : crh, isX ? cxl : crl, crh, crl, bi, bj, w, l, acc);
    int mt0 = bi * 4 + 2 * (w & 1), nt0 = bj * 4 + 2 * (w >> 1);
    u16* Oh = isX ? nxh : nrh;
    u16* Ol = isX ? nxl : nrl;
#pragma unroll
    for (int i = 0; i < 2; ++i)
#pragma unroll
        for (int jn = 0; jn < 2; ++jn)
#pragma unroll
            for (int j = 0; j < 4; ++j) {
                int m = (mt0 + i) * 16 + ((l >> 4) << 2) + j;
                int p = (nt0 + jn) * 16 + (l & 15);
                float v = acc[i][jn][j];
                if (isX) {
                    int id = frag_idx(m, p);
                    v += bf2f(cxh[id]) + bf2f(cxl[id]);
                }
                dwrite_frag(Oh, Ol, m, p, v);
            }
}

// ---------------------------------------------------------------------------
// Launch 8: blocks 0-35: Y = X @ SK ; blocks 36-41: cvec = X @ q_mu
__global__ void __launch_bounds__(256) y_kernel(
    const u16* __restrict__ Xh, const u16* __restrict__ Xl,
    const u16* __restrict__ SKh, const u16* __restrict__ SKl,
    const float* __restrict__ qmu,
    u16* __restrict__ Yh, u16* __restrict__ Yl, float* __restrict__ cvec) {
    __shared__ float q[MM];
    int tid = threadIdx.x, blk = blockIdx.x;
    int w = tid >> 6, l = tid & 63;
    if (blk < 36) {
        int bi = blk / 6, bj = blk % 6;
        floatx4 acc[2][2];
        frag_gemm64(Xh, Xl, SKh, SKl, bi, bj, w, l, acc);
        int mt0 = bi * 4 + 2 * (w & 1), nt0 = bj * 4 + 2 * (w >> 1);
#pragma unroll
        for (int i = 0; i < 2; ++i)
#pragma unroll
            for (int jn = 0; jn < 2; ++jn)
#pragma unroll
                for (int j = 0; j < 4; ++j) {
                    int m = (mt0 + i) * 16 + ((l >> 4) << 2) + j;
                    int p = (nt0 + jn) * 16 + (l & 15);
                    dwrite_frag(Yh, Yl, m, p, acc[i][jn][j]);
                }
    } else {
        if (tid < MM) q[tid] = qmu[tid];
        if (tid + 256 < MM) q[tid + 256] = qmu[tid + 256];
        __syncthreads();
        int mt = (blk - 36) * 4 + w;
        float s = 0.f;
        for (int kt = 0; kt < 12; ++kt) {
            int b = ((mt * 12 + kt) * 64 + l) * 8;
            short8 h8 = *(const short8*)&Xh[b];
            short8 l8 = *(const short8*)&Xl[b];
            int kb = kt * 32 + ((l >> 4) << 3);
#pragma unroll
            for (int j = 0; j < 8; ++j)
                s += (bf2f((u16)h8[j]) + bf2f((u16)l8[j])) * q[kb + j];
        }
        s += __shfl_xor(s, 16);
        s += __shfl_xor(s, 32);
        if (l < 16) cvec[mt * 16 + l] = s;
    }
}

// Launch 9: Bq = Y @ X
__global__ void __launch_bounds__(256) bq_kernel(
    const u16* __restrict__ Yh, const u16* __restrict__ Yl,
    const u16* __restrict__ Xh, const u16* __restrict__ Xl,
    u16* __restrict__ Bh, u16* __restrict__ Bl) {
    int blk = blockIdx.x, tid = threadIdx.x;
    int bi = blk / 6, bj = blk % 6;
    int w = tid >> 6, l = tid & 63;
    floatx4 acc[2][2];
    frag_gemm64(Yh, Yl, Xh, Xl, bi, bj, w, l, acc);
    int mt0 = bi * 4 + 2 * (w & 1), nt0 = bj * 4 + 2 * (w >> 1);
#pragma unroll
    for (int i = 0; i < 2; ++i)
#pragma unroll
        for (int jn = 0; jn < 2; ++jn)
#pragma unroll
            for (int j = 0; j < 4; ++j) {
                int m = (mt0 + i) * 16 + ((l >> 4) << 2) + j;
                int p = (nt0 + jn) * 16 + (l & 15);
                dwrite_frag(Bh, Bl, m, p, acc[i][jn][j]);
            }
}

// ---------------------------------------------------------------------------
// Main fused kernel, 128 points/block, 512 threads, pipelined halves with
// LOW register pressure: per-half kpk (24 regs), per-half acc (48 AGPR, dies
// after the half's diag dot), no pb prefetch (patch persists in its own LDS).
// Rounds 8/10 spilled (135 MB scratch) because kpk[48]+acc[96]+pb1[32] were
// live simultaneously against the unified VGPR/AGPR budget; this fits 128.
__global__ void __launch_bounds__(512) main_kernel(
    const float* __restrict__ Xin,
    const u16* __restrict__ Zfh, const u16* __restrict__ Zfl,
    const float* __restrict__ z2g,
    const u16* __restrict__ Bfh, const u16* __restrict__ Bfl,
    const float* __restrict__ cvec,
    const float* __restrict__ var_p, const float* __restrict__ ls_p,
    float* __restrict__ out) {
    __shared__ u16 kh[12 * 8 * 64 * 8];   // 96 KB: B-frag K tile (hi)
    __shared__ float patch[128 * 36];     // 18 KB (persists whole kernel)
    __shared__ float zsq[MM];
    __shared__ float xsq[128];
    __shared__ float red[1024];

    int tid = threadIdx.x;
    int np0 = blockIdx.x * 128;
    float var = var_p[0];
    float ls = ls_p[0];
    float c2 = -0.72134752044f / (ls * ls);   // -0.5*log2(e)/ls^2

    if (tid < MM) zsq[tid] = z2g[tid];
    for (int e = tid; e < 128 * 36; e += 512) {
        int pt = e / 36, c = e % 36;
        float v = 0.f;
        if (c < 25) {
            int np = np0 + pt;
            int n = np / PP, p = np % PP;
            int oi = p / 36, oj = p % 36;
            v = Xin[n * (HH * WW) + (oi + c / 5) * WW + (oj + c % 5)];
        }
        patch[e] = v;
    }
    __syncthreads();
    if (tid < 128) {
        float s = 0.f;
#pragma unroll
        for (int d = 0; d < LL; ++d) { float x = patch[tid * 36 + d]; s += x * x; }
        xsq[tid] = s;
    }
    __syncthreads();

    int w = tid >> 6, l = tid & 63;
    int u = l >> 4;

    float mp[8] = {0.f, 0.f, 0.f, 0.f, 0.f, 0.f, 0.f, 0.f};
    float dp[8] = {0.f, 0.f, 0.f, 0.f, 0.f, 0.f, 0.f, 0.f};

    // ======================= HALF 0 (points 0-63) =======================
    {
        short8 pbh[4], pbl[4];
#pragma unroll
        for (int nt = 0; nt < 4; ++nt) {
            int p = nt * 16 + (l & 15);
            int pb = p * 36 + (u << 3);
            float4 f0 = *(const float4*)&patch[pb];
            float4 f1 = *(const float4*)&patch[pb + 4];
            float xv[8] = {f0.x, f0.y, f0.z, f0.w, f1.x, f1.y, f1.z, f1.w};
#pragma unroll
            for (int j = 0; j < 8; ++j) {
                u16 hh, lo;
                split_bf16(xv[j], hh, lo);
                pbh[nt][j] = (short)hh;
                pbl[nt][j] = (short)lo;
            }
        }
        u32 kpk[3][4][2];
#pragma unroll
        for (int i = 0; i < 3; ++i) {
            int zt = w * 3 + i;
            short8 zah = *(const short8*)&Zfh[(zt * 64 + l) * 8];
            short8 zal = *(const short8*)&Zfl[(zt * 64 + l) * 8];
            floatx4 acc2[4];
#pragma unroll
            for (int nt = 0; nt < 4; ++nt) {
                floatx4 z = {0.f, 0.f, 0.f, 0.f};
                z = __builtin_amdgcn_mfma_f32_16x16x32_bf16(zah, pbh[nt], z, 0, 0, 0);
                z = __builtin_amdgcn_mfma_f32_16x16x32_bf16(zah, pbl[nt], z, 0, 0, 0);
                z = __builtin_amdgcn_mfma_f32_16x16x32_bf16(zal, pbh[nt], z, 0, 0, 0);
                acc2[nt] = z;
            }
            int a2 = w * 3 + i;
            int kt = a2 >> 1;
            int rr = 2 * (a2 & 1) + (u >> 1);
            int k0 = a2 * 16 + 4 * u;
            float4 c4 = *(const float4*)&cvec[k0];
            float cvl[4] = {c4.x, c4.y, c4.z, c4.w};
#pragma unroll
            for (int nt = 0; nt < 4; ++nt) {
                int p = nt * 16 + (l & 15);
                u16 hi[4];
#pragma unroll
                for (int j = 0; j < 4; ++j) {
                    float s = zsq[k0 + j] + xsq[p] - 2.f * acc2[nt][j];
                    float v = var * exp2f(s * c2);
                    mp[nt] += cvl[j] * v;
                    hi[j] = f2bf(v);
                }
                u32 p0 = (u32)hi[0] | ((u32)hi[1] << 16);
                u32 p1 = (u32)hi[2] | ((u32)hi[3] << 16);
                int base = ((kt * 8 + nt) * 64 + rr * 16 + (l & 15)) * 8 + 4 * (u & 1);
                *(u32*)&kh[base]     = p0;
                *(u32*)&kh[base + 2] = p1;
                kpk[i][nt][0] = p0;
                kpk[i][nt][1] = p1;
            }
        }
        __syncthreads();   // kh ntg 0-3 published

        floatx4 acc[3][4];
#pragma unroll
        for (int i = 0; i < 3; ++i)
#pragma unroll
            for (int nt = 0; nt < 4; ++nt) { floatx4 z = {0.f, 0.f, 0.f, 0.f}; acc[i][nt] = z; }
        for (int kt = 0; kt < 12; ++kt) {
            short8 bh[4];
#pragma unroll
            for (int nt = 0; nt < 4; ++nt)
                bh[nt] = *(const short8*)&kh[((kt * 8 + nt) * 64 + l) * 8];
#pragma unroll
            for (int i = 0; i < 3; ++i) {
                int mt = w * 3 + i;
                int ab = ((mt * 12 + kt) * 64 + l) * 8;
                short8 ah = *(const short8*)&Bfh[ab];
                short8 al = *(const short8*)&Bfl[ab];
#pragma unroll
                for (int nt = 0; nt < 4; ++nt) {
                    acc[i][nt] = __builtin_amdgcn_mfma_f32_16x16x32_bf16(ah, bh[nt], acc[i][nt], 0, 0, 0);
                    acc[i][nt] = __builtin_amdgcn_mfma_f32_16x16x32_bf16(al, bh[nt], acc[i][nt], 0, 0, 0);
                }
            }
        }
        // diag dot for half 0 — frees kpk and acc before half 1
#pragma unroll
        for (int i = 0; i < 3; ++i)
#pragma unroll
            for (int nt = 0; nt < 4; ++nt) {
                float kv0 = bf2f((u16)(kpk[i][nt][0] & 0xFFFFu));
                float kv1 = bf2f((u16)(kpk[i][nt][0] >> 16));
                float kv2 = bf2f((u16)(kpk[i][nt][1] & 0xFFFFu));
                float kv3 = bf2f((u16)(kpk[i][nt][1] >> 16));
                dp[nt] += kv0 * acc[i][nt][0] + kv1 * acc[i][nt][1]
                        + kv2 * acc[i][nt][2] + kv3 * acc[i][nt][3];
            }
    }

    // ======================= HALF 1 (points 64-127) =====================
    // Phase 1 here writes kh ntg 4-7 — disjoint from half-0's ntg 0-3 reads,
    // so no barrier: slow waves' half-0 MFMA overlaps fast waves' VALU here.
    {
        short8 pbh[4], pbl[4];
#pragma unroll
        for (int nt = 0; nt < 4; ++nt) {
            int p = 64 + nt * 16 + (l & 15);
            int pb = p * 36 + (u << 3);
            float4 f0 = *(const float4*)&patch[pb];
            float4 f1 = *(const float4*)&patch[pb + 4];
            float xv[8] = {f0.x, f0.y, f0.z, f0.w, f1.x, f1.y, f1.z, f1.w};
#pragma unroll
            for (int j = 0; j < 8; ++j) {
                u16 hh, lo;
                split_bf16(xv[j], hh, lo);
                pbh[nt][j] = (short)hh;
                pbl[nt][j] = (short)lo;
            }
        }
        u32 kpk[3][4][2];
#pragma unroll
        for (int i = 0; i < 3; ++i) {
            int zt = w * 3 + i;
            short8 zah = *(const short8*)&Zfh[(zt * 64 + l) * 8];
            short8 zal = *(const short8*)&Zfl[(zt * 64 + l) * 8];
            floatx4 acc2[4];
#pragma unroll
            for (int nt = 0; nt < 4; ++nt) {
                floatx4 z = {0.f, 0.f, 0.f, 0.f};
                z = __builtin_amdgcn_mfma_f32_16x16x32_bf16(zah, pbh[nt], z, 0, 0, 0);
                z = __builtin_amdgcn_mfma_f32_16x16x32_bf16(zah, pbl[nt], z, 0, 0, 0);
                z = __builtin_amdgcn_mfma_f32_16x16x32_bf16(zal, pbh[nt], z, 0, 0, 0);
                acc2[nt] = z;
            }
            int a2 = w * 3 + i;
            int kt = a2 >> 1;
            int rr = 2 * (a2 & 1) + (u >> 1);
            int k0 = a2 * 16 + 4 * u;
            float4 c4 = *(const float4*)&cvec[k0];
            float cvl[4] = {c4.x, c4.y, c4.z, c4.w};
#pragma unroll
            for (int nt = 0; nt < 4; ++nt) {
                int ntg = 4 + nt;
                int p = 64 + nt * 16 + (l & 15);
                u16 hi[4];
#pragma unroll
                for (int j = 0; j < 4; ++j) {
                    float s = zsq[k0 + j] + xsq[p] - 2.f * acc2[nt][j];
                    float v = var * exp2f(s * c2);
                    mp[ntg] += cvl[j] * v;
                    hi[j] = f2bf(v);
                }
                u32 p0 = (u32)hi[0] | ((u32)hi[1] << 16);
                u32 p1 = (u32)hi[2] | ((u32)hi[3] << 16);
                int base = ((kt * 8 + ntg) * 64 + rr * 16 + (l & 15)) * 8 + 4 * (u & 1);
                *(u32*)&kh[base]     = p0;
                *(u32*)&kh[base + 2] = p1;
                kpk[i][nt][0] = p0;
                kpk[i][nt][1] = p1;
            }
        }
        __syncthreads();   // kh ntg 4-7 published

        floatx4 acc[3][4];
#pragma unroll
        for (int i = 0; i < 3; ++i)
#pragma unroll
            for (int nt = 0; nt < 4; ++nt) { floatx4 z = {0.f, 0.f, 0.f, 0.f}; acc[i][nt] = z; }
        for (int kt = 0; kt < 12; ++kt) {
            short8 bh[4];
#pragma unroll
            for (int nt = 0; nt < 4; ++nt)
                bh[nt] = *(const short8*)&kh[((kt * 8 + 4 + nt) * 64 + l) * 8];
#pragma unroll
            for (int i = 0; i < 3; ++i) {
                int mt = w * 3 + i;
                int ab = ((mt * 12 + kt) * 64 + l) * 8;
                short8 ah = *(const short8*)&Bfh[ab];
                short8 al = *(const short8*)&Bfl[ab];
#pragma unroll
                for (int nt = 0; nt < 4; ++nt) {
                    acc[i][nt] = __builtin_amdgcn_mfma_f32_16x16x32_bf16(ah, bh[nt], acc[i][nt], 0, 0, 0);
                    acc[i][nt] = __builtin_amdgcn_mfma_f32_16x16x32_bf16(al, bh[nt], acc[i][nt], 0, 0, 0);
                }
            }
        }
#pragma unroll
        for (int i = 0; i < 3; ++i)
#pragma unroll
            for (int nt = 0; nt < 4; ++nt) {
                float kv0 = bf2f((u16)(kpk[i][nt][0] & 0xFFFFu));
                float kv1 = bf2f((u16)(kpk[i][nt][0] >> 16));
                float kv2 = bf2f((u16)(kpk[i][nt][1] & 0xFFFFu));
                float kv3 = bf2f((u16)(kpk[i][nt][1] >> 16));
                dp[4 + nt] += kv0 * acc[i][nt][0] + kv1 * acc[i][nt][1]
                            + kv2 * acc[i][nt][2] + kv3 * acc[i][nt][3];
            }
    }

    // ======================= epilogues =======================
#pragma unroll
    for (int nt = 0; nt < 8; ++nt) {
        mp[nt] += __shfl_xor(mp[nt], 16);
        mp[nt] += __shfl_xor(mp[nt], 32);
        dp[nt] += __shfl_xor(dp[nt], 16);
        dp[nt] += __shfl_xor(dp[nt], 32);
    }
    if (l < 16) {
#pragma unroll
        for (int nt = 0; nt < 8; ++nt) red[w * 128 + nt * 16 + l] = mp[nt];
    }
    __syncthreads();
    if (tid < 128) {
        float s = 0.f;
#pragma unroll
        for (int ww = 0; ww < 8; ++ww) s += red[ww * 128 + tid];
        out[np0 + tid] = s;   // mean
    }
    __syncthreads();
    if (l < 16) {
#pragma unroll
        for (int nt = 0; nt < 8; ++nt) red[w * 128 + nt * 16 + l] = dp[nt];
    }
    __syncthreads();
    if (tid < 128) {
        float s = 0.f;
#pragma unroll
        for (int ww = 0; ww < 8; ++ww) s += red[ww * 128 + tid];
        out[NPTS + np0 + tid] = var + s;   // variance
    }
}

// ---------------------------------------------------------------------------
extern "C" void kernel_launch(void* const* d_in, const int* in_sizes, int n_in,
                              void* d_out, int out_size, void* d_ws, size_t ws_size,
                              hipStream_t stream) {
    const float* Xin    = (const float*)d_in[0];
    const float* Z      = (const float*)d_in[1];
    const float* q_mu   = (const float*)d_in[2];
    const float* q_sqrt = (const float*)d_in[3];
    const float* var_p  = (const float*)d_in[4];
    const float* ls_p   = (const float*)d_in[5];
    float* out = (float*)d_out;

    const size_t HB = (size_t)FRAG_N * 2;  // 294912 B per frag half-array
    char* base = (char*)d_ws;
    float* Kuu = (float*)base;                 // 2 HB; Bq frags overlay later
    u16* Bqh = (u16*)base;
    u16* Bql = (u16*)(base + HB);
    u16* Xh_a = (u16*)(base + 2 * HB);         // Kuu frags overlay (used only in ns1)
    u16* Xl_a = (u16*)(base + 3 * HB);
    u16* Kfh = Xh_a;
    u16* Kfl = Xl_a;
    u16* Xh_b = (u16*)(base + 4 * HB);
    u16* Xl_b = (u16*)(base + 5 * HB);
    u16* Rh_a = (u16*)(base + 6 * HB);
    u16* Rl_a = (u16*)(base + 7 * HB);
    u16* Rh_b = (u16*)(base + 8 * HB);
    u16* Rl_b = (u16*)(base + 9 * HB);
    u16* Qh   = (u16*)(base + 10 * HB);        // Q frags; Y overlays later
    u16* Ql   = (u16*)(base + 11 * HB);
    u16* Yh = Qh;
    u16* Yl = Ql;
    u16* SKh  = (u16*)(base + 12 * HB);
    u16* SKl  = (u16*)(base + 13 * HB);
    char* pF = base + 14 * HB;
    u16* Zfh = (u16*)pF;
    u16* Zfl = (u16*)(pF + ZFRAG_N * 2);
    float* z2g  = (float*)(pF + ZFRAG_N * 4);
    float* cvec = z2g + MM;
    float* rsum = cvec + MM;

    // 1) prep: Kuu dense+frags, rowsums, z2, Z frags, Q frags
    prep_kernel<<<MM, 384, 0, stream>>>(Z, q_sqrt, var_p, ls_p, Kuu, rsum, z2g,
                                        Kfh, Kfl, Qh, Ql, Zfh, Zfl);
    // 2) ns1: X1 elementwise | R1 = I-2aK+a^2 K@K | SK = QQ^T - Kuu
    ns1_kernel<<<108, 256, 0, stream>>>(Kuu, rsum, Kfh, Kfl, Qh, Ql,
                                        Xh_b, Xl_b, Rh_b, Rl_b, SKh, SKl);
    // 3-7) NS rounds 2..6 (5 launches -> 6 total NS iterations; 5 total FAILED
    //      at absmax 0.049 in round 9 — 6 is the verified convergence point)
    u16 *cxh = Xh_b, *cxl = Xl_b, *nxh = Xh_a, *nxl = Xl_a;
    u16 *crh = Rh_b, *crl = Rl_b, *nrh = Rh_a, *nrl = Rl_a;
    for (int it = 0; it < 5; ++it) {
        ns_kernel<<<72, 256, 0, stream>>>(cxh, cxl, crh, crl, nxh, nxl, nrh, nrl);
        u16* t;
        t = cxh; cxh = nxh; nxh = t;
        t = cxl; cxl = nxl; nxl = t;
        t = crh; crh = nrh; nrh = t;
        t = crl; crl = nrl; nrl = t;
    }
    // 8) Y = X@SK | cvec = X@q_mu
    y_kernel<<<42, 256, 0, stream>>>(cxh, cxl, SKh, SKl, q_mu, Yh, Yl, cvec);
    // 9) Bq = Y@X (into Kuu region)
    bq_kernel<<<36, 256, 0, stream>>>(Yh, Yl, cxh, cxl, Bqh, Bql);
    // 10) main (128 points/block, pipelined, low register pressure)
    main_kernel<<<NPTS / 128, 512, 0, stream>>>(Xin, Zfh, Zfl, z2g, Bqh, Bql, cvec,
                                                var_p, ls_p, out);
}

// Round 12
// 195.183 us; speedup vs baseline: 1.3682x; 1.0598x over previous
//
#include <hip/hip_runtime.h>
#include <hip/hip_bf16.h>

// Problem constants
#define HH 40
#define WW 40
#define KK 5
#define PP 1296            // 36*36
#define LL 25
#define MM 384
#define NN 64
#define NPTS (NN * PP)     // 82944
#define JITTER 1e-6f

typedef unsigned short u16;
typedef unsigned int   u32;
using short8  = __attribute__((ext_vector_type(8))) short;
using floatx4 = __attribute__((ext_vector_type(4))) float;

#define FRAG_N (MM * MM)        // u16 per frag half-array (147456)
#define ZFRAG_N (24 * 64 * 8)   // 12288

// ---------------------------------------------------------------------------
// bf16 split helpers (RNE)
__device__ inline u16 f2bf(float v) {
    u32 b = __float_as_uint(v);
    return (u16)((b + 0x7FFFu + ((b >> 16) & 1u)) >> 16);
}
__device__ inline float bf2f(u16 h) { return __uint_as_float(((u32)h) << 16); }
__device__ inline void split_bf16(float v, u16& hi, u16& lo) {
    hi = f2bf(v);
    lo = f2bf(v - bf2f(hi));
}

// A-fragment linear index (u16 units) for element (m,k), HW-verified rounds 2-11.
__device__ inline int frag_idx(int m, int k) {
    return (((m >> 4) * 12 + (k >> 5)) * 64 + ((m & 15) + (((k >> 3) & 3) << 4))) * 8 + (k & 7);
}

// ---------------------------------------------------------------------------
// Split-bf16 MFMA 64x64-tile GEMM on A-frag operands: C = A . B^T_storage.
__device__ inline void frag_gemm64(const u16* __restrict__ Ah, const u16* __restrict__ Al,
                                   const u16* __restrict__ Bh, const u16* __restrict__ Bl,
                                   int bi, int bj, int w, int l, floatx4 acc[2][2]) {
    int mt0 = bi * 4 + 2 * (w & 1);
    int nt0 = bj * 4 + 2 * (w >> 1);
#pragma unroll
    for (int i = 0; i < 2; ++i)
#pragma unroll
        for (int jn = 0; jn < 2; ++jn) { floatx4 z = {0.f, 0.f, 0.f, 0.f}; acc[i][jn] = z; }
    for (int kt = 0; kt < 12; ++kt) {
        int ab0 = (((mt0 + 0) * 12 + kt) * 64 + l) * 8;
        int ab1 = (((mt0 + 1) * 12 + kt) * 64 + l) * 8;
        int bb0 = (((nt0 + 0) * 12 + kt) * 64 + l) * 8;
        int bb1 = (((nt0 + 1) * 12 + kt) * 64 + l) * 8;
        short8 a0h = *(const short8*)&Ah[ab0];
        short8 a0l = *(const short8*)&Al[ab0];
        short8 a1h = *(const short8*)&Ah[ab1];
        short8 a1l = *(const short8*)&Al[ab1];
        short8 b0h = *(const short8*)&Bh[bb0];
        short8 b0l = *(const short8*)&Bl[bb0];
        short8 b1h = *(const short8*)&Bh[bb1];
        short8 b1l = *(const short8*)&Bl[bb1];
        acc[0][0] = __builtin_amdgcn_mfma_f32_16x16x32_bf16(a0h, b0h, acc[0][0], 0, 0, 0);
        acc[0][0] = __builtin_amdgcn_mfma_f32_16x16x32_bf16(a0h, b0l, acc[0][0], 0, 0, 0);
        acc[0][0] = __builtin_amdgcn_mfma_f32_16x16x32_bf16(a0l, b0h, acc[0][0], 0, 0, 0);
        acc[0][1] = __builtin_amdgcn_mfma_f32_16x16x32_bf16(a0h, b1h, acc[0][1], 0, 0, 0);
        acc[0][1] = __builtin_amdgcn_mfma_f32_16x16x32_bf16(a0h, b1l, acc[0][1], 0, 0, 0);
        acc[0][1] = __builtin_amdgcn_mfma_f32_16x16x32_bf16(a0l, b1h, acc[0][1], 0, 0, 0);
        acc[1][0] = __builtin_amdgcn_mfma_f32_16x16x32_bf16(a1h, b0h, acc[1][0], 0, 0, 0);
        acc[1][0] = __builtin_amdgcn_mfma_f32_16x16x32_bf16(a1h, b0l, acc[1][0], 0, 0, 0);
        acc[1][0] = __builtin_amdgcn_mfma_f32_16x16x32_bf16(a1l, b0h, acc[1][0], 0, 0, 0);
        acc[1][1] = __builtin_amdgcn_mfma_f32_16x16x32_bf16(a1h, b1h, acc[1][1], 0, 0, 0);
        acc[1][1] = __builtin_amdgcn_mfma_f32_16x16x32_bf16(a1h, b1l, acc[1][1], 0, 0, 0);
        acc[1][1] = __builtin_amdgcn_mfma_f32_16x16x32_bf16(a1l, b1h, acc[1][1], 0, 0, 0);
    }
}

__device__ inline void dwrite_frag(u16* __restrict__ Oh, u16* __restrict__ Ol,
                                   int m, int p, float v) {
    int idx = frag_idx(m, p);
    u16 hi, lo;
    split_bf16(v, hi, lo);
    Oh[idx] = hi; Ol[idx] = lo;
}

// ---------------------------------------------------------------------------
// Launch 1: Kuu dense + Kuu frags + rowsums + z2 + Z frags + Q frags.
__global__ void __launch_bounds__(384) prep_kernel(
    const float* __restrict__ Z, const float* __restrict__ q_sqrt,
    const float* __restrict__ var_p, const float* __restrict__ ls_p,
    float* __restrict__ Kuu, float* __restrict__ rsum, float* __restrict__ z2g,
    u16* __restrict__ Kfh, u16* __restrict__ Kfl,
    u16* __restrict__ Qh, u16* __restrict__ Ql,
    u16* __restrict__ Zfh, u16* __restrict__ Zfl) {
    __shared__ float Zs[LL];
    __shared__ float red[384];
    int r = blockIdx.x, tid = threadIdx.x;
    if (tid < LL) Zs[tid] = Z[r * LL + tid];
    __syncthreads();
    float var = var_p[0];
    float ls = ls_p[0];
    float c0 = -0.5f / (ls * ls);
    float s = 0.f;
#pragma unroll
    for (int d = 0; d < LL; ++d) {
        float dd = Zs[d] - Z[tid * LL + d];
        s += dd * dd;
    }
    float v = var * expf(c0 * s);
    if (tid == r) v += JITTER;
    Kuu[r * MM + tid] = v;
    red[tid] = v;
    __syncthreads();
    if (tid < 128) red[tid] += red[tid + 256];
    __syncthreads();
    for (int o = 128; o > 0; o >>= 1) {
        if (tid < o) red[tid] += red[tid + o];
        __syncthreads();
    }
    if (tid == 0) {
        rsum[r] = red[0];
        float t = 0.f;
#pragma unroll
        for (int d = 0; d < LL; ++d) t += Zs[d] * Zs[d];
        z2g[r] = t;
    }
    // frag-order writes: one element per thread (384*384 == FRAG_N)
    {
        int o = r * MM + tid;
        int j = o & 7, ln = (o >> 3) & 63, kt = (o >> 9) % 12, mt = o / 6144;
        int m = mt * 16 + (ln & 15);
        int k = kt * 32 + ((ln >> 4) << 3) + j;
        u16 h, lo;
        // Q frag
        float qv = (k <= m) ? q_sqrt[m * MM + k] : 0.f;
        split_bf16(qv, h, lo);
        Qh[o] = h; Ql[o] = lo;
        // Kuu frag (recompute distance for (m,k))
        float s2 = 0.f;
#pragma unroll
        for (int d = 0; d < LL; ++d) {
            float dd = Z[m * LL + d] - Z[k * LL + d];
            s2 += dd * dd;
        }
        float kv = var * expf(c0 * s2);
        if (m == k) kv += JITTER;
        split_bf16(kv, h, lo);
        Kfh[o] = h; Kfl[o] = lo;
        // Z frag
        if (o < ZFRAG_N) {
            int zt = o >> 9;
            int mz = zt * 16 + (ln & 15);
            int kd = ((ln >> 4) << 3) + j;
            float zv = (kd < LL) ? Z[mz * LL + kd] : 0.f;
            split_bf16(zv, h, lo);
            Zfh[o] = h; Zfl[o] = lo;
        }
    }
}

// ---------------------------------------------------------------------------
// Launch 2: blocks 0-35: X1 = alpha*(2I - alpha*Kuu);
//           36-71: R1 = I - 2a*K + a^2*(K@K)  (K frags from prep);
//           72-107: SK = Q@Q^T - Kuu.
__global__ void __launch_bounds__(256) ns1_kernel(
    const float* __restrict__ Kuu, const float* __restrict__ rsum,
    const u16* __restrict__ Kfh, const u16* __restrict__ Kfl,
    const u16* __restrict__ Qh, const u16* __restrict__ Ql,
    u16* __restrict__ Xh, u16* __restrict__ Xl,
    u16* __restrict__ Rh, u16* __restrict__ Rl,
    u16* __restrict__ SKh, u16* __restrict__ SKl) {
    __shared__ float red[256];
    int tid = threadIdx.x, blk = blockIdx.x;
    int w = tid >> 6, l = tid & 63;
    float alpha = 0.f;
    if (blk < 72) {
        float v0 = rsum[tid];
        if (tid < 128) v0 = fmaxf(v0, rsum[tid + 256]);
        red[tid] = v0;
        __syncthreads();
        for (int o = 128; o > 0; o >>= 1) {
            if (tid < o) red[tid] = fmaxf(red[tid], red[tid + o]);
            __syncthreads();
        }
        alpha = 1.0f / red[0];
    }
    if (blk < 36) {
        float a2 = alpha * alpha;
        for (int o = blk * 256 + tid; o < FRAG_N; o += 36 * 256) {
            int j = o & 7, ln = (o >> 3) & 63, kt = (o >> 9) % 12, mt = o / 6144;
            int m = mt * 16 + (ln & 15);
            int k = kt * 32 + ((ln >> 4) << 3) + j;
            float v = ((m == k) ? 2.f * alpha : 0.f) - a2 * Kuu[m * MM + k];
            u16 h, lo;
            split_bf16(v, h, lo);
            Xh[o] = h; Xl[o] = lo;
        }
    } else if (blk < 72) {
        int tile = blk - 36;
        int bi = tile / 6, bj = tile % 6;
        floatx4 acc[2][2];
        frag_gemm64(Kfh, Kfl, Kfh, Kfl, bi, bj, w, l, acc);   // K @ K
        int mt0 = bi * 4 + 2 * (w & 1), nt0 = bj * 4 + 2 * (w >> 1);
        float a2 = alpha * alpha;
#pragma unroll
        for (int i = 0; i < 2; ++i)
#pragma unroll
            for (int jn = 0; jn < 2; ++jn)
#pragma unroll
                for (int j = 0; j < 4; ++j) {
                    int m = (mt0 + i) * 16 + ((l >> 4) << 2) + j;
                    int p = (nt0 + jn) * 16 + (l & 15);
                    float v = a2 * acc[i][jn][j] - 2.f * alpha * Kuu[m * MM + p]
                            + ((m == p) ? 1.f : 0.f);
                    dwrite_frag(Rh, Rl, m, p, v);
                }
    } else {
        int tile = blk - 72;
        int bi = tile / 6, bj = tile % 6;
        floatx4 acc[2][2];
        frag_gemm64(Qh, Ql, Qh, Ql, bi, bj, w, l, acc);
        int mt0 = bi * 4 + 2 * (w & 1), nt0 = bj * 4 + 2 * (w >> 1);
#pragma unroll
        for (int i = 0; i < 2; ++i)
#pragma unroll
            for (int jn = 0; jn < 2; ++jn)
#pragma unroll
                for (int j = 0; j < 4; ++j) {
                    int m = (mt0 + i) * 16 + ((l >> 4) << 2) + j;
                    int p = (nt0 + jn) * 16 + (l & 15);
                    dwrite_frag(SKh, SKl, m, p, acc[i][jn][j] - Kuu[m * MM + p]);
                }
    }
}

// ---------------------------------------------------------------------------
// NS rounds: blocks 0-35: X' = X + X@R ; 36-71: R' = R@R
__global__ void __launch_bounds__(256) ns_kernel(
    const u16* __restrict__ cxh, const u16* __restrict__ cxl,
    const u16* __restrict__ crh, const u16* __restrict__ crl,
    u16* __restrict__ nxh, u16* __restrict__ nxl,
    u16* __restrict__ nrh, u16* __restrict__ nrl) {
    int blk = blockIdx.x, tid = threadIdx.x;
    bool isX = (blk < 36);
    int tile = isX ? blk : blk - 36;
    int bi = tile / 6, bj = tile % 6;
    int w = tid >> 6, l = tid & 63;
    floatx4 acc[2][2];
    frag_gemm64(isX ? cxh : crh, isX ? cxl : crl, crh, crl, bi, bj, w, l, acc);
    int mt0 = bi * 4 + 2 * (w & 1), nt0 = bj * 4 + 2 * (w >> 1);
    u16* Oh = isX ? nxh : nrh;
    u16* Ol = isX ? nxl : nrl;
#pragma unroll
    for (int i = 0; i < 2; ++i)
#pragma unroll
        for (int jn = 0; jn < 2; ++jn)
#pragma unroll
            for (int j = 0; j < 4; ++j) {
                int m = (mt0 + i) * 16 + ((l >> 4) << 2) + j;
                int p = (nt0 + jn) * 16 + (l & 15);
                float v = acc[i][jn][j];
                if (isX) {
                    int id = frag_idx(m, p);
                    v += bf2f(cxh[id]) + bf2f(cxl[id]);
                }
                dwrite_frag(Oh, Ol, m, p, v);
            }
}

// ---------------------------------------------------------------------------
// Launch 8: blocks 0-35: Y = X @ SK ; blocks 36-41: cvec = X @ q_mu
__global__ void __launch_bounds__(256) y_kernel(
    const u16* __restrict__ Xh, const u16* __restrict__ Xl,
    const u16* __restrict__ SKh, const u16* __restrict__ SKl,
    const float* __restrict__ qmu,
    u16* __restrict__ Yh, u16* __restrict__ Yl, float* __restrict__ cvec) {
    __shared__ float q[MM];
    int tid = threadIdx.x, blk = blockIdx.x;
    int w = tid >> 6, l = tid & 63;
    if (blk < 36) {
        int bi = blk / 6, bj = blk % 6;
        floatx4 acc[2][2];
        frag_gemm64(Xh, Xl, SKh, SKl, bi, bj, w, l, acc);
        int mt0 = bi * 4 + 2 * (w & 1), nt0 = bj * 4 + 2 * (w >> 1);
#pragma unroll
        for (int i = 0; i < 2; ++i)
#pragma unroll
            for (int jn = 0; jn < 2; ++jn)
#pragma unroll
                for (int j = 0; j < 4; ++j) {
                    int m = (mt0 + i) * 16 + ((l >> 4) << 2) + j;
                    int p = (nt0 + jn) * 16 + (l & 15);
                    dwrite_frag(Yh, Yl, m, p, acc[i][jn][j]);
                }
    } else {
        if (tid < MM) q[tid] = qmu[tid];
        if (tid + 256 < MM) q[tid + 256] = qmu[tid + 256];
        __syncthreads();
        int mt = (blk - 36) * 4 + w;
        float s = 0.f;
        for (int kt = 0; kt < 12; ++kt) {
            int b = ((mt * 12 + kt) * 64 + l) * 8;
            short8 h8 = *(const short8*)&Xh[b];
            short8 l8 = *(const short8*)&Xl[b];
            int kb = kt * 32 + ((l >> 4) << 3);
#pragma unroll
            for (int j = 0; j < 8; ++j)
                s += (bf2f((u16)h8[j]) + bf2f((u16)l8[j])) * q[kb + j];
        }
        s += __shfl_xor(s, 16);
        s += __shfl_xor(s, 32);
        if (l < 16) cvec[mt * 16 + l] = s;
    }
}

// Launch 9: Bq = Y @ X
__global__ void __launch_bounds__(256) bq_kernel(
    const u16* __restrict__ Yh, const u16* __restrict__ Yl,
    const u16* __restrict__ Xh, const u16* __restrict__ Xl,
    u16* __restrict__ Bh, u16* __restrict__ Bl) {
    int blk = blockIdx.x, tid = threadIdx.x;
    int bi = blk / 6, bj = blk % 6;
    int w = tid >> 6, l = tid & 63;
    floatx4 acc[2][2];
    frag_gemm64(Yh, Yl, Xh, Xl, bi, bj, w, l, acc);
    int mt0 = bi * 4 + 2 * (w & 1), nt0 = bj * 4 + 2 * (w >> 1);
#pragma unroll
    for (int i = 0; i < 2; ++i)
#pragma unroll
        for (int jn = 0; jn < 2; ++jn)
#pragma unroll
            for (int j = 0; j < 4; ++j) {
                int m = (mt0 + i) * 16 + ((l >> 4) << 2) + j;
                int p = (nt0 + jn) * 16 + (l & 15);
                dwrite_frag(Bh, Bl, m, p, acc[i][jn][j]);
            }
}

// ---------------------------------------------------------------------------
// Main fused kernel — EXACT round-7 structure (measured 77.4 µs, VGPR 128,
// no spill): two sequential phase-1 halves filling kh ntg 0-7 + packed kpk,
// then ONE phase-2 pass over all 8 n-tiles (single Bq L2 stream), then
// register-dot diag. Rounds 8-11's pipelined variants all lost (spill or
// doubled Bq traffic) — the unified VGPR/AGPR budget is the wall.
__global__ void __launch_bounds__(512) main_kernel(
    const float* __restrict__ Xin,
    const u16* __restrict__ Zfh, const u16* __restrict__ Zfl,
    const float* __restrict__ z2g,
    const u16* __restrict__ Bfh, const u16* __restrict__ Bfl,
    const float* __restrict__ cvec,
    const float* __restrict__ var_p, const float* __restrict__ ls_p,
    float* __restrict__ out) {
    __shared__ u16 kh[12 * 8 * 64 * 8];   // 96 KB: B-frag K tile (hi)
    __shared__ float patch[128 * 36];     // 18 KB
    __shared__ float zsq[MM];
    __shared__ float xsq[128];
    __shared__ float red[1024];

    int tid = threadIdx.x;
    int np0 = blockIdx.x * 128;
    float var = var_p[0];
    float ls = ls_p[0];
    float c2 = -0.72134752044f / (ls * ls);   // -0.5*log2(e)/ls^2

    if (tid < MM) zsq[tid] = z2g[tid];
    for (int e = tid; e < 128 * 36; e += 512) {
        int pt = e / 36, c = e % 36;
        float v = 0.f;
        if (c < 25) {
            int np = np0 + pt;
            int n = np / PP, p = np % PP;
            int oi = p / 36, oj = p % 36;
            v = Xin[n * (HH * WW) + (oi + c / 5) * WW + (oj + c % 5)];
        }
        patch[e] = v;
    }
    __syncthreads();
    if (tid < 128) {
        float s = 0.f;
#pragma unroll
        for (int d = 0; d < LL; ++d) { float x = patch[tid * 36 + d]; s += x * x; }
        xsq[tid] = s;
    }
    __syncthreads();

    int w = tid >> 6, l = tid & 63;
    int u = l >> 4;

    u32 kpk[3][8][2];                     // packed bf16 K values (diag left factor)
    float mp[8] = {0.f, 0.f, 0.f, 0.f, 0.f, 0.f, 0.f, 0.f};

    // phase 1 in two 64-point halves: cross = Z @ patch^T, then K finalize.
#pragma unroll
    for (int h = 0; h < 2; ++h) {
        short8 pbh[4], pbl[4];
#pragma unroll
        for (int nt = 0; nt < 4; ++nt) {
            int p = h * 64 + nt * 16 + (l & 15);
            int pb = p * 36 + (u << 3);
            float4 f0 = *(const float4*)&patch[pb];
            float4 f1 = *(const float4*)&patch[pb + 4];
            float xv[8] = {f0.x, f0.y, f0.z, f0.w, f1.x, f1.y, f1.z, f1.w};
#pragma unroll
            for (int j = 0; j < 8; ++j) {
                u16 hh, lo;
                split_bf16(xv[j], hh, lo);
                pbh[nt][j] = (short)hh;
                pbl[nt][j] = (short)lo;
            }
        }
        floatx4 acc2[3][4];
#pragma unroll
        for (int i = 0; i < 3; ++i) {
            int zt = w * 3 + i;
            short8 zah = *(const short8*)&Zfh[(zt * 64 + l) * 8];
            short8 zal = *(const short8*)&Zfl[(zt * 64 + l) * 8];
#pragma unroll
            for (int nt = 0; nt < 4; ++nt) {
                floatx4 z = {0.f, 0.f, 0.f, 0.f};
                z = __builtin_amdgcn_mfma_f32_16x16x32_bf16(zah, pbh[nt], z, 0, 0, 0);
                z = __builtin_amdgcn_mfma_f32_16x16x32_bf16(zah, pbl[nt], z, 0, 0, 0);
                z = __builtin_amdgcn_mfma_f32_16x16x32_bf16(zal, pbh[nt], z, 0, 0, 0);
                acc2[i][nt] = z;
            }
        }
        // finalize K for this half
#pragma unroll
        for (int i = 0; i < 3; ++i) {
            int a2 = w * 3 + i;
            int kt = a2 >> 1;
            int rr = 2 * (a2 & 1) + (u >> 1);
            int k0 = a2 * 16 + 4 * u;
            float4 c4 = *(const float4*)&cvec[k0];
            float cvl[4] = {c4.x, c4.y, c4.z, c4.w};
#pragma unroll
            for (int nt = 0; nt < 4; ++nt) {
                int ntg = h * 4 + nt;
                int p = h * 64 + nt * 16 + (l & 15);
                u16 hi[4];
#pragma unroll
                for (int j = 0; j < 4; ++j) {
                    float s = zsq[k0 + j] + xsq[p] - 2.f * acc2[i][nt][j];
                    float v = var * exp2f(s * c2);
                    mp[ntg] += cvl[j] * v;
                    hi[j] = f2bf(v);
                }
                u32 p0 = (u32)hi[0] | ((u32)hi[1] << 16);
                u32 p1 = (u32)hi[2] | ((u32)hi[3] << 16);
                int base = ((kt * 8 + ntg) * 64 + rr * 16 + (l & 15)) * 8 + 4 * (u & 1);
                *(u32*)&kh[base]     = p0;
                *(u32*)&kh[base + 2] = p1;
                kpk[i][ntg][0] = p0;
                kpk[i][ntg][1] = p1;
            }
        }
    }

    // mean partials: wave-reduce, cross-wave via red
#pragma unroll
    for (int nt = 0; nt < 8; ++nt) {
        mp[nt] += __shfl_xor(mp[nt], 16);
        mp[nt] += __shfl_xor(mp[nt], 32);
    }
    if (l < 16) {
#pragma unroll
        for (int nt = 0; nt < 8; ++nt) red[w * 128 + nt * 16 + l] = mp[nt];
    }
    __syncthreads();   // publishes kh AND mean partials
    if (tid < 128) {
        float s = 0.f;
#pragma unroll
        for (int ww = 0; ww < 8; ++ww) s += red[ww * 128 + tid];
        out[np0 + tid] = s;   // mean
    }

    // phase 2: acc[m][p] = sum_k Bq[m][k] K[k][p]; B split 2-term, K hi only
    floatx4 acc[3][8];
#pragma unroll
    for (int i = 0; i < 3; ++i)
#pragma unroll
        for (int nt = 0; nt < 8; ++nt) { floatx4 z = {0.f, 0.f, 0.f, 0.f}; acc[i][nt] = z; }
    for (int kt = 0; kt < 12; ++kt) {
        short8 bh[8];
#pragma unroll
        for (int nt = 0; nt < 8; ++nt)
            bh[nt] = *(const short8*)&kh[((kt * 8 + nt) * 64 + l) * 8];
#pragma unroll
        for (int i = 0; i < 3; ++i) {
            int mt = w * 3 + i;
            int ab = ((mt * 12 + kt) * 64 + l) * 8;
            short8 ah = *(const short8*)&Bfh[ab];
            short8 al = *(const short8*)&Bfl[ab];
#pragma unroll
            for (int nt = 0; nt < 8; ++nt) {
                acc[i][nt] = __builtin_amdgcn_mfma_f32_16x16x32_bf16(ah, bh[nt], acc[i][nt], 0, 0, 0);
                acc[i][nt] = __builtin_amdgcn_mfma_f32_16x16x32_bf16(al, bh[nt], acc[i][nt], 0, 0, 0);
            }
        }
    }
    __syncthreads();   // mean readers done before red reuse

    // diag epilogue: register dot; left factor = K hi (same D-frag map)
    float dp[8] = {0.f, 0.f, 0.f, 0.f, 0.f, 0.f, 0.f, 0.f};
#pragma unroll
    for (int i = 0; i < 3; ++i)
#pragma unroll
        for (int nt = 0; nt < 8; ++nt) {
            float kv0 = bf2f((u16)(kpk[i][nt][0] & 0xFFFFu));
            float kv1 = bf2f((u16)(kpk[i][nt][0] >> 16));
            float kv2 = bf2f((u16)(kpk[i][nt][1] & 0xFFFFu));
            float kv3 = bf2f((u16)(kpk[i][nt][1] >> 16));
            dp[nt] += kv0 * acc[i][nt][0] + kv1 * acc[i][nt][1]
                    + kv2 * acc[i][nt][2] + kv3 * acc[i][nt][3];
        }
#pragma unroll
    for (int nt = 0; nt < 8; ++nt) {
        dp[nt] += __shfl_xor(dp[nt], 16);
        dp[nt] += __shfl_xor(dp[nt], 32);
    }
    if (l < 16) {
#pragma unroll
        for (int nt = 0; nt < 8; ++nt) red[w * 128 + nt * 16 + l] = dp[nt];
    }
    __syncthreads();
    if (tid < 128) {
        float s = 0.f;
#pragma unroll
        for (int ww = 0; ww < 8; ++ww) s += red[ww * 128 + tid];
        out[NPTS + np0 + tid] = var + s;
    }
}

// ---------------------------------------------------------------------------
extern "C" void kernel_launch(void* const* d_in, const int* in_sizes, int n_in,
                              void* d_out, int out_size, void* d_ws, size_t ws_size,
                              hipStream_t stream) {
    const float* Xin    = (const float*)d_in[0];
    const float* Z      = (const float*)d_in[1];
    const float* q_mu   = (const float*)d_in[2];
    const float* q_sqrt = (const float*)d_in[3];
    const float* var_p  = (const float*)d_in[4];
    const float* ls_p   = (const float*)d_in[5];
    float* out = (float*)d_out;

    const size_t HB = (size_t)FRAG_N * 2;  // 294912 B per frag half-array
    char* base = (char*)d_ws;
    float* Kuu = (float*)base;                 // 2 HB; Bq frags overlay later
    u16* Bqh = (u16*)base;
    u16* Bql = (u16*)(base + HB);
    u16* Xh_a = (u16*)(base + 2 * HB);         // Kuu frags overlay (used only in ns1)
    u16* Xl_a = (u16*)(base + 3 * HB);
    u16* Kfh = Xh_a;
    u16* Kfl = Xl_a;
    u16* Xh_b = (u16*)(base + 4 * HB);
    u16* Xl_b = (u16*)(base + 5 * HB);
    u16* Rh_a = (u16*)(base + 6 * HB);
    u16* Rl_a = (u16*)(base + 7 * HB);
    u16* Rh_b = (u16*)(base + 8 * HB);
    u16* Rl_b = (u16*)(base + 9 * HB);
    u16* Qh   = (u16*)(base + 10 * HB);        // Q frags; Y overlays later
    u16* Ql   = (u16*)(base + 11 * HB);
    u16* Yh = Qh;
    u16* Yl = Ql;
    u16* SKh  = (u16*)(base + 12 * HB);
    u16* SKl  = (u16*)(base + 13 * HB);
    char* pF = base + 14 * HB;
    u16* Zfh = (u16*)pF;
    u16* Zfl = (u16*)(pF + ZFRAG_N * 2);
    float* z2g  = (float*)(pF + ZFRAG_N * 4);
    float* cvec = z2g + MM;
    float* rsum = cvec + MM;

    // 1) prep: Kuu dense+frags, rowsums, z2, Z frags, Q frags
    prep_kernel<<<MM, 384, 0, stream>>>(Z, q_sqrt, var_p, ls_p, Kuu, rsum, z2g,
                                        Kfh, Kfl, Qh, Ql, Zfh, Zfl);
    // 2) ns1: X1 elementwise | R1 = I-2aK+a^2 K@K | SK = QQ^T - Kuu
    ns1_kernel<<<108, 256, 0, stream>>>(Kuu, rsum, Kfh, Kfl, Qh, Ql,
                                        Xh_b, Xl_b, Rh_b, Rl_b, SKh, SKl);
    // 3-7) NS rounds 2..6 (5 launches -> 6 total NS iterations; 5 total FAILED
    //      at absmax 0.049 in round 9 — 6 is the verified convergence point)
    u16 *cxh = Xh_b, *cxl = Xl_b, *nxh = Xh_a, *nxl = Xl_a;
    u16 *crh = Rh_b, *crl = Rl_b, *nrh = Rh_a, *nrl = Rl_a;
    for (int it = 0; it < 5; ++it) {
        ns_kernel<<<72, 256, 0, stream>>>(cxh, cxl, crh, crl, nxh, nxl, nrh, nrl);
        u16* t;
        t = cxh; cxh = nxh; nxh = t;
        t = cxl; cxl = nxl; nxl = t;
        t = crh; crh = nrh; nrh = t;
        t = crl; crl = nrl; nrl = t;
    }
    // 8) Y = X@SK | cvec = X@q_mu
    y_kernel<<<42, 256, 0, stream>>>(cxh, cxl, SKh, SKl, q_mu, Yh, Yl, cvec);
    // 9) Bq = Y@X (into Kuu region)
    bq_kernel<<<36, 256, 0, stream>>>(Yh, Yl, cxh, cxl, Bqh, Bql);
    // 10) main (128 points/block, round-7 structure)
    main_kernel<<<NPTS / 128, 512, 0, stream>>>(Xin, Zfh, Zfl, z2g, Bqh, Bql, cvec,
                                                var_p, ls_p, out);
}

// Round 13
// 179.224 us; speedup vs baseline: 1.4900x; 1.0890x over previous
//
#include <hip/hip_runtime.h>
#include <hip/hip_bf16.h>

// Problem constants
#define HH 40
#define WW 40
#define KK 5
#define PP 1296            // 36*36
#define LL 25
#define MM 384
#define NN 64
#define NPTS (NN * PP)     // 82944
#define JITTER 1e-6f

typedef unsigned short u16;
typedef unsigned int   u32;
using short8  = __attribute__((ext_vector_type(8))) short;
using floatx4 = __attribute__((ext_vector_type(4))) float;

#define FRAG_N (MM * MM)        // u16 per frag half-array (147456)
#define ZFRAG_N (24 * 64 * 8)   // 12288

// ---------------------------------------------------------------------------
// bf16 split helpers (RNE)
__device__ inline u16 f2bf(float v) {
    u32 b = __float_as_uint(v);
    return (u16)((b + 0x7FFFu + ((b >> 16) & 1u)) >> 16);
}
__device__ inline float bf2f(u16 h) { return __uint_as_float(((u32)h) << 16); }
__device__ inline void split_bf16(float v, u16& hi, u16& lo) {
    hi = f2bf(v);
    lo = f2bf(v - bf2f(hi));
}

// A-fragment linear index (u16 units) for element (m,k), HW-verified rounds 2-12.
__device__ inline int frag_idx(int m, int k) {
    return (((m >> 4) * 12 + (k >> 5)) * 64 + ((m & 15) + (((k >> 3) & 3) << 4))) * 8 + (k & 7);
}

// ---------------------------------------------------------------------------
// Split-bf16 MFMA 64x64-tile GEMM on A-frag operands: C = A . B^T_storage.
__device__ inline void frag_gemm64(const u16* __restrict__ Ah, const u16* __restrict__ Al,
                                   const u16* __restrict__ Bh, const u16* __restrict__ Bl,
                                   int bi, int bj, int w, int l, floatx4 acc[2][2]) {
    int mt0 = bi * 4 + 2 * (w & 1);
    int nt0 = bj * 4 + 2 * (w >> 1);
#pragma unroll
    for (int i = 0; i < 2; ++i)
#pragma unroll
        for (int jn = 0; jn < 2; ++jn) { floatx4 z = {0.f, 0.f, 0.f, 0.f}; acc[i][jn] = z; }
    for (int kt = 0; kt < 12; ++kt) {
        int ab0 = (((mt0 + 0) * 12 + kt) * 64 + l) * 8;
        int ab1 = (((mt0 + 1) * 12 + kt) * 64 + l) * 8;
        int bb0 = (((nt0 + 0) * 12 + kt) * 64 + l) * 8;
        int bb1 = (((nt0 + 1) * 12 + kt) * 64 + l) * 8;
        short8 a0h = *(const short8*)&Ah[ab0];
        short8 a0l = *(const short8*)&Al[ab0];
        short8 a1h = *(const short8*)&Ah[ab1];
        short8 a1l = *(const short8*)&Al[ab1];
        short8 b0h = *(const short8*)&Bh[bb0];
        short8 b0l = *(const short8*)&Bl[bb0];
        short8 b1h = *(const short8*)&Bh[bb1];
        short8 b1l = *(const short8*)&Bl[bb1];
        acc[0][0] = __builtin_amdgcn_mfma_f32_16x16x32_bf16(a0h, b0h, acc[0][0], 0, 0, 0);
        acc[0][0] = __builtin_amdgcn_mfma_f32_16x16x32_bf16(a0h, b0l, acc[0][0], 0, 0, 0);
        acc[0][0] = __builtin_amdgcn_mfma_f32_16x16x32_bf16(a0l, b0h, acc[0][0], 0, 0, 0);
        acc[0][1] = __builtin_amdgcn_mfma_f32_16x16x32_bf16(a0h, b1h, acc[0][1], 0, 0, 0);
        acc[0][1] = __builtin_amdgcn_mfma_f32_16x16x32_bf16(a0h, b1l, acc[0][1], 0, 0, 0);
        acc[0][1] = __builtin_amdgcn_mfma_f32_16x16x32_bf16(a0l, b1h, acc[0][1], 0, 0, 0);
        acc[1][0] = __builtin_amdgcn_mfma_f32_16x16x32_bf16(a1h, b0h, acc[1][0], 0, 0, 0);
        acc[1][0] = __builtin_amdgcn_mfma_f32_16x16x32_bf16(a1h, b0l, acc[1][0], 0, 0, 0);
        acc[1][0] = __builtin_amdgcn_mfma_f32_16x16x32_bf16(a1l, b0h, acc[1][0], 0, 0, 0);
        acc[1][1] = __builtin_amdgcn_mfma_f32_16x16x32_bf16(a1h, b1h, acc[1][1], 0, 0, 0);
        acc[1][1] = __builtin_amdgcn_mfma_f32_16x16x32_bf16(a1h, b1l, acc[1][1], 0, 0, 0);
        acc[1][1] = __builtin_amdgcn_mfma_f32_16x16x32_bf16(a1l, b1h, acc[1][1], 0, 0, 0);
    }
}

__device__ inline void dwrite_frag(u16* __restrict__ Oh, u16* __restrict__ Ol,
                                   int m, int p, float v) {
    int idx = frag_idx(m, p);
    u16 hi, lo;
    split_bf16(v, hi, lo);
    Oh[idx] = hi; Ol[idx] = lo;
}

// ---------------------------------------------------------------------------
// Launch 1: Kuu dense + Kuu frags + rowsums + z2 + Z frags + Q frags.
__global__ void __launch_bounds__(384) prep_kernel(
    const float* __restrict__ Z, const float* __restrict__ q_sqrt,
    const float* __restrict__ var_p, const float* __restrict__ ls_p,
    float* __restrict__ Kuu, float* __restrict__ rsum, float* __restrict__ z2g,
    u16* __restrict__ Kfh, u16* __restrict__ Kfl,
    u16* __restrict__ Qh, u16* __restrict__ Ql,
    u16* __restrict__ Zfh, u16* __restrict__ Zfl) {
    __shared__ float Zs[LL];
    __shared__ float red[384];
    int r = blockIdx.x, tid = threadIdx.x;
    if (tid < LL) Zs[tid] = Z[r * LL + tid];
    __syncthreads();
    float var = var_p[0];
    float ls = ls_p[0];
    float c0 = -0.5f / (ls * ls);
    float s = 0.f;
#pragma unroll
    for (int d = 0; d < LL; ++d) {
        float dd = Zs[d] - Z[tid * LL + d];
        s += dd * dd;
    }
    float v = var * expf(c0 * s);
    if (tid == r) v += JITTER;
    Kuu[r * MM + tid] = v;
    red[tid] = v;
    __syncthreads();
    if (tid < 128) red[tid] += red[tid + 256];
    __syncthreads();
    for (int o = 128; o > 0; o >>= 1) {
        if (tid < o) red[tid] += red[tid + o];
        __syncthreads();
    }
    if (tid == 0) {
        rsum[r] = red[0];
        float t = 0.f;
#pragma unroll
        for (int d = 0; d < LL; ++d) t += Zs[d] * Zs[d];
        z2g[r] = t;
    }
    // frag-order writes: one element per thread (384*384 == FRAG_N)
    {
        int o = r * MM + tid;
        int j = o & 7, ln = (o >> 3) & 63, kt = (o >> 9) % 12, mt = o / 6144;
        int m = mt * 16 + (ln & 15);
        int k = kt * 32 + ((ln >> 4) << 3) + j;
        u16 h, lo;
        // Q frag
        float qv = (k <= m) ? q_sqrt[m * MM + k] : 0.f;
        split_bf16(qv, h, lo);
        Qh[o] = h; Ql[o] = lo;
        // Kuu frag (recompute distance for (m,k))
        float s2 = 0.f;
#pragma unroll
        for (int d = 0; d < LL; ++d) {
            float dd = Z[m * LL + d] - Z[k * LL + d];
            s2 += dd * dd;
        }
        float kv = var * expf(c0 * s2);
        if (m == k) kv += JITTER;
        split_bf16(kv, h, lo);
        Kfh[o] = h; Kfl[o] = lo;
        // Z frag
        if (o < ZFRAG_N) {
            int zt = o >> 9;
            int mz = zt * 16 + (ln & 15);
            int kd = ((ln >> 4) << 3) + j;
            float zv = (kd < LL) ? Z[mz * LL + kd] : 0.f;
            split_bf16(zv, h, lo);
            Zfh[o] = h; Zfl[o] = lo;
        }
    }
}

// ---------------------------------------------------------------------------
// Launch 2: blocks 0-35: X1 = a*(2I - a*Kuu);
//           36-71: R1 = I - 2a*K + a^2*(K@K)  (K frags from prep);
//           72-107: SK = Q@Q^T - Kuu.
// a = 1.7/maxrowsum (scaled seed): shrinks the lambda_min residual ratio
// from r to 1-1.7(1-r), making 5 total NS iterations sufficient (was 6).
// Convergence guaranteed: a*lmax <= 1.7 < 2.
__global__ void __launch_bounds__(256) ns1_kernel(
    const float* __restrict__ Kuu, const float* __restrict__ rsum,
    const u16* __restrict__ Kfh, const u16* __restrict__ Kfl,
    const u16* __restrict__ Qh, const u16* __restrict__ Ql,
    u16* __restrict__ Xh, u16* __restrict__ Xl,
    u16* __restrict__ Rh, u16* __restrict__ Rl,
    u16* __restrict__ SKh, u16* __restrict__ SKl) {
    __shared__ float red[256];
    int tid = threadIdx.x, blk = blockIdx.x;
    int w = tid >> 6, l = tid & 63;
    float alpha = 0.f;
    if (blk < 72) {
        float v0 = rsum[tid];
        if (tid < 128) v0 = fmaxf(v0, rsum[tid + 256]);
        red[tid] = v0;
        __syncthreads();
        for (int o = 128; o > 0; o >>= 1) {
            if (tid < o) red[tid] = fmaxf(red[tid], red[tid + o]);
            __syncthreads();
        }
        alpha = 1.7f / red[0];   // scaled seed
    }
    if (blk < 36) {
        float a2 = alpha * alpha;
        for (int o = blk * 256 + tid; o < FRAG_N; o += 36 * 256) {
            int j = o & 7, ln = (o >> 3) & 63, kt = (o >> 9) % 12, mt = o / 6144;
            int m = mt * 16 + (ln & 15);
            int k = kt * 32 + ((ln >> 4) << 3) + j;
            float v = ((m == k) ? 2.f * alpha : 0.f) - a2 * Kuu[m * MM + k];
            u16 h, lo;
            split_bf16(v, h, lo);
            Xh[o] = h; Xl[o] = lo;
        }
    } else if (blk < 72) {
        int tile = blk - 36;
        int bi = tile / 6, bj = tile % 6;
        floatx4 acc[2][2];
        frag_gemm64(Kfh, Kfl, Kfh, Kfl, bi, bj, w, l, acc);   // K @ K
        int mt0 = bi * 4 + 2 * (w & 1), nt0 = bj * 4 + 2 * (w >> 1);
        float a2 = alpha * alpha;
#pragma unroll
        for (int i = 0; i < 2; ++i)
#pragma unroll
            for (int jn = 0; jn < 2; ++jn)
#pragma unroll
                for (int j = 0; j < 4; ++j) {
                    int m = (mt0 + i) * 16 + ((l >> 4) << 2) + j;
                    int p = (nt0 + jn) * 16 + (l & 15);
                    float v = a2 * acc[i][jn][j] - 2.f * alpha * Kuu[m * MM + p]
                            + ((m == p) ? 1.f : 0.f);
                    dwrite_frag(Rh, Rl, m, p, v);
                }
    } else {
        int tile = blk - 72;
        int bi = tile / 6, bj = tile % 6;
        floatx4 acc[2][2];
        frag_gemm64(Qh, Ql, Qh, Ql, bi, bj, w, l, acc);
        int mt0 = bi * 4 + 2 * (w & 1), nt0 = bj * 4 + 2 * (w >> 1);
#pragma unroll
        for (int i = 0; i < 2; ++i)
#pragma unroll
            for (int jn = 0; jn < 2; ++jn)
#pragma unroll
                for (int j = 0; j < 4; ++j) {
                    int m = (mt0 + i) * 16 + ((l >> 4) << 2) + j;
                    int p = (nt0 + jn) * 16 + (l & 15);
                    dwrite_frag(SKh, SKl, m, p, acc[i][jn][j] - Kuu[m * MM + p]);
                }
    }
}

// ---------------------------------------------------------------------------
// NS rounds: blocks 0-35: X' = X + X@R ; 36-71: R' = R@R
__global__ void __launch_bounds__(256) ns_kernel(
    const u16* __restrict__ cxh, const u16* __restrict__ cxl,
    const u16* __restrict__ crh, const u16* __restrict__ crl,
    u16* __restrict__ nxh, u16* __restrict__ nxl,
    u16* __restrict__ nrh, u16* __restrict__ nrl) {
    int blk = blockIdx.x, tid = threadIdx.x;
    bool isX = (blk < 36);
    int tile = isX ? blk : blk - 36;
    int bi = tile / 6, bj = tile % 6;
    int w = tid >> 6, l = tid & 63;
    floatx4 acc[2][2];
    frag_gemm64(isX ? cxh : crh, isX ? cxl : crl, crh, crl, bi, bj, w, l, acc);
    int mt0 = bi * 4 + 2 * (w & 1), nt0 = bj * 4 + 2 * (w >> 1);
    u16* Oh = isX ? nxh : nrh;
    u16* Ol = isX ? nxl : nrl;
#pragma unroll
    for (int i = 0; i < 2; ++i)
#pragma unroll
        for (int jn = 0; jn < 2; ++jn)
#pragma unroll
            for (int j = 0; j < 4; ++j) {
                int m = (mt0 + i) * 16 + ((l >> 4) << 2) + j;
                int p = (nt0 + jn) * 16 + (l & 15);
                float v = acc[i][jn][j];
                if (isX) {
                    int id = frag_idx(m, p);
                    v += bf2f(cxh[id]) + bf2f(cxl[id]);
                }
                dwrite_frag(Oh, Ol, m, p, v);
            }
}

// ---------------------------------------------------------------------------
// Launch 7: blocks 0-35: Y = X @ SK ; blocks 36-41: cvec = X @ q_mu
__global__ void __launch_bounds__(256) y_kernel(
    const u16* __restrict__ Xh, const u16* __restrict__ Xl,
    const u16* __restrict__ SKh, const u16* __restrict__ SKl,
    const float* __restrict__ qmu,
    u16* __restrict__ Yh, u16* __restrict__ Yl, float* __restrict__ cvec) {
    __shared__ float q[MM];
    int tid = threadIdx.x, blk = blockIdx.x;
    int w = tid >> 6, l = tid & 63;
    if (blk < 36) {
        int bi = blk / 6, bj = blk % 6;
        floatx4 acc[2][2];
        frag_gemm64(Xh, Xl, SKh, SKl, bi, bj, w, l, acc);
        int mt0 = bi * 4 + 2 * (w & 1), nt0 = bj * 4 + 2 * (w >> 1);
#pragma unroll
        for (int i = 0; i < 2; ++i)
#pragma unroll
            for (int jn = 0; jn < 2; ++jn)
#pragma unroll
                for (int j = 0; j < 4; ++j) {
                    int m = (mt0 + i) * 16 + ((l >> 4) << 2) + j;
                    int p = (nt0 + jn) * 16 + (l & 15);
                    dwrite_frag(Yh, Yl, m, p, acc[i][jn][j]);
                }
    } else {
        if (tid < MM) q[tid] = qmu[tid];
        if (tid + 256 < MM) q[tid + 256] = qmu[tid + 256];
        __syncthreads();
        int mt = (blk - 36) * 4 + w;
        float s = 0.f;
        for (int kt = 0; kt < 12; ++kt) {
            int b = ((mt * 12 + kt) * 64 + l) * 8;
            short8 h8 = *(const short8*)&Xh[b];
            short8 l8 = *(const short8*)&Xl[b];
            int kb = kt * 32 + ((l >> 4) << 3);
#pragma unroll
            for (int j = 0; j < 8; ++j)
                s += (bf2f((u16)h8[j]) + bf2f((u16)l8[j])) * q[kb + j];
        }
        s += __shfl_xor(s, 16);
        s += __shfl_xor(s, 32);
        if (l < 16) cvec[mt * 16 + l] = s;
    }
}

// Launch 8: Bq = Y @ X
__global__ void __launch_bounds__(256) bq_kernel(
    const u16* __restrict__ Yh, const u16* __restrict__ Yl,
    const u16* __restrict__ Xh, const u16* __restrict__ Xl,
    u16* __restrict__ Bh, u16* __restrict__ Bl) {
    int blk = blockIdx.x, tid = threadIdx.x;
    int bi = blk / 6, bj = blk % 6;
    int w = tid >> 6, l = tid & 63;
    floatx4 acc[2][2];
    frag_gemm64(Yh, Yl, Xh, Xl, bi, bj, w, l, acc);
    int mt0 = bi * 4 + 2 * (w & 1), nt0 = bj * 4 + 2 * (w >> 1);
#pragma unroll
    for (int i = 0; i < 2; ++i)
#pragma unroll
        for (int jn = 0; jn < 2; ++jn)
#pragma unroll
            for (int j = 0; j < 4; ++j) {
                int m = (mt0 + i) * 16 + ((l >> 4) << 2) + j;
                int p = (nt0 + jn) * 16 + (l & 15);
                dwrite_frag(Bh, Bl, m, p, acc[i][jn][j]);
            }
}

// ---------------------------------------------------------------------------
// Main fused kernel — round-7/12 structure (measured 77.5 µs, VGPR 128, no
// spill): two sequential phase-1 halves filling kh ntg 0-7 + packed kpk,
// then ONE phase-2 pass over all 8 n-tiles (single Bq L2 stream), then
// register-dot diag.
__global__ void __launch_bounds__(512) main_kernel(
    const float* __restrict__ Xin,
    const u16* __restrict__ Zfh, const u16* __restrict__ Zfl,
    const float* __restrict__ z2g,
    const u16* __restrict__ Bfh, const u16* __restrict__ Bfl,
    const float* __restrict__ cvec,
    const float* __restrict__ var_p, const float* __restrict__ ls_p,
    float* __restrict__ out) {
    __shared__ u16 kh[12 * 8 * 64 * 8];   // 96 KB: B-frag K tile (hi)
    __shared__ float patch[128 * 36];     // 18 KB
    __shared__ float zsq[MM];
    __shared__ float xsq[128];
    __shared__ float red[1024];

    int tid = threadIdx.x;
    int np0 = blockIdx.x * 128;
    float var = var_p[0];
    float ls = ls_p[0];
    float c2 = -0.72134752044f / (ls * ls);   // -0.5*log2(e)/ls^2

    if (tid < MM) zsq[tid] = z2g[tid];
    for (int e = tid; e < 128 * 36; e += 512) {
        int pt = e / 36, c = e % 36;
        float v = 0.f;
        if (c < 25) {
            int np = np0 + pt;
            int n = np / PP, p = np % PP;
            int oi = p / 36, oj = p % 36;
            v = Xin[n * (HH * WW) + (oi + c / 5) * WW + (oj + c % 5)];
        }
        patch[e] = v;
    }
    __syncthreads();
    if (tid < 128) {
        float s = 0.f;
#pragma unroll
        for (int d = 0; d < LL; ++d) { float x = patch[tid * 36 + d]; s += x * x; }
        xsq[tid] = s;
    }
    __syncthreads();

    int w = tid >> 6, l = tid & 63;
    int u = l >> 4;

    u32 kpk[3][8][2];                     // packed bf16 K values (diag left factor)
    float mp[8] = {0.f, 0.f, 0.f, 0.f, 0.f, 0.f, 0.f, 0.f};

    // phase 1 in two 64-point halves: cross = Z @ patch^T, then K finalize.
#pragma unroll
    for (int h = 0; h < 2; ++h) {
        short8 pbh[4], pbl[4];
#pragma unroll
        for (int nt = 0; nt < 4; ++nt) {
            int p = h * 64 + nt * 16 + (l & 15);
            int pb = p * 36 + (u << 3);
            float4 f0 = *(const float4*)&patch[pb];
            float4 f1 = *(const float4*)&patch[pb + 4];
            float xv[8] = {f0.x, f0.y, f0.z, f0.w, f1.x, f1.y, f1.z, f1.w};
#pragma unroll
            for (int j = 0; j < 8; ++j) {
                u16 hh, lo;
                split_bf16(xv[j], hh, lo);
                pbh[nt][j] = (short)hh;
                pbl[nt][j] = (short)lo;
            }
        }
        floatx4 acc2[3][4];
#pragma unroll
        for (int i = 0; i < 3; ++i) {
            int zt = w * 3 + i;
            short8 zah = *(const short8*)&Zfh[(zt * 64 + l) * 8];
            short8 zal = *(const short8*)&Zfl[(zt * 64 + l) * 8];
#pragma unroll
            for (int nt = 0; nt < 4; ++nt) {
                floatx4 z = {0.f, 0.f, 0.f, 0.f};
                z = __builtin_amdgcn_mfma_f32_16x16x32_bf16(zah, pbh[nt], z, 0, 0, 0);
                z = __builtin_amdgcn_mfma_f32_16x16x32_bf16(zah, pbl[nt], z, 0, 0, 0);
                z = __builtin_amdgcn_mfma_f32_16x16x32_bf16(zal, pbh[nt], z, 0, 0, 0);
                acc2[i][nt] = z;
            }
        }
        // finalize K for this half
#pragma unroll
        for (int i = 0; i < 3; ++i) {
            int a2 = w * 3 + i;
            int kt = a2 >> 1;
            int rr = 2 * (a2 & 1) + (u >> 1);
            int k0 = a2 * 16 + 4 * u;
            float4 c4 = *(const float4*)&cvec[k0];
            float cvl[4] = {c4.x, c4.y, c4.z, c4.w};
#pragma unroll
            for (int nt = 0; nt < 4; ++nt) {
                int ntg = h * 4 + nt;
                int p = h * 64 + nt * 16 + (l & 15);
                u16 hi[4];
#pragma unroll
                for (int j = 0; j < 4; ++j) {
                    float s = zsq[k0 + j] + xsq[p] - 2.f * acc2[i][nt][j];
                    float v = var * exp2f(s * c2);
                    mp[ntg] += cvl[j] * v;
                    hi[j] = f2bf(v);
                }
                u32 p0 = (u32)hi[0] | ((u32)hi[1] << 16);
                u32 p1 = (u32)hi[2] | ((u32)hi[3] << 16);
                int base = ((kt * 8 + ntg) * 64 + rr * 16 + (l & 15)) * 8 + 4 * (u & 1);
                *(u32*)&kh[base]     = p0;
                *(u32*)&kh[base + 2] = p1;
                kpk[i][ntg][0] = p0;
                kpk[i][ntg][1] = p1;
            }
        }
    }

    // mean partials: wave-reduce, cross-wave via red
#pragma unroll
    for (int nt = 0; nt < 8; ++nt) {
        mp[nt] += __shfl_xor(mp[nt], 16);
        mp[nt] += __shfl_xor(mp[nt], 32);
    }
    if (l < 16) {
#pragma unroll
        for (int nt = 0; nt < 8; ++nt) red[w * 128 + nt * 16 + l] = mp[nt];
    }
    __syncthreads();   // publishes kh AND mean partials
    if (tid < 128) {
        float s = 0.f;
#pragma unroll
        for (int ww = 0; ww < 8; ++ww) s += red[ww * 128 + tid];
        out[np0 + tid] = s;   // mean
    }

    // phase 2: acc[m][p] = sum_k Bq[m][k] K[k][p]; B split 2-term, K hi only
    floatx4 acc[3][8];
#pragma unroll
    for (int i = 0; i < 3; ++i)
#pragma unroll
        for (int nt = 0; nt < 8; ++nt) { floatx4 z = {0.f, 0.f, 0.f, 0.f}; acc[i][nt] = z; }
    for (int kt = 0; kt < 12; ++kt) {
        short8 bh[8];
#pragma unroll
        for (int nt = 0; nt < 8; ++nt)
            bh[nt] = *(const short8*)&kh[((kt * 8 + nt) * 64 + l) * 8];
#pragma unroll
        for (int i = 0; i < 3; ++i) {
            int mt = w * 3 + i;
            int ab = ((mt * 12 + kt) * 64 + l) * 8;
            short8 ah = *(const short8*)&Bfh[ab];
            short8 al = *(const short8*)&Bfl[ab];
#pragma unroll
            for (int nt = 0; nt < 8; ++nt) {
                acc[i][nt] = __builtin_amdgcn_mfma_f32_16x16x32_bf16(ah, bh[nt], acc[i][nt], 0, 0, 0);
                acc[i][nt] = __builtin_amdgcn_mfma_f32_16x16x32_bf16(al, bh[nt], acc[i][nt], 0, 0, 0);
            }
        }
    }
    __syncthreads();   // mean readers done before red reuse

    // diag epilogue: register dot; left factor = K hi (same D-frag map)
    float dp[8] = {0.f, 0.f, 0.f, 0.f, 0.f, 0.f, 0.f, 0.f};
#pragma unroll
    for (int i = 0; i < 3; ++i)
#pragma unroll
        for (int nt = 0; nt < 8; ++nt) {
            float kv0 = bf2f((u16)(kpk[i][nt][0] & 0xFFFFu));
            float kv1 = bf2f((u16)(kpk[i][nt][0] >> 16));
            float kv2 = bf2f((u16)(kpk[i][nt][1] & 0xFFFFu));
            float kv3 = bf2f((u16)(kpk[i][nt][1] >> 16));
            dp[nt] += kv0 * acc[i][nt][0] + kv1 * acc[i][nt][1]
                    + kv2 * acc[i][nt][2] + kv3 * acc[i][nt][3];
        }
#pragma unroll
    for (int nt = 0; nt < 8; ++nt) {
        dp[nt] += __shfl_xor(dp[nt], 16);
        dp[nt] += __shfl_xor(dp[nt], 32);
    }
    if (l < 16) {
#pragma unroll
        for (int nt = 0; nt < 8; ++nt) red[w * 128 + nt * 16 + l] = dp[nt];
    }
    __syncthreads();
    if (tid < 128) {
        float s = 0.f;
#pragma unroll
        for (int ww = 0; ww < 8; ++ww) s += red[ww * 128 + tid];
        out[NPTS + np0 + tid] = var + s;
    }
}

// ---------------------------------------------------------------------------
extern "C" void kernel_launch(void* const* d_in, const int* in_sizes, int n_in,
                              void* d_out, int out_size, void* d_ws, size_t ws_size,
                              hipStream_t stream) {
    const float* Xin    = (const float*)d_in[0];
    const float* Z      = (const float*)d_in[1];
    const float* q_mu   = (const float*)d_in[2];
    const float* q_sqrt = (const float*)d_in[3];
    const float* var_p  = (const float*)d_in[4];
    const float* ls_p   = (const float*)d_in[5];
    float* out = (float*)d_out;

    const size_t HB = (size_t)FRAG_N * 2;  // 294912 B per frag half-array
    char* base = (char*)d_ws;
    float* Kuu = (float*)base;                 // 2 HB; Bq frags overlay later
    u16* Bqh = (u16*)base;
    u16* Bql = (u16*)(base + HB);
    u16* Xh_a = (u16*)(base + 2 * HB);         // Kuu frags overlay (used only in ns1)
    u16* Xl_a = (u16*)(base + 3 * HB);
    u16* Kfh = Xh_a;
    u16* Kfl = Xl_a;
    u16* Xh_b = (u16*)(base + 4 * HB);
    u16* Xl_b = (u16*)(base + 5 * HB);
    u16* Rh_a = (u16*)(base + 6 * HB);
    u16* Rl_a = (u16*)(base + 7 * HB);
    u16* Rh_b = (u16*)(base + 8 * HB);
    u16* Rl_b = (u16*)(base + 9 * HB);
    u16* Qh   = (u16*)(base + 10 * HB);        // Q frags; Y overlays later
    u16* Ql   = (u16*)(base + 11 * HB);
    u16* Yh = Qh;
    u16* Yl = Ql;
    u16* SKh  = (u16*)(base + 12 * HB);
    u16* SKl  = (u16*)(base + 13 * HB);
    char* pF = base + 14 * HB;
    u16* Zfh = (u16*)pF;
    u16* Zfl = (u16*)(pF + ZFRAG_N * 2);
    float* z2g  = (float*)(pF + ZFRAG_N * 4);
    float* cvec = z2g + MM;
    float* rsum = cvec + MM;

    // 1) prep: Kuu dense+frags, rowsums, z2, Z frags, Q frags
    prep_kernel<<<MM, 384, 0, stream>>>(Z, q_sqrt, var_p, ls_p, Kuu, rsum, z2g,
                                        Kfh, Kfl, Qh, Ql, Zfh, Zfl);
    // 2) ns1 (scaled seed a=1.7/maxrowsum): X1 | R1 | SK
    ns1_kernel<<<108, 256, 0, stream>>>(Kuu, rsum, Kfh, Kfl, Qh, Ql,
                                        Xh_b, Xl_b, Rh_b, Rl_b, SKh, SKl);
    // 3-6) NS rounds 2..5 (4 launches -> 5 total NS iterations with the
    //      scaled seed; plain seed needed 6 — round 9 failed at 5 unscaled)
    u16 *cxh = Xh_b, *cxl = Xl_b, *nxh = Xh_a, *nxl = Xl_a;
    u16 *crh = Rh_b, *crl = Rl_b, *nrh = Rh_a, *nrl = Rl_a;
    for (int it = 0; it < 4; ++it) {
        ns_kernel<<<72, 256, 0, stream>>>(cxh, cxl, crh, crl, nxh, nxl, nrh, nrl);
        u16* t;
        t = cxh; cxh = nxh; nxh = t;
        t = cxl; cxl = nxl; nxl = t;
        t = crh; crh = nrh; nrh = t;
        t = crl; crl = nrl; nrl = t;
    }
    // 7) Y = X@SK | cvec = X@q_mu
    y_kernel<<<42, 256, 0, stream>>>(cxh, cxl, SKh, SKl, q_mu, Yh, Yl, cvec);
    // 8) Bq = Y@X (into Kuu region)
    bq_kernel<<<36, 256, 0, stream>>>(Yh, Yl, cxh, cxl, Bqh, Bql);
    // 9) main (128 points/block, round-7 structure)
    main_kernel<<<NPTS / 128, 512, 0, stream>>>(Xin, Zfh, Zfl, z2g, Bqh, Bql, cvec,
                                                var_p, ls_p, out);
}

// Round 14
// 169.695 us; speedup vs baseline: 1.5737x; 1.0562x over previous
//
#include <hip/hip_runtime.h>
#include <hip/hip_bf16.h>

// Problem constants
#define HH 40
#define WW 40
#define KK 5
#define PP 1296            // 36*36
#define LL 25
#define MM 384
#define NN 64
#define NPTS (NN * PP)     // 82944
#define JITTER 1e-6f

typedef unsigned short u16;
typedef unsigned int   u32;
using short8  = __attribute__((ext_vector_type(8))) short;
using floatx4 = __attribute__((ext_vector_type(4))) float;

#define FRAG_N (MM * MM)        // u16 per frag half-array (147456)
#define ZFRAG_N (24 * 64 * 8)   // 12288

// ---------------------------------------------------------------------------
// bf16 split helpers (RNE)
__device__ inline u16 f2bf(float v) {
    u32 b = __float_as_uint(v);
    return (u16)((b + 0x7FFFu + ((b >> 16) & 1u)) >> 16);
}
__device__ inline float bf2f(u16 h) { return __uint_as_float(((u32)h) << 16); }
__device__ inline void split_bf16(float v, u16& hi, u16& lo) {
    hi = f2bf(v);
    lo = f2bf(v - bf2f(hi));
}

// A-fragment linear index (u16 units) for element (m,k), HW-verified rounds 2-13.
__device__ inline int frag_idx(int m, int k) {
    return (((m >> 4) * 12 + (k >> 5)) * 64 + ((m & 15) + (((k >> 3) & 3) << 4))) * 8 + (k & 7);
}

// ---------------------------------------------------------------------------
// Split-bf16 MFMA 64x64-tile GEMM on A-frag operands: C = A . B^T_storage.
__device__ inline void frag_gemm64(const u16* __restrict__ Ah, const u16* __restrict__ Al,
                                   const u16* __restrict__ Bh, const u16* __restrict__ Bl,
                                   int bi, int bj, int w, int l, floatx4 acc[2][2]) {
    int mt0 = bi * 4 + 2 * (w & 1);
    int nt0 = bj * 4 + 2 * (w >> 1);
#pragma unroll
    for (int i = 0; i < 2; ++i)
#pragma unroll
        for (int jn = 0; jn < 2; ++jn) { floatx4 z = {0.f, 0.f, 0.f, 0.f}; acc[i][jn] = z; }
    for (int kt = 0; kt < 12; ++kt) {
        int ab0 = (((mt0 + 0) * 12 + kt) * 64 + l) * 8;
        int ab1 = (((mt0 + 1) * 12 + kt) * 64 + l) * 8;
        int bb0 = (((nt0 + 0) * 12 + kt) * 64 + l) * 8;
        int bb1 = (((nt0 + 1) * 12 + kt) * 64 + l) * 8;
        short8 a0h = *(const short8*)&Ah[ab0];
        short8 a0l = *(const short8*)&Al[ab0];
        short8 a1h = *(const short8*)&Ah[ab1];
        short8 a1l = *(const short8*)&Al[ab1];
        short8 b0h = *(const short8*)&Bh[bb0];
        short8 b0l = *(const short8*)&Bl[bb0];
        short8 b1h = *(const short8*)&Bh[bb1];
        short8 b1l = *(const short8*)&Bl[bb1];
        acc[0][0] = __builtin_amdgcn_mfma_f32_16x16x32_bf16(a0h, b0h, acc[0][0], 0, 0, 0);
        acc[0][0] = __builtin_amdgcn_mfma_f32_16x16x32_bf16(a0h, b0l, acc[0][0], 0, 0, 0);
        acc[0][0] = __builtin_amdgcn_mfma_f32_16x16x32_bf16(a0l, b0h, acc[0][0], 0, 0, 0);
        acc[0][1] = __builtin_amdgcn_mfma_f32_16x16x32_bf16(a0h, b1h, acc[0][1], 0, 0, 0);
        acc[0][1] = __builtin_amdgcn_mfma_f32_16x16x32_bf16(a0h, b1l, acc[0][1], 0, 0, 0);
        acc[0][1] = __builtin_amdgcn_mfma_f32_16x16x32_bf16(a0l, b1h, acc[0][1], 0, 0, 0);
        acc[1][0] = __builtin_amdgcn_mfma_f32_16x16x32_bf16(a1h, b0h, acc[1][0], 0, 0, 0);
        acc[1][0] = __builtin_amdgcn_mfma_f32_16x16x32_bf16(a1h, b0l, acc[1][0], 0, 0, 0);
        acc[1][0] = __builtin_amdgcn_mfma_f32_16x16x32_bf16(a1l, b0h, acc[1][0], 0, 0, 0);
        acc[1][1] = __builtin_amdgcn_mfma_f32_16x16x32_bf16(a1h, b1h, acc[1][1], 0, 0, 0);
        acc[1][1] = __builtin_amdgcn_mfma_f32_16x16x32_bf16(a1h, b1l, acc[1][1], 0, 0, 0);
        acc[1][1] = __builtin_amdgcn_mfma_f32_16x16x32_bf16(a1l, b1h, acc[1][1], 0, 0, 0);
    }
}

__device__ inline void dwrite_frag(u16* __restrict__ Oh, u16* __restrict__ Ol,
                                   int m, int p, float v) {
    int idx = frag_idx(m, p);
    u16 hi, lo;
    split_bf16(v, hi, lo);
    Oh[idx] = hi; Ol[idx] = lo;
}

// ---------------------------------------------------------------------------
// Launch 1: Kuu dense + Kuu frags + rowsums + z2 + Z frags + Q frags.
__global__ void __launch_bounds__(384) prep_kernel(
    const float* __restrict__ Z, const float* __restrict__ q_sqrt,
    const float* __restrict__ var_p, const float* __restrict__ ls_p,
    float* __restrict__ Kuu, float* __restrict__ rsum, float* __restrict__ z2g,
    u16* __restrict__ Kfh, u16* __restrict__ Kfl,
    u16* __restrict__ Qh, u16* __restrict__ Ql,
    u16* __restrict__ Zfh, u16* __restrict__ Zfl) {
    __shared__ float Zs[LL];
    __shared__ float red[384];
    int r = blockIdx.x, tid = threadIdx.x;
    if (tid < LL) Zs[tid] = Z[r * LL + tid];
    __syncthreads();
    float var = var_p[0];
    float ls = ls_p[0];
    float c0 = -0.5f / (ls * ls);
    float s = 0.f;
#pragma unroll
    for (int d = 0; d < LL; ++d) {
        float dd = Zs[d] - Z[tid * LL + d];
        s += dd * dd;
    }
    float v = var * expf(c0 * s);
    if (tid == r) v += JITTER;
    Kuu[r * MM + tid] = v;
    red[tid] = v;
    __syncthreads();
    if (tid < 128) red[tid] += red[tid + 256];
    __syncthreads();
    for (int o = 128; o > 0; o >>= 1) {
        if (tid < o) red[tid] += red[tid + o];
        __syncthreads();
    }
    if (tid == 0) {
        rsum[r] = red[0];
        float t = 0.f;
#pragma unroll
        for (int d = 0; d < LL; ++d) t += Zs[d] * Zs[d];
        z2g[r] = t;
    }
    // frag-order writes: one element per thread (384*384 == FRAG_N)
    {
        int o = r * MM + tid;
        int j = o & 7, ln = (o >> 3) & 63, kt = (o >> 9) % 12, mt = o / 6144;
        int m = mt * 16 + (ln & 15);
        int k = kt * 32 + ((ln >> 4) << 3) + j;
        u16 h, lo;
        // Q frag
        float qv = (k <= m) ? q_sqrt[m * MM + k] : 0.f;
        split_bf16(qv, h, lo);
        Qh[o] = h; Ql[o] = lo;
        // Kuu frag (recompute distance for (m,k))
        float s2 = 0.f;
#pragma unroll
        for (int d = 0; d < LL; ++d) {
            float dd = Z[m * LL + d] - Z[k * LL + d];
            s2 += dd * dd;
        }
        float kv = var * expf(c0 * s2);
        if (m == k) kv += JITTER;
        split_bf16(kv, h, lo);
        Kfh[o] = h; Kfl[o] = lo;
        // Z frag
        if (o < ZFRAG_N) {
            int zt = o >> 9;
            int mz = zt * 16 + (ln & 15);
            int kd = ((ln >> 4) << 3) + j;
            float zv = (kd < LL) ? Z[mz * LL + kd] : 0.f;
            split_bf16(zv, h, lo);
            Zfh[o] = h; Zfl[o] = lo;
        }
    }
}

// ---------------------------------------------------------------------------
// Launch 2: blocks 0-35: X1 = a*(2I - a*Kuu);
//           36-71: R1 = I - 2a*K + a^2*(K@K)  (K frags from prep);
//           72-107: SK = Q@Q^T - Kuu.
// a = 1.7/maxrowsum (scaled seed, verified round 13: 5 NS its at the floor).
__global__ void __launch_bounds__(256) ns1_kernel(
    const float* __restrict__ Kuu, const float* __restrict__ rsum,
    const u16* __restrict__ Kfh, const u16* __restrict__ Kfl,
    const u16* __restrict__ Qh, const u16* __restrict__ Ql,
    u16* __restrict__ Xh, u16* __restrict__ Xl,
    u16* __restrict__ Rh, u16* __restrict__ Rl,
    u16* __restrict__ SKh, u16* __restrict__ SKl) {
    __shared__ float red[256];
    int tid = threadIdx.x, blk = blockIdx.x;
    int w = tid >> 6, l = tid & 63;
    float alpha = 0.f;
    if (blk < 72) {
        float v0 = rsum[tid];
        if (tid < 128) v0 = fmaxf(v0, rsum[tid + 256]);
        red[tid] = v0;
        __syncthreads();
        for (int o = 128; o > 0; o >>= 1) {
            if (tid < o) red[tid] = fmaxf(red[tid], red[tid + o]);
            __syncthreads();
        }
        alpha = 1.7f / red[0];   // scaled seed
    }
    if (blk < 36) {
        float a2 = alpha * alpha;
        for (int o = blk * 256 + tid; o < FRAG_N; o += 36 * 256) {
            int j = o & 7, ln = (o >> 3) & 63, kt = (o >> 9) % 12, mt = o / 6144;
            int m = mt * 16 + (ln & 15);
            int k = kt * 32 + ((ln >> 4) << 3) + j;
            float v = ((m == k) ? 2.f * alpha : 0.f) - a2 * Kuu[m * MM + k];
            u16 h, lo;
            split_bf16(v, h, lo);
            Xh[o] = h; Xl[o] = lo;
        }
    } else if (blk < 72) {
        int tile = blk - 36;
        int bi = tile / 6, bj = tile % 6;
        floatx4 acc[2][2];
        frag_gemm64(Kfh, Kfl, Kfh, Kfl, bi, bj, w, l, acc);   // K @ K
        int mt0 = bi * 4 + 2 * (w & 1), nt0 = bj * 4 + 2 * (w >> 1);
        float a2 = alpha * alpha;
#pragma unroll
        for (int i = 0; i < 2; ++i)
#pragma unroll
            for (int jn = 0; jn < 2; ++jn)
#pragma unroll
                for (int j = 0; j < 4; ++j) {
                    int m = (mt0 + i) * 16 + ((l >> 4) << 2) + j;
                    int p = (nt0 + jn) * 16 + (l & 15);
                    float v = a2 * acc[i][jn][j] - 2.f * alpha * Kuu[m * MM + p]
                            + ((m == p) ? 1.f : 0.f);
                    dwrite_frag(Rh, Rl, m, p, v);
                }
    } else {
        int tile = blk - 72;
        int bi = tile / 6, bj = tile % 6;
        floatx4 acc[2][2];
        frag_gemm64(Qh, Ql, Qh, Ql, bi, bj, w, l, acc);
        int mt0 = bi * 4 + 2 * (w & 1), nt0 = bj * 4 + 2 * (w >> 1);
#pragma unroll
        for (int i = 0; i < 2; ++i)
#pragma unroll
            for (int jn = 0; jn < 2; ++jn)
#pragma unroll
                for (int j = 0; j < 4; ++j) {
                    int m = (mt0 + i) * 16 + ((l >> 4) << 2) + j;
                    int p = (nt0 + jn) * 16 + (l & 15);
                    dwrite_frag(SKh, SKl, m, p, acc[i][jn][j] - Kuu[m * MM + p]);
                }
    }
}

// ---------------------------------------------------------------------------
// NS rounds: blocks 0-35: X' = X + X@R ; 36-71: R' = R@R
__global__ void __launch_bounds__(256) ns_kernel(
    const u16* __restrict__ cxh, const u16* __restrict__ cxl,
    const u16* __restrict__ crh, const u16* __restrict__ crl,
    u16* __restrict__ nxh, u16* __restrict__ nxl,
    u16* __restrict__ nrh, u16* __restrict__ nrl) {
    int blk = blockIdx.x, tid = threadIdx.x;
    bool isX = (blk < 36);
    int tile = isX ? blk : blk - 36;
    int bi = tile / 6, bj = tile % 6;
    int w = tid >> 6, l = tid & 63;
    floatx4 acc[2][2];
    frag_gemm64(isX ? cxh : crh, isX ? cxl : crl, crh, crl, bi, bj, w, l, acc);
    int mt0 = bi * 4 + 2 * (w & 1), nt0 = bj * 4 + 2 * (w >> 1);
    u16* Oh = isX ? nxh : nrh;
    u16* Ol = isX ? nxl : nrl;
#pragma unroll
    for (int i = 0; i < 2; ++i)
#pragma unroll
        for (int jn = 0; jn < 2; ++jn)
#pragma unroll
            for (int j = 0; j < 4; ++j) {
                int m = (mt0 + i) * 16 + ((l >> 4) << 2) + j;
                int p = (nt0 + jn) * 16 + (l & 15);
                float v = acc[i][jn][j];
                if (isX) {
                    int id = frag_idx(m, p);
                    v += bf2f(cxh[id]) + bf2f(cxl[id]);
                }
                dwrite_frag(Oh, Ol, m, p, v);
            }
}

// ---------------------------------------------------------------------------
// Launch 7: blocks 0-35: Y = X @ SK ; blocks 36-41: cvec = X @ q_mu
__global__ void __launch_bounds__(256) y_kernel(
    const u16* __restrict__ Xh, const u16* __restrict__ Xl,
    const u16* __restrict__ SKh, const u16* __restrict__ SKl,
    const float* __restrict__ qmu,
    u16* __restrict__ Yh, u16* __restrict__ Yl, float* __restrict__ cvec) {
    __shared__ float q[MM];
    int tid = threadIdx.x, blk = blockIdx.x;
    int w = tid >> 6, l = tid & 63;
    if (blk < 36) {
        int bi = blk / 6, bj = blk % 6;
        floatx4 acc[2][2];
        frag_gemm64(Xh, Xl, SKh, SKl, bi, bj, w, l, acc);
        int mt0 = bi * 4 + 2 * (w & 1), nt0 = bj * 4 + 2 * (w >> 1);
#pragma unroll
        for (int i = 0; i < 2; ++i)
#pragma unroll
            for (int jn = 0; jn < 2; ++jn)
#pragma unroll
                for (int j = 0; j < 4; ++j) {
                    int m = (mt0 + i) * 16 + ((l >> 4) << 2) + j;
                    int p = (nt0 + jn) * 16 + (l & 15);
                    dwrite_frag(Yh, Yl, m, p, acc[i][jn][j]);
                }
    } else {
        if (tid < MM) q[tid] = qmu[tid];
        if (tid + 256 < MM) q[tid + 256] = qmu[tid + 256];
        __syncthreads();
        int mt = (blk - 36) * 4 + w;
        float s = 0.f;
        for (int kt = 0; kt < 12; ++kt) {
            int b = ((mt * 12 + kt) * 64 + l) * 8;
            short8 h8 = *(const short8*)&Xh[b];
            short8 l8 = *(const short8*)&Xl[b];
            int kb = kt * 32 + ((l >> 4) << 3);
#pragma unroll
            for (int j = 0; j < 8; ++j)
                s += (bf2f((u16)h8[j]) + bf2f((u16)l8[j])) * q[kb + j];
        }
        s += __shfl_xor(s, 16);
        s += __shfl_xor(s, 32);
        if (l < 16) cvec[mt * 16 + l] = s;
    }
}

// Launch 8: Bq = Y @ X — writes HI half only (main reads Bq-hi only; the
// lo-term's 2^-9 relative error is the same class as the K-lo drop already
// verified invisible at the bf16 output floor).
__global__ void __launch_bounds__(256) bq_kernel(
    const u16* __restrict__ Yh, const u16* __restrict__ Yl,
    const u16* __restrict__ Xh, const u16* __restrict__ Xl,
    u16* __restrict__ Bh) {
    int blk = blockIdx.x, tid = threadIdx.x;
    int bi = blk / 6, bj = blk % 6;
    int w = tid >> 6, l = tid & 63;
    floatx4 acc[2][2];
    frag_gemm64(Yh, Yl, Xh, Xl, bi, bj, w, l, acc);
    int mt0 = bi * 4 + 2 * (w & 1), nt0 = bj * 4 + 2 * (w >> 1);
#pragma unroll
    for (int i = 0; i < 2; ++i)
#pragma unroll
        for (int jn = 0; jn < 2; ++jn)
#pragma unroll
            for (int j = 0; j < 4; ++j) {
                int m = (mt0 + i) * 16 + ((l >> 4) << 2) + j;
                int p = (nt0 + jn) * 16 + (l & 15);
                Bh[frag_idx(m, p)] = f2bf(acc[i][jn][j]);
            }
}

// ---------------------------------------------------------------------------
// Main fused kernel — round-12 structure with single-term (hi-only) Bq in
// phase 2: halves the 765 MB Bq L2 stream and the phase-2 MFMA count.
__global__ void __launch_bounds__(512) main_kernel(
    const float* __restrict__ Xin,
    const u16* __restrict__ Zfh, const u16* __restrict__ Zfl,
    const float* __restrict__ z2g,
    const u16* __restrict__ Bfh,
    const float* __restrict__ cvec,
    const float* __restrict__ var_p, const float* __restrict__ ls_p,
    float* __restrict__ out) {
    __shared__ u16 kh[12 * 8 * 64 * 8];   // 96 KB: B-frag K tile (hi)
    __shared__ float patch[128 * 36];     // 18 KB
    __shared__ float zsq[MM];
    __shared__ float xsq[128];
    __shared__ float red[1024];

    int tid = threadIdx.x;
    int np0 = blockIdx.x * 128;
    float var = var_p[0];
    float ls = ls_p[0];
    float c2 = -0.72134752044f / (ls * ls);   // -0.5*log2(e)/ls^2

    if (tid < MM) zsq[tid] = z2g[tid];
    for (int e = tid; e < 128 * 36; e += 512) {
        int pt = e / 36, c = e % 36;
        float v = 0.f;
        if (c < 25) {
            int np = np0 + pt;
            int n = np / PP, p = np % PP;
            int oi = p / 36, oj = p % 36;
            v = Xin[n * (HH * WW) + (oi + c / 5) * WW + (oj + c % 5)];
        }
        patch[e] = v;
    }
    __syncthreads();
    if (tid < 128) {
        float s = 0.f;
#pragma unroll
        for (int d = 0; d < LL; ++d) { float x = patch[tid * 36 + d]; s += x * x; }
        xsq[tid] = s;
    }
    __syncthreads();

    int w = tid >> 6, l = tid & 63;
    int u = l >> 4;

    u32 kpk[3][8][2];                     // packed bf16 K values (diag left factor)
    float mp[8] = {0.f, 0.f, 0.f, 0.f, 0.f, 0.f, 0.f, 0.f};

    // phase 1 in two 64-point halves: cross = Z @ patch^T, then K finalize.
#pragma unroll
    for (int h = 0; h < 2; ++h) {
        short8 pbh[4], pbl[4];
#pragma unroll
        for (int nt = 0; nt < 4; ++nt) {
            int p = h * 64 + nt * 16 + (l & 15);
            int pb = p * 36 + (u << 3);
            float4 f0 = *(const float4*)&patch[pb];
            float4 f1 = *(const float4*)&patch[pb + 4];
            float xv[8] = {f0.x, f0.y, f0.z, f0.w, f1.x, f1.y, f1.z, f1.w};
#pragma unroll
            for (int j = 0; j < 8; ++j) {
                u16 hh, lo;
                split_bf16(xv[j], hh, lo);
                pbh[nt][j] = (short)hh;
                pbl[nt][j] = (short)lo;
            }
        }
        floatx4 acc2[3][4];
#pragma unroll
        for (int i = 0; i < 3; ++i) {
            int zt = w * 3 + i;
            short8 zah = *(const short8*)&Zfh[(zt * 64 + l) * 8];
            short8 zal = *(const short8*)&Zfl[(zt * 64 + l) * 8];
#pragma unroll
            for (int nt = 0; nt < 4; ++nt) {
                floatx4 z = {0.f, 0.f, 0.f, 0.f};
                z = __builtin_amdgcn_mfma_f32_16x16x32_bf16(zah, pbh[nt], z, 0, 0, 0);
                z = __builtin_amdgcn_mfma_f32_16x16x32_bf16(zah, pbl[nt], z, 0, 0, 0);
                z = __builtin_amdgcn_mfma_f32_16x16x32_bf16(zal, pbh[nt], z, 0, 0, 0);
                acc2[i][nt] = z;
            }
        }
        // finalize K for this half
#pragma unroll
        for (int i = 0; i < 3; ++i) {
            int a2 = w * 3 + i;
            int kt = a2 >> 1;
            int rr = 2 * (a2 & 1) + (u >> 1);
            int k0 = a2 * 16 + 4 * u;
            float4 c4 = *(const float4*)&cvec[k0];
            float cvl[4] = {c4.x, c4.y, c4.z, c4.w};
#pragma unroll
            for (int nt = 0; nt < 4; ++nt) {
                int ntg = h * 4 + nt;
                int p = h * 64 + nt * 16 + (l & 15);
                u16 hi[4];
#pragma unroll
                for (int j = 0; j < 4; ++j) {
                    float s = zsq[k0 + j] + xsq[p] - 2.f * acc2[i][nt][j];
                    float v = var * exp2f(s * c2);
                    mp[ntg] += cvl[j] * v;
                    hi[j] = f2bf(v);
                }
                u32 p0 = (u32)hi[0] | ((u32)hi[1] << 16);
                u32 p1 = (u32)hi[2] | ((u32)hi[3] << 16);
                int base = ((kt * 8 + ntg) * 64 + rr * 16 + (l & 15)) * 8 + 4 * (u & 1);
                *(u32*)&kh[base]     = p0;
                *(u32*)&kh[base + 2] = p1;
                kpk[i][ntg][0] = p0;
                kpk[i][ntg][1] = p1;
            }
        }
    }

    // mean partials: wave-reduce, cross-wave via red
#pragma unroll
    for (int nt = 0; nt < 8; ++nt) {
        mp[nt] += __shfl_xor(mp[nt], 16);
        mp[nt] += __shfl_xor(mp[nt], 32);
    }
    if (l < 16) {
#pragma unroll
        for (int nt = 0; nt < 8; ++nt) red[w * 128 + nt * 16 + l] = mp[nt];
    }
    __syncthreads();   // publishes kh AND mean partials
    if (tid < 128) {
        float s = 0.f;
#pragma unroll
        for (int ww = 0; ww < 8; ++ww) s += red[ww * 128 + tid];
        out[np0 + tid] = s;   // mean
    }

    // phase 2: acc[m][p] = sum_k Bq[m][k] K[k][p]; Bq hi-only, K hi-only
    floatx4 acc[3][8];
#pragma unroll
    for (int i = 0; i < 3; ++i)
#pragma unroll
        for (int nt = 0; nt < 8; ++nt) { floatx4 z = {0.f, 0.f, 0.f, 0.f}; acc[i][nt] = z; }
    for (int kt = 0; kt < 12; ++kt) {
        short8 bh[8];
#pragma unroll
        for (int nt = 0; nt < 8; ++nt)
            bh[nt] = *(const short8*)&kh[((kt * 8 + nt) * 64 + l) * 8];
#pragma unroll
        for (int i = 0; i < 3; ++i) {
            int mt = w * 3 + i;
            int ab = ((mt * 12 + kt) * 64 + l) * 8;
            short8 ah = *(const short8*)&Bfh[ab];
#pragma unroll
            for (int nt = 0; nt < 8; ++nt)
                acc[i][nt] = __builtin_amdgcn_mfma_f32_16x16x32_bf16(ah, bh[nt], acc[i][nt], 0, 0, 0);
        }
    }
    __syncthreads();   // mean readers done before red reuse

    // diag epilogue: register dot; left factor = K hi (same D-frag map)
    float dp[8] = {0.f, 0.f, 0.f, 0.f, 0.f, 0.f, 0.f, 0.f};
#pragma unroll
    for (int i = 0; i < 3; ++i)
#pragma unroll
        for (int nt = 0; nt < 8; ++nt) {
            float kv0 = bf2f((u16)(kpk[i][nt][0] & 0xFFFFu));
            float kv1 = bf2f((u16)(kpk[i][nt][0] >> 16));
            float kv2 = bf2f((u16)(kpk[i][nt][1] & 0xFFFFu));
            float kv3 = bf2f((u16)(kpk[i][nt][1] >> 16));
            dp[nt] += kv0 * acc[i][nt][0] + kv1 * acc[i][nt][1]
                    + kv2 * acc[i][nt][2] + kv3 * acc[i][nt][3];
        }
#pragma unroll
    for (int nt = 0; nt < 8; ++nt) {
        dp[nt] += __shfl_xor(dp[nt], 16);
        dp[nt] += __shfl_xor(dp[nt], 32);
    }
    if (l < 16) {
#pragma unroll
        for (int nt = 0; nt < 8; ++nt) red[w * 128 + nt * 16 + l] = dp[nt];
    }
    __syncthreads();
    if (tid < 128) {
        float s = 0.f;
#pragma unroll
        for (int ww = 0; ww < 8; ++ww) s += red[ww * 128 + tid];
        out[NPTS + np0 + tid] = var + s;
    }
}

// ---------------------------------------------------------------------------
extern "C" void kernel_launch(void* const* d_in, const int* in_sizes, int n_in,
                              void* d_out, int out_size, void* d_ws, size_t ws_size,
                              hipStream_t stream) {
    const float* Xin    = (const float*)d_in[0];
    const float* Z      = (const float*)d_in[1];
    const float* q_mu   = (const float*)d_in[2];
    const float* q_sqrt = (const float*)d_in[3];
    const float* var_p  = (const float*)d_in[4];
    const float* ls_p   = (const float*)d_in[5];
    float* out = (float*)d_out;

    const size_t HB = (size_t)FRAG_N * 2;  // 294912 B per frag half-array
    char* base = (char*)d_ws;
    float* Kuu = (float*)base;                 // 2 HB; Bq-hi overlays later
    u16* Bqh = (u16*)base;
    u16* Xh_a = (u16*)(base + 2 * HB);         // Kuu frags overlay (used only in ns1)
    u16* Xl_a = (u16*)(base + 3 * HB);
    u16* Kfh = Xh_a;
    u16* Kfl = Xl_a;
    u16* Xh_b = (u16*)(base + 4 * HB);
    u16* Xl_b = (u16*)(base + 5 * HB);
    u16* Rh_a = (u16*)(base + 6 * HB);
    u16* Rl_a = (u16*)(base + 7 * HB);
    u16* Rh_b = (u16*)(base + 8 * HB);
    u16* Rl_b = (u16*)(base + 9 * HB);
    u16* Qh   = (u16*)(base + 10 * HB);        // Q frags; Y overlays later
    u16* Ql   = (u16*)(base + 11 * HB);
    u16* Yh = Qh;
    u16* Yl = Ql;
    u16* SKh  = (u16*)(base + 12 * HB);
    u16* SKl  = (u16*)(base + 13 * HB);
    char* pF = base + 14 * HB;
    u16* Zfh = (u16*)pF;
    u16* Zfl = (u16*)(pF + ZFRAG_N * 2);
    float* z2g  = (float*)(pF + ZFRAG_N * 4);
    float* cvec = z2g + MM;
    float* rsum = cvec + MM;

    // 1) prep: Kuu dense+frags, rowsums, z2, Z frags, Q frags
    prep_kernel<<<MM, 384, 0, stream>>>(Z, q_sqrt, var_p, ls_p, Kuu, rsum, z2g,
                                        Kfh, Kfl, Qh, Ql, Zfh, Zfl);
    // 2) ns1 (scaled seed a=1.7/maxrowsum): X1 | R1 | SK
    ns1_kernel<<<108, 256, 0, stream>>>(Kuu, rsum, Kfh, Kfl, Qh, Ql,
                                        Xh_b, Xl_b, Rh_b, Rl_b, SKh, SKl);
    // 3-6) NS rounds 2..5 (4 launches -> 5 total NS iterations w/ scaled seed)
    u16 *cxh = Xh_b, *cxl = Xl_b, *nxh = Xh_a, *nxl = Xl_a;
    u16 *crh = Rh_b, *crl = Rl_b, *nrh = Rh_a, *nrl = Rl_a;
    for (int it = 0; it < 4; ++it) {
        ns_kernel<<<72, 256, 0, stream>>>(cxh, cxl, crh, crl, nxh, nxl, nrh, nrl);
        u16* t;
        t = cxh; cxh = nxh; nxh = t;
        t = cxl; cxl = nxl; nxl = t;
        t = crh; crh = nrh; nrh = t;
        t = crl; crl = nrl; nrl = t;
    }
    // 7) Y = X@SK | cvec = X@q_mu
    y_kernel<<<42, 256, 0, stream>>>(cxh, cxl, SKh, SKl, q_mu, Yh, Yl, cvec);
    // 8) Bq = Y@X, hi only (into Kuu region)
    bq_kernel<<<36, 256, 0, stream>>>(Yh, Yl, cxh, cxl, Bqh);
    // 9) main (128 points/block, hi-only Bq phase 2)
    main_kernel<<<NPTS / 128, 512, 0, stream>>>(Xin, Zfh, Zfl, z2g, Bqh, cvec,
                                                var_p, ls_p, out);
}

// Round 15
// 161.314 us; speedup vs baseline: 1.6555x; 1.0520x over previous
//
#include <hip/hip_runtime.h>
#include <hip/hip_bf16.h>

// Problem constants
#define HH 40
#define WW 40
#define KK 5
#define PP 1296            // 36*36
#define LL 25
#define MM 384
#define NN 64
#define NPTS (NN * PP)     // 82944
#define JITTER 1e-6f

typedef unsigned short u16;
typedef unsigned int   u32;
using short8  = __attribute__((ext_vector_type(8))) short;
using floatx4 = __attribute__((ext_vector_type(4))) float;

#define FRAG_N (MM * MM)        // u16 per frag half-array (147456)
#define ZFRAG_N (24 * 64 * 8)   // 12288

// ---------------------------------------------------------------------------
// bf16 split helpers (RNE)
__device__ inline u16 f2bf(float v) {
    u32 b = __float_as_uint(v);
    return (u16)((b + 0x7FFFu + ((b >> 16) & 1u)) >> 16);
}
__device__ inline float bf2f(u16 h) { return __uint_as_float(((u32)h) << 16); }
__device__ inline void split_bf16(float v, u16& hi, u16& lo) {
    hi = f2bf(v);
    lo = f2bf(v - bf2f(hi));
}

// A-fragment linear index (u16 units) for element (m,k), HW-verified rounds 2-14.
__device__ inline int frag_idx(int m, int k) {
    return (((m >> 4) * 12 + (k >> 5)) * 64 + ((m & 15) + (((k >> 3) & 3) << 4))) * 8 + (k & 7);
}

// ---------------------------------------------------------------------------
// Split-bf16 MFMA 64x64-tile GEMM on A-frag operands: C = A . B^T_storage.
__device__ inline void frag_gemm64(const u16* __restrict__ Ah, const u16* __restrict__ Al,
                                   const u16* __restrict__ Bh, const u16* __restrict__ Bl,
                                   int bi, int bj, int w, int l, floatx4 acc[2][2]) {
    int mt0 = bi * 4 + 2 * (w & 1);
    int nt0 = bj * 4 + 2 * (w >> 1);
#pragma unroll
    for (int i = 0; i < 2; ++i)
#pragma unroll
        for (int jn = 0; jn < 2; ++jn) { floatx4 z = {0.f, 0.f, 0.f, 0.f}; acc[i][jn] = z; }
    for (int kt = 0; kt < 12; ++kt) {
        int ab0 = (((mt0 + 0) * 12 + kt) * 64 + l) * 8;
        int ab1 = (((mt0 + 1) * 12 + kt) * 64 + l) * 8;
        int bb0 = (((nt0 + 0) * 12 + kt) * 64 + l) * 8;
        int bb1 = (((nt0 + 1) * 12 + kt) * 64 + l) * 8;
        short8 a0h = *(const short8*)&Ah[ab0];
        short8 a0l = *(const short8*)&Al[ab0];
        short8 a1h = *(const short8*)&Ah[ab1];
        short8 a1l = *(const short8*)&Al[ab1];
        short8 b0h = *(const short8*)&Bh[bb0];
        short8 b0l = *(const short8*)&Bl[bb0];
        short8 b1h = *(const short8*)&Bh[bb1];
        short8 b1l = *(const short8*)&Bl[bb1];
        acc[0][0] = __builtin_amdgcn_mfma_f32_16x16x32_bf16(a0h, b0h, acc[0][0], 0, 0, 0);
        acc[0][0] = __builtin_amdgcn_mfma_f32_16x16x32_bf16(a0h, b0l, acc[0][0], 0, 0, 0);
        acc[0][0] = __builtin_amdgcn_mfma_f32_16x16x32_bf16(a0l, b0h, acc[0][0], 0, 0, 0);
        acc[0][1] = __builtin_amdgcn_mfma_f32_16x16x32_bf16(a0h, b1h, acc[0][1], 0, 0, 0);
        acc[0][1] = __builtin_amdgcn_mfma_f32_16x16x32_bf16(a0h, b1l, acc[0][1], 0, 0, 0);
        acc[0][1] = __builtin_amdgcn_mfma_f32_16x16x32_bf16(a0l, b1h, acc[0][1], 0, 0, 0);
        acc[1][0] = __builtin_amdgcn_mfma_f32_16x16x32_bf16(a1h, b0h, acc[1][0], 0, 0, 0);
        acc[1][0] = __builtin_amdgcn_mfma_f32_16x16x32_bf16(a1h, b0l, acc[1][0], 0, 0, 0);
        acc[1][0] = __builtin_amdgcn_mfma_f32_16x16x32_bf16(a1l, b0h, acc[1][0], 0, 0, 0);
        acc[1][1] = __builtin_amdgcn_mfma_f32_16x16x32_bf16(a1h, b1h, acc[1][1], 0, 0, 0);
        acc[1][1] = __builtin_amdgcn_mfma_f32_16x16x32_bf16(a1h, b1l, acc[1][1], 0, 0, 0);
        acc[1][1] = __builtin_amdgcn_mfma_f32_16x16x32_bf16(a1l, b1h, acc[1][1], 0, 0, 0);
    }
}

__device__ inline void dwrite_frag(u16* __restrict__ Oh, u16* __restrict__ Ol,
                                   int m, int p, float v) {
    int idx = frag_idx(m, p);
    u16 hi, lo;
    split_bf16(v, hi, lo);
    Oh[idx] = hi; Ol[idx] = lo;
}

// ---------------------------------------------------------------------------
// Launch 1: Kuu dense + Kuu frags + rowsums + z2 + Z frags + Q frags.
__global__ void __launch_bounds__(384) prep_kernel(
    const float* __restrict__ Z, const float* __restrict__ q_sqrt,
    const float* __restrict__ var_p, const float* __restrict__ ls_p,
    float* __restrict__ Kuu, float* __restrict__ rsum, float* __restrict__ z2g,
    u16* __restrict__ Kfh, u16* __restrict__ Kfl,
    u16* __restrict__ Qh, u16* __restrict__ Ql,
    u16* __restrict__ Zfh, u16* __restrict__ Zfl) {
    __shared__ float Zs[LL];
    __shared__ float red[384];
    int r = blockIdx.x, tid = threadIdx.x;
    if (tid < LL) Zs[tid] = Z[r * LL + tid];
    __syncthreads();
    float var = var_p[0];
    float ls = ls_p[0];
    float c0 = -0.5f / (ls * ls);
    float s = 0.f;
#pragma unroll
    for (int d = 0; d < LL; ++d) {
        float dd = Zs[d] - Z[tid * LL + d];
        s += dd * dd;
    }
    float v = var * expf(c0 * s);
    if (tid == r) v += JITTER;
    Kuu[r * MM + tid] = v;
    red[tid] = v;
    __syncthreads();
    if (tid < 128) red[tid] += red[tid + 256];
    __syncthreads();
    for (int o = 128; o > 0; o >>= 1) {
        if (tid < o) red[tid] += red[tid + o];
        __syncthreads();
    }
    if (tid == 0) {
        rsum[r] = red[0];
        float t = 0.f;
#pragma unroll
        for (int d = 0; d < LL; ++d) t += Zs[d] * Zs[d];
        z2g[r] = t;
    }
    // frag-order writes: one element per thread (384*384 == FRAG_N)
    {
        int o = r * MM + tid;
        int j = o & 7, ln = (o >> 3) & 63, kt = (o >> 9) % 12, mt = o / 6144;
        int m = mt * 16 + (ln & 15);
        int k = kt * 32 + ((ln >> 4) << 3) + j;
        u16 h, lo;
        // Q frag
        float qv = (k <= m) ? q_sqrt[m * MM + k] : 0.f;
        split_bf16(qv, h, lo);
        Qh[o] = h; Ql[o] = lo;
        // Kuu frag (recompute distance for (m,k))
        float s2 = 0.f;
#pragma unroll
        for (int d = 0; d < LL; ++d) {
            float dd = Z[m * LL + d] - Z[k * LL + d];
            s2 += dd * dd;
        }
        float kv = var * expf(c0 * s2);
        if (m == k) kv += JITTER;
        split_bf16(kv, h, lo);
        Kfh[o] = h; Kfl[o] = lo;
        // Z frag
        if (o < ZFRAG_N) {
            int zt = o >> 9;
            int mz = zt * 16 + (ln & 15);
            int kd = ((ln >> 4) << 3) + j;
            float zv = (kd < LL) ? Z[mz * LL + kd] : 0.f;
            split_bf16(zv, h, lo);
            Zfh[o] = h; Zfl[o] = lo;
        }
    }
}

// ---------------------------------------------------------------------------
// Launch 2: blocks 0-35: X1 = a*(2I - a*Kuu);
//           36-71: R1 = I - 2a*K + a^2*(K@K)  (K frags from prep);
//           72-107: SK = Q@Q^T - Kuu.
// a = 1.7/maxrowsum (scaled seed, verified round 13: 5 NS its at the floor).
__global__ void __launch_bounds__(256) ns1_kernel(
    const float* __restrict__ Kuu, const float* __restrict__ rsum,
    const u16* __restrict__ Kfh, const u16* __restrict__ Kfl,
    const u16* __restrict__ Qh, const u16* __restrict__ Ql,
    u16* __restrict__ Xh, u16* __restrict__ Xl,
    u16* __restrict__ Rh, u16* __restrict__ Rl,
    u16* __restrict__ SKh, u16* __restrict__ SKl) {
    __shared__ float red[256];
    int tid = threadIdx.x, blk = blockIdx.x;
    int w = tid >> 6, l = tid & 63;
    float alpha = 0.f;
    if (blk < 72) {
        float v0 = rsum[tid];
        if (tid < 128) v0 = fmaxf(v0, rsum[tid + 256]);
        red[tid] = v0;
        __syncthreads();
        for (int o = 128; o > 0; o >>= 1) {
            if (tid < o) red[tid] = fmaxf(red[tid], red[tid + o]);
            __syncthreads();
        }
        alpha = 1.7f / red[0];   // scaled seed
    }
    if (blk < 36) {
        float a2 = alpha * alpha;
        for (int o = blk * 256 + tid; o < FRAG_N; o += 36 * 256) {
            int j = o & 7, ln = (o >> 3) & 63, kt = (o >> 9) % 12, mt = o / 6144;
            int m = mt * 16 + (ln & 15);
            int k = kt * 32 + ((ln >> 4) << 3) + j;
            float v = ((m == k) ? 2.f * alpha : 0.f) - a2 * Kuu[m * MM + k];
            u16 h, lo;
            split_bf16(v, h, lo);
            Xh[o] = h; Xl[o] = lo;
        }
    } else if (blk < 72) {
        int tile = blk - 36;
        int bi = tile / 6, bj = tile % 6;
        floatx4 acc[2][2];
        frag_gemm64(Kfh, Kfl, Kfh, Kfl, bi, bj, w, l, acc);   // K @ K
        int mt0 = bi * 4 + 2 * (w & 1), nt0 = bj * 4 + 2 * (w >> 1);
        float a2 = alpha * alpha;
#pragma unroll
        for (int i = 0; i < 2; ++i)
#pragma unroll
            for (int jn = 0; jn < 2; ++jn)
#pragma unroll
                for (int j = 0; j < 4; ++j) {
                    int m = (mt0 + i) * 16 + ((l >> 4) << 2) + j;
                    int p = (nt0 + jn) * 16 + (l & 15);
                    float v = a2 * acc[i][jn][j] - 2.f * alpha * Kuu[m * MM + p]
                            + ((m == p) ? 1.f : 0.f);
                    dwrite_frag(Rh, Rl, m, p, v);
                }
    } else {
        int tile = blk - 72;
        int bi = tile / 6, bj = tile % 6;
        floatx4 acc[2][2];
        frag_gemm64(Qh, Ql, Qh, Ql, bi, bj, w, l, acc);
        int mt0 = bi * 4 + 2 * (w & 1), nt0 = bj * 4 + 2 * (w >> 1);
#pragma unroll
        for (int i = 0; i < 2; ++i)
#pragma unroll
            for (int jn = 0; jn < 2; ++jn)
#pragma unroll
                for (int j = 0; j < 4; ++j) {
                    int m = (mt0 + i) * 16 + ((l >> 4) << 2) + j;
                    int p = (nt0 + jn) * 16 + (l & 15);
                    dwrite_frag(SKh, SKl, m, p, acc[i][jn][j] - Kuu[m * MM + p]);
                }
    }
}

// ---------------------------------------------------------------------------
// NS rounds: blocks 0-35: X' = X + X@R ; 36-71: R' = R@R
__global__ void __launch_bounds__(256) ns_kernel(
    const u16* __restrict__ cxh, const u16* __restrict__ cxl,
    const u16* __restrict__ crh, const u16* __restrict__ crl,
    u16* __restrict__ nxh, u16* __restrict__ nxl,
    u16* __restrict__ nrh, u16* __restrict__ nrl) {
    int blk = blockIdx.x, tid = threadIdx.x;
    bool isX = (blk < 36);
    int tile = isX ? blk : blk - 36;
    int bi = tile / 6, bj = tile % 6;
    int w = tid >> 6, l = tid & 63;
    floatx4 acc[2][2];
    frag_gemm64(isX ? cxh : crh, isX ? cxl : crl, crh, crl, bi, bj, w, l, acc);
    int mt0 = bi * 4 + 2 * (w & 1), nt0 = bj * 4 + 2 * (w >> 1);
    u16* Oh = isX ? nxh : nrh;
    u16* Ol = isX ? nxl : nrl;
#pragma unroll
    for (int i = 0; i < 2; ++i)
#pragma unroll
        for (int jn = 0; jn < 2; ++jn)
#pragma unroll
            for (int j = 0; j < 4; ++j) {
                int m = (mt0 + i) * 16 + ((l >> 4) << 2) + j;
                int p = (nt0 + jn) * 16 + (l & 15);
                float v = acc[i][jn][j];
                if (isX) {
                    int id = frag_idx(m, p);
                    v += bf2f(cxh[id]) + bf2f(cxl[id]);
                }
                dwrite_frag(Oh, Ol, m, p, v);
            }
}

// ---------------------------------------------------------------------------
// Launch 7: blocks 0-35: Y = X @ SK ; blocks 36-41: cvec = X @ q_mu
__global__ void __launch_bounds__(256) y_kernel(
    const u16* __restrict__ Xh, const u16* __restrict__ Xl,
    const u16* __restrict__ SKh, const u16* __restrict__ SKl,
    const float* __restrict__ qmu,
    u16* __restrict__ Yh, u16* __restrict__ Yl, float* __restrict__ cvec) {
    __shared__ float q[MM];
    int tid = threadIdx.x, blk = blockIdx.x;
    int w = tid >> 6, l = tid & 63;
    if (blk < 36) {
        int bi = blk / 6, bj = blk % 6;
        floatx4 acc[2][2];
        frag_gemm64(Xh, Xl, SKh, SKl, bi, bj, w, l, acc);
        int mt0 = bi * 4 + 2 * (w & 1), nt0 = bj * 4 + 2 * (w >> 1);
#pragma unroll
        for (int i = 0; i < 2; ++i)
#pragma unroll
            for (int jn = 0; jn < 2; ++jn)
#pragma unroll
                for (int j = 0; j < 4; ++j) {
                    int m = (mt0 + i) * 16 + ((l >> 4) << 2) + j;
                    int p = (nt0 + jn) * 16 + (l & 15);
                    dwrite_frag(Yh, Yl, m, p, acc[i][jn][j]);
                }
    } else {
        if (tid < MM) q[tid] = qmu[tid];
        if (tid + 256 < MM) q[tid + 256] = qmu[tid + 256];
        __syncthreads();
        int mt = (blk - 36) * 4 + w;
        float s = 0.f;
        for (int kt = 0; kt < 12; ++kt) {
            int b = ((mt * 12 + kt) * 64 + l) * 8;
            short8 h8 = *(const short8*)&Xh[b];
            short8 l8 = *(const short8*)&Xl[b];
            int kb = kt * 32 + ((l >> 4) << 3);
#pragma unroll
            for (int j = 0; j < 8; ++j)
                s += (bf2f((u16)h8[j]) + bf2f((u16)l8[j])) * q[kb + j];
        }
        s += __shfl_xor(s, 16);
        s += __shfl_xor(s, 32);
        if (l < 16) cvec[mt * 16 + l] = s;
    }
}

// Launch 8: Bq = Y @ X — writes HI half only (verified round 14: invisible
// at the bf16 output floor).
__global__ void __launch_bounds__(256) bq_kernel(
    const u16* __restrict__ Yh, const u16* __restrict__ Yl,
    const u16* __restrict__ Xh, const u16* __restrict__ Xl,
    u16* __restrict__ Bh) {
    int blk = blockIdx.x, tid = threadIdx.x;
    int bi = blk / 6, bj = blk % 6;
    int w = tid >> 6, l = tid & 63;
    floatx4 acc[2][2];
    frag_gemm64(Yh, Yl, Xh, Xl, bi, bj, w, l, acc);
    int mt0 = bi * 4 + 2 * (w & 1), nt0 = bj * 4 + 2 * (w >> 1);
#pragma unroll
    for (int i = 0; i < 2; ++i)
#pragma unroll
        for (int jn = 0; jn < 2; ++jn)
#pragma unroll
            for (int j = 0; j < 4; ++j) {
                int m = (mt0 + i) * 16 + ((l >> 4) << 2) + j;
                int p = (nt0 + jn) * 16 + (l & 15);
                Bh[frag_idx(m, p)] = f2bf(acc[i][jn][j]);
            }
}

// ---------------------------------------------------------------------------
// Main fused kernel — TP=64 points/block, 512 threads, LDS ~61 KB ->
// 2 blocks/CU (16 waves) to hide latency (round 14 was latency-bound at
// 1 block/CU: Occupancy 18%, VALU inst count far below VALUBusy time).
// Bq hi-only single-term phase 2 keeps the extra L2 stream cost at ~+11 us.
__global__ void __launch_bounds__(512) main_kernel(
    const float* __restrict__ Xin,
    const u16* __restrict__ Zfh, const u16* __restrict__ Zfl,
    const float* __restrict__ z2g,
    const u16* __restrict__ Bfh,
    const float* __restrict__ cvec,
    const float* __restrict__ var_p, const float* __restrict__ ls_p,
    float* __restrict__ out) {
    __shared__ u16 kh[12 * 4 * 64 * 8];   // 48 KB: B-frag K tile (hi)
    __shared__ float patch[64 * 36];      // 9 KB
    __shared__ float zsq[MM];
    __shared__ float xsq[64];
    __shared__ float red[512];

    int tid = threadIdx.x;
    int np0 = blockIdx.x * 64;
    float var = var_p[0];
    float ls = ls_p[0];
    float c2 = -0.72134752044f / (ls * ls);   // -0.5*log2(e)/ls^2

    if (tid < MM) zsq[tid] = z2g[tid];
    for (int e = tid; e < 64 * 36; e += 512) {
        int pt = e / 36, c = e % 36;
        float v = 0.f;
        if (c < 25) {
            int np = np0 + pt;
            int n = np / PP, p = np % PP;
            int oi = p / 36, oj = p % 36;
            v = Xin[n * (HH * WW) + (oi + c / 5) * WW + (oj + c % 5)];
        }
        patch[e] = v;
    }
    __syncthreads();
    if (tid < 64) {
        float s = 0.f;
#pragma unroll
        for (int d = 0; d < LL; ++d) { float x = patch[tid * 36 + d]; s += x * x; }
        xsq[tid] = s;
    }
    __syncthreads();

    int w = tid >> 6, l = tid & 63;
    int u = l >> 4;

    u32 kpk[3][4][2];                     // packed bf16 K values (diag left factor)
    float mp[4] = {0.f, 0.f, 0.f, 0.f};

    // phase 1: cross = Z @ patch^T (split-bf16 MFMA, 3-term), K finalize
    {
        short8 pbh[4], pbl[4];
#pragma unroll
        for (int nt = 0; nt < 4; ++nt) {
            int p = nt * 16 + (l & 15);
            int pb = p * 36 + (u << 3);
            float4 f0 = *(const float4*)&patch[pb];
            float4 f1 = *(const float4*)&patch[pb + 4];
            float xv[8] = {f0.x, f0.y, f0.z, f0.w, f1.x, f1.y, f1.z, f1.w};
#pragma unroll
            for (int j = 0; j < 8; ++j) {
                u16 hh, lo;
                split_bf16(xv[j], hh, lo);
                pbh[nt][j] = (short)hh;
                pbl[nt][j] = (short)lo;
            }
        }
        floatx4 acc2[3][4];
#pragma unroll
        for (int i = 0; i < 3; ++i) {
            int zt = w * 3 + i;
            short8 zah = *(const short8*)&Zfh[(zt * 64 + l) * 8];
            short8 zal = *(const short8*)&Zfl[(zt * 64 + l) * 8];
#pragma unroll
            for (int nt = 0; nt < 4; ++nt) {
                floatx4 z = {0.f, 0.f, 0.f, 0.f};
                z = __builtin_amdgcn_mfma_f32_16x16x32_bf16(zah, pbh[nt], z, 0, 0, 0);
                z = __builtin_amdgcn_mfma_f32_16x16x32_bf16(zah, pbl[nt], z, 0, 0, 0);
                z = __builtin_amdgcn_mfma_f32_16x16x32_bf16(zal, pbh[nt], z, 0, 0, 0);
                acc2[i][nt] = z;
            }
        }
#pragma unroll
        for (int i = 0; i < 3; ++i) {
            int a2 = w * 3 + i;
            int kt = a2 >> 1;
            int rr = 2 * (a2 & 1) + (u >> 1);
            int k0 = a2 * 16 + 4 * u;
            float4 c4 = *(const float4*)&cvec[k0];
            float cvl[4] = {c4.x, c4.y, c4.z, c4.w};
#pragma unroll
            for (int nt = 0; nt < 4; ++nt) {
                int p = nt * 16 + (l & 15);
                u16 hi[4];
#pragma unroll
                for (int j = 0; j < 4; ++j) {
                    float s = zsq[k0 + j] + xsq[p] - 2.f * acc2[i][nt][j];
                    float v = var * exp2f(s * c2);
                    mp[nt] += cvl[j] * v;
                    hi[j] = f2bf(v);
                }
                u32 p0 = (u32)hi[0] | ((u32)hi[1] << 16);
                u32 p1 = (u32)hi[2] | ((u32)hi[3] << 16);
                int base = ((kt * 4 + nt) * 64 + rr * 16 + (l & 15)) * 8 + 4 * (u & 1);
                *(u32*)&kh[base]     = p0;
                *(u32*)&kh[base + 2] = p1;
                kpk[i][nt][0] = p0;
                kpk[i][nt][1] = p1;
            }
        }
    }

    // mean partials: wave-reduce, cross-wave via red
#pragma unroll
    for (int nt = 0; nt < 4; ++nt) {
        mp[nt] += __shfl_xor(mp[nt], 16);
        mp[nt] += __shfl_xor(mp[nt], 32);
    }
    if (l < 16) {
#pragma unroll
        for (int nt = 0; nt < 4; ++nt) red[w * 64 + nt * 16 + l] = mp[nt];
    }
    __syncthreads();   // publishes kh AND mean partials
    if (tid < 64) {
        float s = 0.f;
#pragma unroll
        for (int ww = 0; ww < 8; ++ww) s += red[ww * 64 + tid];
        out[np0 + tid] = s;   // mean
    }

    // phase 2: acc[m][p] = sum_k Bq[m][k] K[k][p]; Bq hi-only, K hi-only
    floatx4 acc[3][4];
#pragma unroll
    for (int i = 0; i < 3; ++i)
#pragma unroll
        for (int nt = 0; nt < 4; ++nt) { floatx4 z = {0.f, 0.f, 0.f, 0.f}; acc[i][nt] = z; }
    for (int kt = 0; kt < 12; ++kt) {
        short8 bh[4];
#pragma unroll
        for (int nt = 0; nt < 4; ++nt)
            bh[nt] = *(const short8*)&kh[((kt * 4 + nt) * 64 + l) * 8];
#pragma unroll
        for (int i = 0; i < 3; ++i) {
            int mt = w * 3 + i;
            int ab = ((mt * 12 + kt) * 64 + l) * 8;
            short8 ah = *(const short8*)&Bfh[ab];
#pragma unroll
            for (int nt = 0; nt < 4; ++nt)
                acc[i][nt] = __builtin_amdgcn_mfma_f32_16x16x32_bf16(ah, bh[nt], acc[i][nt], 0, 0, 0);
        }
    }
    __syncthreads();   // mean readers done before red reuse

    // diag epilogue: register dot; left factor = K hi (same D-frag map)
    float dp[4] = {0.f, 0.f, 0.f, 0.f};
#pragma unroll
    for (int i = 0; i < 3; ++i)
#pragma unroll
        for (int nt = 0; nt < 4; ++nt) {
            float kv0 = bf2f((u16)(kpk[i][nt][0] & 0xFFFFu));
            float kv1 = bf2f((u16)(kpk[i][nt][0] >> 16));
            float kv2 = bf2f((u16)(kpk[i][nt][1] & 0xFFFFu));
            float kv3 = bf2f((u16)(kpk[i][nt][1] >> 16));
            dp[nt] += kv0 * acc[i][nt][0] + kv1 * acc[i][nt][1]
                    + kv2 * acc[i][nt][2] + kv3 * acc[i][nt][3];
        }
#pragma unroll
    for (int nt = 0; nt < 4; ++nt) {
        dp[nt] += __shfl_xor(dp[nt], 16);
        dp[nt] += __shfl_xor(dp[nt], 32);
    }
    if (l < 16) {
#pragma unroll
        for (int nt = 0; nt < 4; ++nt) red[w * 64 + nt * 16 + l] = dp[nt];
    }
    __syncthreads();
    if (tid < 64) {
        float s = 0.f;
#pragma unroll
        for (int ww = 0; ww < 8; ++ww) s += red[ww * 64 + tid];
        out[NPTS + np0 + tid] = var + s;
    }
}

// ---------------------------------------------------------------------------
extern "C" void kernel_launch(void* const* d_in, const int* in_sizes, int n_in,
                              void* d_out, int out_size, void* d_ws, size_t ws_size,
                              hipStream_t stream) {
    const float* Xin    = (const float*)d_in[0];
    const float* Z      = (const float*)d_in[1];
    const float* q_mu   = (const float*)d_in[2];
    const float* q_sqrt = (const float*)d_in[3];
    const float* var_p  = (const float*)d_in[4];
    const float* ls_p   = (const float*)d_in[5];
    float* out = (float*)d_out;

    const size_t HB = (size_t)FRAG_N * 2;  // 294912 B per frag half-array
    char* base = (char*)d_ws;
    float* Kuu = (float*)base;                 // 2 HB; Bq-hi overlays later
    u16* Bqh = (u16*)base;
    u16* Xh_a = (u16*)(base + 2 * HB);         // Kuu frags overlay (used only in ns1)
    u16* Xl_a = (u16*)(base + 3 * HB);
    u16* Kfh = Xh_a;
    u16* Kfl = Xl_a;
    u16* Xh_b = (u16*)(base + 4 * HB);
    u16* Xl_b = (u16*)(base + 5 * HB);
    u16* Rh_a = (u16*)(base + 6 * HB);
    u16* Rl_a = (u16*)(base + 7 * HB);
    u16* Rh_b = (u16*)(base + 8 * HB);
    u16* Rl_b = (u16*)(base + 9 * HB);
    u16* Qh   = (u16*)(base + 10 * HB);        // Q frags; Y overlays later
    u16* Ql   = (u16*)(base + 11 * HB);
    u16* Yh = Qh;
    u16* Yl = Ql;
    u16* SKh  = (u16*)(base + 12 * HB);
    u16* SKl  = (u16*)(base + 13 * HB);
    char* pF = base + 14 * HB;
    u16* Zfh = (u16*)pF;
    u16* Zfl = (u16*)(pF + ZFRAG_N * 2);
    float* z2g  = (float*)(pF + ZFRAG_N * 4);
    float* cvec = z2g + MM;
    float* rsum = cvec + MM;

    // 1) prep: Kuu dense+frags, rowsums, z2, Z frags, Q frags
    prep_kernel<<<MM, 384, 0, stream>>>(Z, q_sqrt, var_p, ls_p, Kuu, rsum, z2g,
                                        Kfh, Kfl, Qh, Ql, Zfh, Zfl);
    // 2) ns1 (scaled seed a=1.7/maxrowsum): X1 | R1 | SK
    ns1_kernel<<<108, 256, 0, stream>>>(Kuu, rsum, Kfh, Kfl, Qh, Ql,
                                        Xh_b, Xl_b, Rh_b, Rl_b, SKh, SKl);
    // 3-6) NS rounds 2..5 (4 launches -> 5 total NS iterations w/ scaled seed)
    u16 *cxh = Xh_b, *cxl = Xl_b, *nxh = Xh_a, *nxl = Xl_a;
    u16 *crh = Rh_b, *crl = Rl_b, *nrh = Rh_a, *nrl = Rl_a;
    for (int it = 0; it < 4; ++it) {
        ns_kernel<<<72, 256, 0, stream>>>(cxh, cxl, crh, crl, nxh, nxl, nrh, nrl);
        u16* t;
        t = cxh; cxh = nxh; nxh = t;
        t = cxl; cxl = nxl; nxl = t;
        t = crh; crh = nrh; nrh = t;
        t = crl; crl = nrl; nrl = t;
    }
    // 7) Y = X@SK | cvec = X@q_mu
    y_kernel<<<42, 256, 0, stream>>>(cxh, cxl, SKh, SKl, q_mu, Yh, Yl, cvec);
    // 8) Bq = Y@X, hi only (into Kuu region)
    bq_kernel<<<36, 256, 0, stream>>>(Yh, Yl, cxh, cxl, Bqh);
    // 9) main (64 points/block, 2 blocks/CU)
    main_kernel<<<NPTS / 64, 512, 0, stream>>>(Xin, Zfh, Zfl, z2g, Bqh, cvec,
                                               var_p, ls_p, out);
}

// Round 16
// 159.954 us; speedup vs baseline: 1.6695x; 1.0085x over previous
//
#include <hip/hip_runtime.h>
#include <hip/hip_bf16.h>

// Problem constants
#define HH 40
#define WW 40
#define KK 5
#define PP 1296            // 36*36
#define LL 25
#define MM 384
#define NN 64
#define NPTS (NN * PP)     // 82944
#define JITTER 1e-6f

typedef unsigned short u16;
typedef unsigned int   u32;
using short8  = __attribute__((ext_vector_type(8))) short;
using floatx4 = __attribute__((ext_vector_type(4))) float;

#define FRAG_N (MM * MM)        // u16 per frag half-array (147456)
#define ZFRAG_N (24 * 64 * 8)   // 12288

// ---------------------------------------------------------------------------
// bf16 split helpers (RNE)
__device__ inline u16 f2bf(float v) {
    u32 b = __float_as_uint(v);
    return (u16)((b + 0x7FFFu + ((b >> 16) & 1u)) >> 16);
}
__device__ inline float bf2f(u16 h) { return __uint_as_float(((u32)h) << 16); }
__device__ inline void split_bf16(float v, u16& hi, u16& lo) {
    hi = f2bf(v);
    lo = f2bf(v - bf2f(hi));
}

// A-fragment linear index (u16 units) for element (m,k), HW-verified rounds 2-15.
__device__ inline int frag_idx(int m, int k) {
    return (((m >> 4) * 12 + (k >> 5)) * 64 + ((m & 15) + (((k >> 3) & 3) << 4))) * 8 + (k & 7);
}

// ---------------------------------------------------------------------------
// Split-bf16 MFMA 64x64-tile GEMM on A-frag operands: C = A . B^T_storage.
__device__ inline void frag_gemm64(const u16* __restrict__ Ah, const u16* __restrict__ Al,
                                   const u16* __restrict__ Bh, const u16* __restrict__ Bl,
                                   int bi, int bj, int w, int l, floatx4 acc[2][2]) {
    int mt0 = bi * 4 + 2 * (w & 1);
    int nt0 = bj * 4 + 2 * (w >> 1);
#pragma unroll
    for (int i = 0; i < 2; ++i)
#pragma unroll
        for (int jn = 0; jn < 2; ++jn) { floatx4 z = {0.f, 0.f, 0.f, 0.f}; acc[i][jn] = z; }
    for (int kt = 0; kt < 12; ++kt) {
        int ab0 = (((mt0 + 0) * 12 + kt) * 64 + l) * 8;
        int ab1 = (((mt0 + 1) * 12 + kt) * 64 + l) * 8;
        int bb0 = (((nt0 + 0) * 12 + kt) * 64 + l) * 8;
        int bb1 = (((nt0 + 1) * 12 + kt) * 64 + l) * 8;
        short8 a0h = *(const short8*)&Ah[ab0];
        short8 a0l = *(const short8*)&Al[ab0];
        short8 a1h = *(const short8*)&Ah[ab1];
        short8 a1l = *(const short8*)&Al[ab1];
        short8 b0h = *(const short8*)&Bh[bb0];
        short8 b0l = *(const short8*)&Bl[bb0];
        short8 b1h = *(const short8*)&Bh[bb1];
        short8 b1l = *(const short8*)&Bl[bb1];
        acc[0][0] = __builtin_amdgcn_mfma_f32_16x16x32_bf16(a0h, b0h, acc[0][0], 0, 0, 0);
        acc[0][0] = __builtin_amdgcn_mfma_f32_16x16x32_bf16(a0h, b0l, acc[0][0], 0, 0, 0);
        acc[0][0] = __builtin_amdgcn_mfma_f32_16x16x32_bf16(a0l, b0h, acc[0][0], 0, 0, 0);
        acc[0][1] = __builtin_amdgcn_mfma_f32_16x16x32_bf16(a0h, b1h, acc[0][1], 0, 0, 0);
        acc[0][1] = __builtin_amdgcn_mfma_f32_16x16x32_bf16(a0h, b1l, acc[0][1], 0, 0, 0);
        acc[0][1] = __builtin_amdgcn_mfma_f32_16x16x32_bf16(a0l, b1h, acc[0][1], 0, 0, 0);
        acc[1][0] = __builtin_amdgcn_mfma_f32_16x16x32_bf16(a1h, b0h, acc[1][0], 0, 0, 0);
        acc[1][0] = __builtin_amdgcn_mfma_f32_16x16x32_bf16(a1h, b0l, acc[1][0], 0, 0, 0);
        acc[1][0] = __builtin_amdgcn_mfma_f32_16x16x32_bf16(a1l, b0h, acc[1][0], 0, 0, 0);
        acc[1][1] = __builtin_amdgcn_mfma_f32_16x16x32_bf16(a1h, b1h, acc[1][1], 0, 0, 0);
        acc[1][1] = __builtin_amdgcn_mfma_f32_16x16x32_bf16(a1h, b1l, acc[1][1], 0, 0, 0);
        acc[1][1] = __builtin_amdgcn_mfma_f32_16x16x32_bf16(a1l, b1h, acc[1][1], 0, 0, 0);
    }
}

__device__ inline void dwrite_frag(u16* __restrict__ Oh, u16* __restrict__ Ol,
                                   int m, int p, float v) {
    int idx = frag_idx(m, p);
    u16 hi, lo;
    split_bf16(v, hi, lo);
    Oh[idx] = hi; Ol[idx] = lo;
}

// ---------------------------------------------------------------------------
// Launch 1: Kuu dense + Kuu frags + rowsums + z2 + Z frags + Q frags.
__global__ void __launch_bounds__(384) prep_kernel(
    const float* __restrict__ Z, const float* __restrict__ q_sqrt,
    const float* __restrict__ var_p, const float* __restrict__ ls_p,
    float* __restrict__ Kuu, float* __restrict__ rsum, float* __restrict__ z2g,
    u16* __restrict__ Kfh, u16* __restrict__ Kfl,
    u16* __restrict__ Qh, u16* __restrict__ Ql,
    u16* __restrict__ Zfh, u16* __restrict__ Zfl) {
    __shared__ float Zs[LL];
    __shared__ float red[384];
    int r = blockIdx.x, tid = threadIdx.x;
    if (tid < LL) Zs[tid] = Z[r * LL + tid];
    __syncthreads();
    float var = var_p[0];
    float ls = ls_p[0];
    float c0 = -0.5f / (ls * ls);
    float s = 0.f;
#pragma unroll
    for (int d = 0; d < LL; ++d) {
        float dd = Zs[d] - Z[tid * LL + d];
        s += dd * dd;
    }
    float v = var * expf(c0 * s);
    if (tid == r) v += JITTER;
    Kuu[r * MM + tid] = v;
    red[tid] = v;
    __syncthreads();
    if (tid < 128) red[tid] += red[tid + 256];
    __syncthreads();
    for (int o = 128; o > 0; o >>= 1) {
        if (tid < o) red[tid] += red[tid + o];
        __syncthreads();
    }
    if (tid == 0) {
        rsum[r] = red[0];
        float t = 0.f;
#pragma unroll
        for (int d = 0; d < LL; ++d) t += Zs[d] * Zs[d];
        z2g[r] = t;
    }
    // frag-order writes: one element per thread (384*384 == FRAG_N)
    {
        int o = r * MM + tid;
        int j = o & 7, ln = (o >> 3) & 63, kt = (o >> 9) % 12, mt = o / 6144;
        int m = mt * 16 + (ln & 15);
        int k = kt * 32 + ((ln >> 4) << 3) + j;
        u16 h, lo;
        // Q frag
        float qv = (k <= m) ? q_sqrt[m * MM + k] : 0.f;
        split_bf16(qv, h, lo);
        Qh[o] = h; Ql[o] = lo;
        // Kuu frag (recompute distance for (m,k))
        float s2 = 0.f;
#pragma unroll
        for (int d = 0; d < LL; ++d) {
            float dd = Z[m * LL + d] - Z[k * LL + d];
            s2 += dd * dd;
        }
        float kv = var * expf(c0 * s2);
        if (m == k) kv += JITTER;
        split_bf16(kv, h, lo);
        Kfh[o] = h; Kfl[o] = lo;
        // Z frag
        if (o < ZFRAG_N) {
            int zt = o >> 9;
            int mz = zt * 16 + (ln & 15);
            int kd = ((ln >> 4) << 3) + j;
            float zv = (kd < LL) ? Z[mz * LL + kd] : 0.f;
            split_bf16(zv, h, lo);
            Zfh[o] = h; Zfl[o] = lo;
        }
    }
}

// ---------------------------------------------------------------------------
// Launch 2: blocks 0-35: X1 = a*(2I - a*Kuu);
//           36-71: R1 = I - 2a*K + a^2*(K@K)  (K frags from prep);
//           72-107: SK = Q@Q^T - Kuu.
// a = 1.7/maxrowsum (scaled seed, verified round 13: 5 NS its at the floor).
__global__ void __launch_bounds__(256) ns1_kernel(
    const float* __restrict__ Kuu, const float* __restrict__ rsum,
    const u16* __restrict__ Kfh, const u16* __restrict__ Kfl,
    const u16* __restrict__ Qh, const u16* __restrict__ Ql,
    u16* __restrict__ Xh, u16* __restrict__ Xl,
    u16* __restrict__ Rh, u16* __restrict__ Rl,
    u16* __restrict__ SKh, u16* __restrict__ SKl) {
    __shared__ float red[256];
    int tid = threadIdx.x, blk = blockIdx.x;
    int w = tid >> 6, l = tid & 63;
    float alpha = 0.f;
    if (blk < 72) {
        float v0 = rsum[tid];
        if (tid < 128) v0 = fmaxf(v0, rsum[tid + 256]);
        red[tid] = v0;
        __syncthreads();
        for (int o = 128; o > 0; o >>= 1) {
            if (tid < o) red[tid] = fmaxf(red[tid], red[tid + o]);
            __syncthreads();
        }
        alpha = 1.7f / red[0];   // scaled seed
    }
    if (blk < 36) {
        float a2 = alpha * alpha;
        for (int o = blk * 256 + tid; o < FRAG_N; o += 36 * 256) {
            int j = o & 7, ln = (o >> 3) & 63, kt = (o >> 9) % 12, mt = o / 6144;
            int m = mt * 16 + (ln & 15);
            int k = kt * 32 + ((ln >> 4) << 3) + j;
            float v = ((m == k) ? 2.f * alpha : 0.f) - a2 * Kuu[m * MM + k];
            u16 h, lo;
            split_bf16(v, h, lo);
            Xh[o] = h; Xl[o] = lo;
        }
    } else if (blk < 72) {
        int tile = blk - 36;
        int bi = tile / 6, bj = tile % 6;
        floatx4 acc[2][2];
        frag_gemm64(Kfh, Kfl, Kfh, Kfl, bi, bj, w, l, acc);   // K @ K
        int mt0 = bi * 4 + 2 * (w & 1), nt0 = bj * 4 + 2 * (w >> 1);
        float a2 = alpha * alpha;
#pragma unroll
        for (int i = 0; i < 2; ++i)
#pragma unroll
            for (int jn = 0; jn < 2; ++jn)
#pragma unroll
                for (int j = 0; j < 4; ++j) {
                    int m = (mt0 + i) * 16 + ((l >> 4) << 2) + j;
                    int p = (nt0 + jn) * 16 + (l & 15);
                    float v = a2 * acc[i][jn][j] - 2.f * alpha * Kuu[m * MM + p]
                            + ((m == p) ? 1.f : 0.f);
                    dwrite_frag(Rh, Rl, m, p, v);
                }
    } else {
        int tile = blk - 72;
        int bi = tile / 6, bj = tile % 6;
        floatx4 acc[2][2];
        frag_gemm64(Qh, Ql, Qh, Ql, bi, bj, w, l, acc);
        int mt0 = bi * 4 + 2 * (w & 1), nt0 = bj * 4 + 2 * (w >> 1);
#pragma unroll
        for (int i = 0; i < 2; ++i)
#pragma unroll
            for (int jn = 0; jn < 2; ++jn)
#pragma unroll
                for (int j = 0; j < 4; ++j) {
                    int m = (mt0 + i) * 16 + ((l >> 4) << 2) + j;
                    int p = (nt0 + jn) * 16 + (l & 15);
                    dwrite_frag(SKh, SKl, m, p, acc[i][jn][j] - Kuu[m * MM + p]);
                }
    }
}

// ---------------------------------------------------------------------------
// NS rounds: blocks 0-35: X' = X + X@R ; 36-71: R' = R@R
__global__ void __launch_bounds__(256) ns_kernel(
    const u16* __restrict__ cxh, const u16* __restrict__ cxl,
    const u16* __restrict__ crh, const u16* __restrict__ crl,
    u16* __restrict__ nxh, u16* __restrict__ nxl,
    u16* __restrict__ nrh, u16* __restrict__ nrl) {
    int blk = blockIdx.x, tid = threadIdx.x;
    bool isX = (blk < 36);
    int tile = isX ? blk : blk - 36;
    int bi = tile / 6, bj = tile % 6;
    int w = tid >> 6, l = tid & 63;
    floatx4 acc[2][2];
    frag_gemm64(isX ? cxh : crh, isX ? cxl : crl, crh, crl, bi, bj, w, l, acc);
    int mt0 = bi * 4 + 2 * (w & 1), nt0 = bj * 4 + 2 * (w >> 1);
    u16* Oh = isX ? nxh : nrh;
    u16* Ol = isX ? nxl : nrl;
#pragma unroll
    for (int i = 0; i < 2; ++i)
#pragma unroll
        for (int jn = 0; jn < 2; ++jn)
#pragma unroll
            for (int j = 0; j < 4; ++j) {
                int m = (mt0 + i) * 16 + ((l >> 4) << 2) + j;
                int p = (nt0 + jn) * 16 + (l & 15);
                float v = acc[i][jn][j];
                if (isX) {
                    int id = frag_idx(m, p);
                    v += bf2f(cxh[id]) + bf2f(cxl[id]);
                }
                dwrite_frag(Oh, Ol, m, p, v);
            }
}

// ---------------------------------------------------------------------------
// Launch 7: blocks 0-35: Y = X @ SK ; blocks 36-41: cvec = X @ q_mu
__global__ void __launch_bounds__(256) y_kernel(
    const u16* __restrict__ Xh, const u16* __restrict__ Xl,
    const u16* __restrict__ SKh, const u16* __restrict__ SKl,
    const float* __restrict__ qmu,
    u16* __restrict__ Yh, u16* __restrict__ Yl, float* __restrict__ cvec) {
    __shared__ float q[MM];
    int tid = threadIdx.x, blk = blockIdx.x;
    int w = tid >> 6, l = tid & 63;
    if (blk < 36) {
        int bi = blk / 6, bj = blk % 6;
        floatx4 acc[2][2];
        frag_gemm64(Xh, Xl, SKh, SKl, bi, bj, w, l, acc);
        int mt0 = bi * 4 + 2 * (w & 1), nt0 = bj * 4 + 2 * (w >> 1);
#pragma unroll
        for (int i = 0; i < 2; ++i)
#pragma unroll
            for (int jn = 0; jn < 2; ++jn)
#pragma unroll
                for (int j = 0; j < 4; ++j) {
                    int m = (mt0 + i) * 16 + ((l >> 4) << 2) + j;
                    int p = (nt0 + jn) * 16 + (l & 15);
                    dwrite_frag(Yh, Yl, m, p, acc[i][jn][j]);
                }
    } else {
        if (tid < MM) q[tid] = qmu[tid];
        if (tid + 256 < MM) q[tid + 256] = qmu[tid + 256];
        __syncthreads();
        int mt = (blk - 36) * 4 + w;
        float s = 0.f;
        for (int kt = 0; kt < 12; ++kt) {
            int b = ((mt * 12 + kt) * 64 + l) * 8;
            short8 h8 = *(const short8*)&Xh[b];
            short8 l8 = *(const short8*)&Xl[b];
            int kb = kt * 32 + ((l >> 4) << 3);
#pragma unroll
            for (int j = 0; j < 8; ++j)
                s += (bf2f((u16)h8[j]) + bf2f((u16)l8[j])) * q[kb + j];
        }
        s += __shfl_xor(s, 16);
        s += __shfl_xor(s, 32);
        if (l < 16) cvec[mt * 16 + l] = s;
    }
}

// Launch 8: Bq = Y @ X — writes HI half only (verified round 14: invisible
// at the bf16 output floor).
__global__ void __launch_bounds__(256) bq_kernel(
    const u16* __restrict__ Yh, const u16* __restrict__ Yl,
    const u16* __restrict__ Xh, const u16* __restrict__ Xl,
    u16* __restrict__ Bh) {
    int blk = blockIdx.x, tid = threadIdx.x;
    int bi = blk / 6, bj = blk % 6;
    int w = tid >> 6, l = tid & 63;
    floatx4 acc[2][2];
    frag_gemm64(Yh, Yl, Xh, Xl, bi, bj, w, l, acc);
    int mt0 = bi * 4 + 2 * (w & 1), nt0 = bj * 4 + 2 * (w >> 1);
#pragma unroll
    for (int i = 0; i < 2; ++i)
#pragma unroll
        for (int jn = 0; jn < 2; ++jn)
#pragma unroll
            for (int j = 0; j < 4; ++j) {
                int m = (mt0 + i) * 16 + ((l >> 4) << 2) + j;
                int p = (nt0 + jn) * 16 + (l & 15);
                Bh[frag_idx(m, p)] = f2bf(acc[i][jn][j]);
            }
}

// ---------------------------------------------------------------------------
// Main fused kernel — TP=64, 512 threads. patch ALIASED into kh (dead after
// pb-frag reads; hazard structure verified in round 6) -> LDS ~53 KB ->
// 3 blocks/CU, 24 waves/CU to hide latency (round 15: 2 blocks/CU, Occ 31%).
__global__ void __launch_bounds__(512) main_kernel(
    const float* __restrict__ Xin,
    const u16* __restrict__ Zfh, const u16* __restrict__ Zfl,
    const float* __restrict__ z2g,
    const u16* __restrict__ Bfh,
    const float* __restrict__ cvec,
    const float* __restrict__ var_p, const float* __restrict__ ls_p,
    float* __restrict__ out) {
    __shared__ u16 kh[12 * 4 * 64 * 8];   // 48 KB; first 9216 B double as patch
    __shared__ float zsq[MM];
    __shared__ float xsq[64];
    __shared__ float red[512];
    float* patch = (float*)kh;            // [64][36], dead before kh writes

    int tid = threadIdx.x;
    int np0 = blockIdx.x * 64;
    float var = var_p[0];
    float ls = ls_p[0];
    float c2 = -0.72134752044f / (ls * ls);   // -0.5*log2(e)/ls^2

    if (tid < MM) zsq[tid] = z2g[tid];
    for (int e = tid; e < 64 * 36; e += 512) {
        int pt = e / 36, c = e % 36;
        float v = 0.f;
        if (c < 25) {
            int np = np0 + pt;
            int n = np / PP, p = np % PP;
            int oi = p / 36, oj = p % 36;
            v = Xin[n * (HH * WW) + (oi + c / 5) * WW + (oj + c % 5)];
        }
        patch[e] = v;
    }
    __syncthreads();
    if (tid < 64) {
        float s = 0.f;
#pragma unroll
        for (int d = 0; d < LL; ++d) { float x = patch[tid * 36 + d]; s += x * x; }
        xsq[tid] = s;
    }
    int w = tid >> 6, l = tid & 63;
    int u = l >> 4;

    // pb frags: LAST patch readers
    short8 pbh[4], pbl[4];
#pragma unroll
    for (int nt = 0; nt < 4; ++nt) {
        int p = nt * 16 + (l & 15);
        int pb = p * 36 + (u << 3);
        float4 f0 = *(const float4*)&patch[pb];
        float4 f1 = *(const float4*)&patch[pb + 4];
        float xv[8] = {f0.x, f0.y, f0.z, f0.w, f1.x, f1.y, f1.z, f1.w};
#pragma unroll
        for (int j = 0; j < 8; ++j) {
            u16 hh, lo;
            split_bf16(xv[j], hh, lo);
            pbh[nt][j] = (short)hh;
            pbl[nt][j] = (short)lo;
        }
    }
    __syncthreads();   // patch dead; kh region reusable; xsq visible

    u32 kpk[3][4][2];                     // packed bf16 K values (diag left factor)
    float mp[4] = {0.f, 0.f, 0.f, 0.f};

    // phase 1: cross = Z @ patch^T (split-bf16 MFMA, 3-term), K finalize
    {
        floatx4 acc2[3][4];
#pragma unroll
        for (int i = 0; i < 3; ++i) {
            int zt = w * 3 + i;
            short8 zah = *(const short8*)&Zfh[(zt * 64 + l) * 8];
            short8 zal = *(const short8*)&Zfl[(zt * 64 + l) * 8];
#pragma unroll
            for (int nt = 0; nt < 4; ++nt) {
                floatx4 z = {0.f, 0.f, 0.f, 0.f};
                z = __builtin_amdgcn_mfma_f32_16x16x32_bf16(zah, pbh[nt], z, 0, 0, 0);
                z = __builtin_amdgcn_mfma_f32_16x16x32_bf16(zah, pbl[nt], z, 0, 0, 0);
                z = __builtin_amdgcn_mfma_f32_16x16x32_bf16(zal, pbh[nt], z, 0, 0, 0);
                acc2[i][nt] = z;
            }
        }
#pragma unroll
        for (int i = 0; i < 3; ++i) {
            int a2 = w * 3 + i;
            int kt = a2 >> 1;
            int rr = 2 * (a2 & 1) + (u >> 1);
            int k0 = a2 * 16 + 4 * u;
            float4 c4 = *(const float4*)&cvec[k0];
            float cvl[4] = {c4.x, c4.y, c4.z, c4.w};
#pragma unroll
            for (int nt = 0; nt < 4; ++nt) {
                int p = nt * 16 + (l & 15);
                u16 hi[4];
#pragma unroll
                for (int j = 0; j < 4; ++j) {
                    float s = zsq[k0 + j] + xsq[p] - 2.f * acc2[i][nt][j];
                    float v = var * exp2f(s * c2);
                    mp[nt] += cvl[j] * v;
                    hi[j] = f2bf(v);
                }
                u32 p0 = (u32)hi[0] | ((u32)hi[1] << 16);
                u32 p1 = (u32)hi[2] | ((u32)hi[3] << 16);
                int base = ((kt * 4 + nt) * 64 + rr * 16 + (l & 15)) * 8 + 4 * (u & 1);
                *(u32*)&kh[base]     = p0;
                *(u32*)&kh[base + 2] = p1;
                kpk[i][nt][0] = p0;
                kpk[i][nt][1] = p1;
            }
        }
    }

    // mean partials: wave-reduce, cross-wave via red
#pragma unroll
    for (int nt = 0; nt < 4; ++nt) {
        mp[nt] += __shfl_xor(mp[nt], 16);
        mp[nt] += __shfl_xor(mp[nt], 32);
    }
    if (l < 16) {
#pragma unroll
        for (int nt = 0; nt < 4; ++nt) red[w * 64 + nt * 16 + l] = mp[nt];
    }
    __syncthreads();   // publishes kh AND mean partials
    if (tid < 64) {
        float s = 0.f;
#pragma unroll
        for (int ww = 0; ww < 8; ++ww) s += red[ww * 64 + tid];
        out[np0 + tid] = s;   // mean
    }

    // phase 2: acc[m][p] = sum_k Bq[m][k] K[k][p]; Bq hi-only, K hi-only
    floatx4 acc[3][4];
#pragma unroll
    for (int i = 0; i < 3; ++i)
#pragma unroll
        for (int nt = 0; nt < 4; ++nt) { floatx4 z = {0.f, 0.f, 0.f, 0.f}; acc[i][nt] = z; }
    for (int kt = 0; kt < 12; ++kt) {
        short8 bh[4];
#pragma unroll
        for (int nt = 0; nt < 4; ++nt)
            bh[nt] = *(const short8*)&kh[((kt * 4 + nt) * 64 + l) * 8];
#pragma unroll
        for (int i = 0; i < 3; ++i) {
            int mt = w * 3 + i;
            int ab = ((mt * 12 + kt) * 64 + l) * 8;
            short8 ah = *(const short8*)&Bfh[ab];
#pragma unroll
            for (int nt = 0; nt < 4; ++nt)
                acc[i][nt] = __builtin_amdgcn_mfma_f32_16x16x32_bf16(ah, bh[nt], acc[i][nt], 0, 0, 0);
        }
    }
    __syncthreads();   // mean readers done before red reuse

    // diag epilogue: register dot; left factor = K hi (same D-frag map)
    float dp[4] = {0.f, 0.f, 0.f, 0.f};
#pragma unroll
    for (int i = 0; i < 3; ++i)
#pragma unroll
        for (int nt = 0; nt < 4; ++nt) {
            float kv0 = bf2f((u16)(kpk[i][nt][0] & 0xFFFFu));
            float kv1 = bf2f((u16)(kpk[i][nt][0] >> 16));
            float kv2 = bf2f((u16)(kpk[i][nt][1] & 0xFFFFu));
            float kv3 = bf2f((u16)(kpk[i][nt][1] >> 16));
            dp[nt] += kv0 * acc[i][nt][0] + kv1 * acc[i][nt][1]
                    + kv2 * acc[i][nt][2] + kv3 * acc[i][nt][3];
        }
#pragma unroll
    for (int nt = 0; nt < 4; ++nt) {
        dp[nt] += __shfl_xor(dp[nt], 16);
        dp[nt] += __shfl_xor(dp[nt], 32);
    }
    if (l < 16) {
#pragma unroll
        for (int nt = 0; nt < 4; ++nt) red[w * 64 + nt * 16 + l] = dp[nt];
    }
    __syncthreads();
    if (tid < 64) {
        float s = 0.f;
#pragma unroll
        for (int ww = 0; ww < 8; ++ww) s += red[ww * 64 + tid];
        out[NPTS + np0 + tid] = var + s;
    }
}

// ---------------------------------------------------------------------------
extern "C" void kernel_launch(void* const* d_in, const int* in_sizes, int n_in,
                              void* d_out, int out_size, void* d_ws, size_t ws_size,
                              hipStream_t stream) {
    const float* Xin    = (const float*)d_in[0];
    const float* Z      = (const float*)d_in[1];
    const float* q_mu   = (const float*)d_in[2];
    const float* q_sqrt = (const float*)d_in[3];
    const float* var_p  = (const float*)d_in[4];
    const float* ls_p   = (const float*)d_in[5];
    float* out = (float*)d_out;

    const size_t HB = (size_t)FRAG_N * 2;  // 294912 B per frag half-array
    char* base = (char*)d_ws;
    float* Kuu = (float*)base;                 // 2 HB; Bq-hi overlays later
    u16* Bqh = (u16*)base;
    u16* Xh_a = (u16*)(base + 2 * HB);         // Kuu frags overlay (used only in ns1)
    u16* Xl_a = (u16*)(base + 3 * HB);
    u16* Kfh = Xh_a;
    u16* Kfl = Xl_a;
    u16* Xh_b = (u16*)(base + 4 * HB);
    u16* Xl_b = (u16*)(base + 5 * HB);
    u16* Rh_a = (u16*)(base + 6 * HB);
    u16* Rl_a = (u16*)(base + 7 * HB);
    u16* Rh_b = (u16*)(base + 8 * HB);
    u16* Rl_b = (u16*)(base + 9 * HB);
    u16* Qh   = (u16*)(base + 10 * HB);        // Q frags; Y overlays later
    u16* Ql   = (u16*)(base + 11 * HB);
    u16* Yh = Qh;
    u16* Yl = Ql;
    u16* SKh  = (u16*)(base + 12 * HB);
    u16* SKl  = (u16*)(base + 13 * HB);
    char* pF = base + 14 * HB;
    u16* Zfh = (u16*)pF;
    u16* Zfl = (u16*)(pF + ZFRAG_N * 2);
    float* z2g  = (float*)(pF + ZFRAG_N * 4);
    float* cvec = z2g + MM;
    float* rsum = cvec + MM;

    // 1) prep: Kuu dense+frags, rowsums, z2, Z frags, Q frags
    prep_kernel<<<MM, 384, 0, stream>>>(Z, q_sqrt, var_p, ls_p, Kuu, rsum, z2g,
                                        Kfh, Kfl, Qh, Ql, Zfh, Zfl);
    // 2) ns1 (scaled seed a=1.7/maxrowsum): X1 | R1 | SK
    ns1_kernel<<<108, 256, 0, stream>>>(Kuu, rsum, Kfh, Kfl, Qh, Ql,
                                        Xh_b, Xl_b, Rh_b, Rl_b, SKh, SKl);
    // 3-6) NS rounds 2..5 (4 launches -> 5 total NS iterations w/ scaled seed)
    u16 *cxh = Xh_b, *cxl = Xl_b, *nxh = Xh_a, *nxl = Xl_a;
    u16 *crh = Rh_b, *crl = Rl_b, *nrh = Rh_a, *nrl = Rl_a;
    for (int it = 0; it < 4; ++it) {
        ns_kernel<<<72, 256, 0, stream>>>(cxh, cxl, crh, crl, nxh, nxl, nrh, nrl);
        u16* t;
        t = cxh; cxh = nxh; nxh = t;
        t = cxl; cxl = nxl; nxl = t;
        t = crh; crh = nrh; nrh = t;
        t = crl; crl = nrl; nrl = t;
    }
    // 7) Y = X@SK | cvec = X@q_mu
    y_kernel<<<42, 256, 0, stream>>>(cxh, cxl, SKh, SKl, q_mu, Yh, Yl, cvec);
    // 8) Bq = Y@X, hi only (into Kuu region)
    bq_kernel<<<36, 256, 0, stream>>>(Yh, Yl, cxh, cxl, Bqh);
    // 9) main (64 points/block, 3 blocks/CU)
    main_kernel<<<NPTS / 64, 512, 0, stream>>>(Xin, Zfh, Zfl, z2g, Bqh, cvec,
                                               var_p, ls_p, out);
}